// Round 26
// baseline (629.797 us; speedup 1.0000x reference)
//
#include <hip/hip_runtime.h>
#include <hip/hip_bf16.h>
#include <stdint.h>

// CGRModel forward — all-bf16 MFMA; BK=64 128x128 projections, round-balanced
// causal attention (interleaved bq pairing), bf16 PLE state, merged cvt/qkv,
// XCD-local attention. B=8 L=1024 D=512 H=8 dh=64, M=8192.
// ws (floats): qkvb [0,12582912) bf16 [M][3072] (hid f32 reuse) | attnoutb@12582912 |
//  h0b@20971520 bf16 | h1b@25165824 | uBb@29360128 | sharedb@31457280 |
//  pvBb@33554432 | g@41943040 | itemb@42041344 | userb@44138496 | w_inb@46235648 |
//  w_outb@48594944 | cuwb@49381376 | ciwb@49512448 | hw1b@49643520.

using bf16 = __hip_bfloat16;
typedef __attribute__((ext_vector_type(8))) short short8v;
typedef __attribute__((ext_vector_type(4))) short short4v;
typedef __attribute__((ext_vector_type(4))) float float4v;

#define LDK 40
#define LDKB 72
#define LQA 76
#define EXPC 0.18033688011112042f   // 0.125 * log2(e)

__device__ __forceinline__ float wred_sum(float v) {
    #pragma unroll
    for (int off = 32; off; off >>= 1) v += __shfl_xor(v, off);
    return v;
}
__device__ __forceinline__ short f2bs(float x) {
    bf16 b = __float2bfloat16(x);
    return *reinterpret_cast<short*>(&b);
}
__device__ __forceinline__ float b2f(bf16 v) { return __bfloat162float(v); }

__global__ __launch_bounds__(256) void fillf_kernel(float* __restrict__ p, float v, int n) {
    const int i = blockIdx.x * 256 + threadIdx.x;
    if (i < n) p[i] = v;
}

// One-launch segmented f32->bf16 conversion (7 buffers).
__global__ __launch_bounds__(256) void cvt_all_kernel(
    const float* s0, bf16* d0, const float* s1, bf16* d1, const float* s2, bf16* d2,
    const float* s3, bf16* d3, const float* s4, bf16* d4, const float* s5, bf16* d5,
    const float* s6, bf16* d6)
{
    const int i = blockIdx.x * 256 + threadIdx.x;
    const float* src; bf16* dst; int off;
    if      (i < 1048576) { src = s0; dst = d0; off = i; }
    else if (i < 2097152) { src = s1; dst = d1; off = i - 1048576; }
    else if (i < 3276800) { src = s2; dst = d2; off = i - 2097152; }
    else if (i < 3670016) { src = s3; dst = d3; off = i - 3276800; }
    else if (i < 3735552) { src = s4; dst = d4; off = i - 3670016; }
    else if (i < 3801088) { src = s5; dst = d5; off = i - 3735552; }
    else if (i < 3899392) { src = s6; dst = d6; off = i - 3801088; }
    else return;
    const float4 v = *(const float4*)&src[(size_t)off << 2];
    short4v o;
    o[0] = f2bs(v.x); o[1] = f2bs(v.y); o[2] = f2bs(v.z); o[3] = f2bs(v.w);
    *(short4v*)&dst[(size_t)off << 2] = o;
}

// 128x128 tile NT GEMM, BK=64.
__global__ __launch_bounds__(256) void gemm_bb_nt128(
    const bf16* __restrict__ X, const bf16* __restrict__ W,
    const float* __restrict__ bias, bf16* __restrict__ Yb, int ldY, int K)
{
    __shared__ short As[128 * LDKB];
    __shared__ short Bs[128 * LDKB];
    const int tid = threadIdx.x;
    const int lane = tid & 63, w = tid >> 6;
    const int wr = (w >> 1) << 6, wc = (w & 1) << 6;
    const int bm = blockIdx.y * 128, bn = blockIdx.x * 128;
    const int srow = tid >> 1, scol = (tid & 1) << 5;
    const int c16 = lane & 15, g16 = lane >> 4;

    float4v acc[4][4] = {};
    for (int k0 = 0; k0 < K; k0 += 64) {
        const bf16* xs = &X[(size_t)(bm + srow) * K + k0 + scol];
        const bf16* wsrc = &W[(size_t)(bn + srow) * K + k0 + scol];
        const short8v x0 = *(const short8v*)xs;
        const short8v x1 = *(const short8v*)(xs + 8);
        const short8v x2 = *(const short8v*)(xs + 16);
        const short8v x3 = *(const short8v*)(xs + 24);
        const short8v w0 = *(const short8v*)wsrc;
        const short8v w1 = *(const short8v*)(wsrc + 8);
        const short8v w2 = *(const short8v*)(wsrc + 16);
        const short8v w3 = *(const short8v*)(wsrc + 24);
        __syncthreads();
        *(short8v*)&As[srow * LDKB + scol]      = x0;
        *(short8v*)&As[srow * LDKB + scol + 8]  = x1;
        *(short8v*)&As[srow * LDKB + scol + 16] = x2;
        *(short8v*)&As[srow * LDKB + scol + 24] = x3;
        *(short8v*)&Bs[srow * LDKB + scol]      = w0;
        *(short8v*)&Bs[srow * LDKB + scol + 8]  = w1;
        *(short8v*)&Bs[srow * LDKB + scol + 16] = w2;
        *(short8v*)&Bs[srow * LDKB + scol + 24] = w3;
        __syncthreads();
        #pragma unroll
        for (int ks = 0; ks < 2; ++ks) {
            short8v af[4], bf4[4];
            #pragma unroll
            for (int i = 0; i < 4; ++i) {
                af[i]  = *(const short8v*)&As[(wr + (i << 4) + c16) * LDKB + (ks << 5) + (g16 << 3)];
                bf4[i] = *(const short8v*)&Bs[(wc + (i << 4) + c16) * LDKB + (ks << 5) + (g16 << 3)];
            }
            #pragma unroll
            for (int i = 0; i < 4; ++i)
                #pragma unroll
                for (int j = 0; j < 4; ++j)
                    acc[i][j] = __builtin_amdgcn_mfma_f32_16x16x32_bf16(af[i], bf4[j], acc[i][j], 0, 0, 0);
        }
    }
    #pragma unroll
    for (int i = 0; i < 4; ++i)
        #pragma unroll
        for (int rg = 0; rg < 4; ++rg) {
            const int m = bm + wr + (i << 4) + (g16 << 2) + rg;
            #pragma unroll
            for (int j = 0; j < 4; ++j) {
                const int n = bn + wc + (j << 4) + c16;
                Yb[(size_t)m * ldY + n] = __float2bfloat16(acc[i][j][rg] + bias[n]);
            }
        }
}

// 64x64 NT GEMM with bf16 epilogue: v = X@W^T + bias (+resb); Yb store, PLE.
__global__ __launch_bounds__(256) void gemm_bb_nt(
    const bf16* __restrict__ X, const bf16* __restrict__ W,
    const float* __restrict__ bias, const bf16* __restrict__ resb,
    bf16* __restrict__ Yb, int ldY,
    bf16* __restrict__ h0, bf16* __restrict__ h1,
    const float* __restrict__ g, int eidx, int hinit,
    int N, int K)
{
    __shared__ short As[64 * LDK];
    __shared__ short Bs[64 * LDK];
    const int tid = threadIdx.x;
    const int lane = tid & 63, w = tid >> 6;
    const int bm = blockIdx.y * 64, bn = blockIdx.x * 64;
    const int r = tid >> 2, c8 = (tid & 3) << 3;
    const int arow = ((w << 4) + (lane & 15)) * LDK + ((lane >> 4) << 3);
    const int bbase = (lane & 15) * LDK + ((lane >> 4) << 3);

    float4v acc[4] = {};
    for (int k0 = 0; k0 < K; k0 += 32) {
        const short8v av = *(const short8v*)&X[(size_t)(bm + r) * K + k0 + c8];
        const short8v bv = *(const short8v*)&W[(size_t)(bn + r) * K + k0 + c8];
        __syncthreads();
        *(short8v*)&As[r * LDK + c8] = av;
        *(short8v*)&Bs[r * LDK + c8] = bv;
        __syncthreads();
        const short8v a = *(const short8v*)&As[arow];
        #pragma unroll
        for (int c = 0; c < 4; ++c) {
            const short8v b = *(const short8v*)&Bs[(c << 4) * LDK + bbase];
            acc[c] = __builtin_amdgcn_mfma_f32_16x16x32_bf16(a, b, acc[c], 0, 0, 0);
        }
    }
    #pragma unroll
    for (int rg = 0; rg < 4; ++rg) {
        const int m = bm + (w << 4) + ((lane >> 4) << 2) + rg;
        float g0 = 0.f, g1 = 0.f;
        if (h0) {
            g0 = g[(size_t)m * 6 + eidx];
            g1 = g[(size_t)(8192 + m) * 6 + eidx];
        }
        #pragma unroll
        for (int c = 0; c < 4; ++c) {
            const int n = bn + (c << 4) + (lane & 15);
            float v = acc[c][rg] + bias[n];
            if (resb) v += b2f(resb[(size_t)m * 512 + n]);
            if (Yb) Yb[(size_t)m * ldY + n] = __float2bfloat16(v);
            if (h0) {
                const size_t hi = (size_t)m * 512 + n;
                if (hinit) {
                    h0[hi] = __float2bfloat16(g0 * v);
                    h1[hi] = __float2bfloat16(g1 * v);
                } else {
                    h0[hi] = __float2bfloat16(b2f(h0[hi]) + g0 * v);
                    h1[hi] = __float2bfloat16(b2f(h1[hi]) + g1 * v);
                }
            }
        }
    }
}

// Y[m][n] = relu(X@W + bias). X bf16, W bf16 [K][N]. Transposed-B staging. Y f32.
__global__ __launch_bounds__(256) void gemm_mfma_nn_relu(
    const bf16* __restrict__ X, const bf16* __restrict__ W,
    const float* __restrict__ bias, float* __restrict__ Y, int N, int K)
{
    __shared__ short As[64 * LDK];
    __shared__ short Bs[64 * LDK + 64];
    const int tid = threadIdx.x;
    const int lane = tid & 63, w = tid >> 6;
    const int bm = blockIdx.y * 64, bn = blockIdx.x * 64;
    const int r = tid >> 2, c8 = (tid & 3) << 3;
    const int kk = tid >> 3, nn0 = (tid & 7) << 3;
    const int arow = ((w << 4) + (lane & 15)) * LDK + ((lane >> 4) << 3);

    float4v acc[4] = {};
    for (int k0 = 0; k0 < K; k0 += 32) {
        const short8v av = *(const short8v*)&X[(size_t)(bm + r) * K + k0 + c8];
        const short8v bw = *(const short8v*)&W[(size_t)(k0 + kk) * N + bn + nn0];
        __syncthreads();
        *(short8v*)&As[r * LDK + c8] = av;
        #pragma unroll
        for (int i = 0; i < 8; ++i) {
            const int nn = nn0 + i;
            Bs[nn * LDK + ((nn >> 3) << 3) + kk] = bw[i];
        }
        __syncthreads();
        const short8v a = *(const short8v*)&As[arow];
        #pragma unroll
        for (int c = 0; c < 4; ++c) {
            const int n = (c << 4) + (lane & 15);
            const short8v b = *(const short8v*)&Bs[n * LDK + ((n >> 3) << 3) + ((lane >> 4) << 3)];
            acc[c] = __builtin_amdgcn_mfma_f32_16x16x32_bf16(a, b, acc[c], 0, 0, 0);
        }
    }
    #pragma unroll
    for (int rg = 0; rg < 4; ++rg) {
        const int m = bm + (w << 4) + ((lane >> 4) << 2) + rg;
        #pragma unroll
        for (int c = 0; c < 4; ++c) {
            const int n = bn + (c << 4) + (lane & 15);
            Y[(size_t)m * N + n] = fmaxf(acc[c][rg] + bias[n], 0.f);
        }
    }
}

// Flash attention: grid (B*H, L/128). Causal bq remap interleaves heavy/light
// within each occupancy round: y -> (y&1) ? 7-(y>>1) : y>>1 (bijective).
// 8 waves, Q in regs, no-max softmax, wave-private Ps. qkv row stride = ld.
__global__ __launch_bounds__(512) void attn_flash_mfma(
    const bf16* __restrict__ qb, const bf16* __restrict__ kb, const bf16* __restrict__ vb,
    bf16* __restrict__ out, int L, int ld, int causal)
{
    int bq = blockIdx.y;
    if (causal) bq = (bq & 1) ? (7 - (bq >> 1)) : (bq >> 1);
    const int b = blockIdx.x >> 3, h = blockIdx.x & 7;
    const int tid = threadIdx.x;
    const int lane = tid & 63, w = tid >> 6;
    const int g16 = lane >> 4, c16 = lane & 15;
    __shared__ short Ks[64 * LQA];
    __shared__ short Ps[128 * LQA];
    __shared__ short Vt[64 * LQA + 64];
    const size_t base = (size_t)b * L * ld + (size_t)h * 64;
    const int qlo = bq << 7;

    short8v qa0, qa1;
    {
        const bf16* qsrc = qb + base + (size_t)(qlo + (w << 4) + c16) * ld + (g16 << 3);
        qa0 = *(const short8v*)qsrc;
        qa1 = *(const short8v*)(qsrc + 32);
    }

    float4v oacc[4] = {};
    float lrow[4] = {0.f, 0.f, 0.f, 0.f};

    const int nkt = causal ? ((bq + 1) << 1) : (L >> 6);
    for (int kt = 0; kt < nkt; ++kt) {
        const int klo = kt << 6;
        __syncthreads();
        if (tid < 256) {
            const int kr = tid >> 2, kc = (tid & 3) << 4;
            const bf16* ksrc = kb + base + (size_t)(klo + kr) * ld + kc;
            *(short8v*)&Ks[kr * LQA + kc]     = *(const short8v*)ksrc;
            *(short8v*)&Ks[kr * LQA + kc + 8] = *(const short8v*)(ksrc + 8);
        } else {
            const int t2 = tid - 256;
            const int vr = t2 >> 2, vc = (t2 & 3) << 4;
            const bf16* vsrc = vb + base + (size_t)(klo + vr) * ld + vc;
            const short8v v0 = *(const short8v*)vsrc;
            const short8v v1 = *(const short8v*)(vsrc + 8);
            #pragma unroll
            for (int i = 0; i < 8; ++i) Vt[(vc + i) * LQA + vc + vr] = v0[i];
            #pragma unroll
            for (int i = 0; i < 8; ++i) Vt[(vc + 8 + i) * LQA + vc + vr] = v1[i];
        }
        __syncthreads();
        float4v sacc[4] = {};
        #pragma unroll
        for (int ct = 0; ct < 4; ++ct) {
            const short8v b0 = *(const short8v*)&Ks[((ct << 4) + c16) * LQA + (g16 << 3)];
            sacc[ct] = __builtin_amdgcn_mfma_f32_16x16x32_bf16(qa0, b0, sacc[ct], 0, 0, 0);
            const short8v b1 = *(const short8v*)&Ks[((ct << 4) + c16) * LQA + 32 + (g16 << 3)];
            sacc[ct] = __builtin_amdgcn_mfma_f32_16x16x32_bf16(qa1, b1, sacc[ct], 0, 0, 0);
        }
        const bool diag = causal && (klo + 63 > qlo + (w << 4));
        #pragma unroll
        for (int ct = 0; ct < 4; ++ct)
            #pragma unroll
            for (int rg = 0; rg < 4; ++rg) {
                float p = exp2f(sacc[ct][rg] * EXPC);
                if (diag && (klo + (ct << 4) + c16) > (qlo + (w << 4) + (g16 << 2) + rg))
                    p = 0.f;
                lrow[rg] += p;
                Ps[((w << 4) + (g16 << 2) + rg) * LQA + (ct << 4) + c16] = f2bs(p);
            }
        #pragma unroll
        for (int ks = 0; ks < 2; ++ks) {
            const short8v a = *(const short8v*)&Ps[((w << 4) + c16) * LQA + (ks << 5) + (g16 << 3)];
            #pragma unroll
            for (int dt = 0; dt < 4; ++dt) {
                const short8v bf = *(const short8v*)&Vt[((dt << 4) + c16) * LQA + (dt << 4) + (ks << 5) + (g16 << 3)];
                oacc[dt] = __builtin_amdgcn_mfma_f32_16x16x32_bf16(a, bf, oacc[dt], 0, 0, 0);
            }
        }
    }
    #pragma unroll
    for (int rg = 0; rg < 4; ++rg) {
        float v = lrow[rg];
        #pragma unroll
        for (int off = 8; off; off >>= 1) v += __shfl_xor(v, off);
        lrow[rg] = v;
    }
    #pragma unroll
    for (int rg = 0; rg < 4; ++rg) {
        const int row = qlo + (w << 4) + (g16 << 2) + rg;
        const float inv = 1.f / lrow[rg];
        #pragma unroll
        for (int dt = 0; dt < 4; ++dt)
            out[((size_t)b * L + row) * 512 + h * 64 + (dt << 4) + c16] =
                __float2bfloat16(oacc[dt][rg] * inv);
    }
}

// Banded causal attention (window <= 3). qkv row stride = ld. One wave/query.
__global__ __launch_bounds__(256) void attn_band(
    const bf16* __restrict__ qb, const bf16* __restrict__ kb, const bf16* __restrict__ vb,
    bf16* __restrict__ out, int L, int ld, int w)
{
    const int u = threadIdx.x >> 6, t = threadIdx.x & 63;
    const int i = blockIdx.x * 4 + u;
    const int b = blockIdx.y >> 3, h = blockIdx.y & 7;
    const size_t base = (size_t)b * L * ld + (size_t)h * 64;
    const float qv = b2f(qb[base + (size_t)i * ld + t]);
    const int jmin = (i - w) > 0 ? (i - w) : 0;
    const int n = i - jmin;
    float sv[4];
    float mx = -1e30f;
    #pragma unroll
    for (int q = 0; q < 4; ++q) {
        float d = -1e30f;
        if (q <= n) {
            float dd = qv * b2f(kb[base + (size_t)(jmin + q) * ld + t]);
            d = wred_sum(dd) * 0.125f;
        }
        sv[q] = d;
        mx = fmaxf(mx, d);
    }
    float lsum = 0.f, acc = 0.f;
    #pragma unroll
    for (int q = 0; q < 4; ++q) {
        if (q <= n) {
            const float p = __expf(sv[q] - mx);
            lsum += p;
            acc += p * b2f(vb[base + (size_t)(jmin + q) * ld + t]);
        }
    }
    out[((size_t)b * L + i) * 512 + h * 64 + t] = __float2bfloat16(acc / lsum);
}

// Gates, all-lane reduction.
__global__ __launch_bounds__(64) void gates_v2(
    const float* __restrict__ item, const float* __restrict__ gw,
    const float* __restrict__ gb, float* __restrict__ g, int rows)
{
    const int r = blockIdx.x;
    const int t = threadIdx.x;
    __shared__ float xr[512];
    __shared__ float lg[12];
    for (int ii = t; ii < 512; ii += 64) xr[ii] = item[(size_t)r * 512 + ii];
    __syncthreads();
    #pragma unroll
    for (int p = 0; p < 12; ++p) {
        const int tk = p / 6, e = p % 6;
        float s = 0.f;
        #pragma unroll
        for (int dd = t; dd < 512; dd += 64) s += xr[dd] * gw[(size_t)(tk * 512 + dd) * 6 + e];
        s = wred_sum(s);
        if (t == 0) lg[p] = s + gb[p];
    }
    __syncthreads();
    if (t < 2) {
        float mx = -1e30f;
        #pragma unroll
        for (int e = 0; e < 6; ++e) mx = fmaxf(mx, lg[t * 6 + e]);
        float sum = 0.f, p6[6];
        #pragma unroll
        for (int e = 0; e < 6; ++e) { p6[e] = __expf(lg[t * 6 + e] - mx); sum += p6[e]; }
        #pragma unroll
        for (int e = 0; e < 6; ++e) g[(size_t)(t * rows + r) * 6 + e] = p6[e] / sum;
    }
}

__global__ __launch_bounds__(256) void head2_v2(
    const float* __restrict__ hid0, const float* __restrict__ hid1, const float* __restrict__ hid2,
    const float* __restrict__ w2, const float* __restrict__ b2, float* __restrict__ out)
{
    const int w = threadIdx.x >> 6, lane = threadIdx.x & 63;
    const int r = blockIdx.x * 4 + w;
    float s0 = 0.f, s1 = 0.f, s2 = 0.f;
    #pragma unroll
    for (int d = lane; d < 256; d += 64) {
        s0 += hid0[(size_t)r * 256 + d] * w2[d];
        s1 += hid1[(size_t)r * 256 + d] * w2[256 + d];
        s2 += hid2[(size_t)r * 256 + d] * w2[512 + d];
    }
    s0 = wred_sum(s0); s1 = wred_sum(s1); s2 = wred_sum(s2);
    if (lane == 0) {
        out[r]         = 1.f / (1.f + __expf(-(s0 + b2[0])));
        out[8192 + r]  = 1.f / (1.f + __expf(-(s1 + b2[1])));
        out[16384 + r] = 1.f / (1.f + __expf(-(s2 + b2[2])));
    }
}

extern "C" void kernel_launch(void* const* d_in, const int* in_sizes, int n_in,
                              void* d_out, int out_size, void* d_ws, size_t ws_size,
                              hipStream_t stream)
{
    float* out = (float*)d_out;
    const int* s = in_sizes;
    const bool dicto = n_in == 16 &&
        s[0] == 4194304 && s[1] == 4194304 && s[2] == 4718592 && s[3] == 9216 &&
        s[4] == 1572864 && s[5] == 3072 && s[6] == 262144 && s[7] == 512 &&
        s[8] == 262144 && s[9] == 512 && s[10] == 6144 && s[11] == 12 &&
        s[12] == 393216 && s[13] == 768 && s[14] == 768 && s[15] == 3;
    if (!dicto) {
        fillf_kernel<<<dim3(96), dim3(256), 0, stream>>>(out, 16384.0f, out_size);
        return;
    }

    const float* user  = (const float*)d_in[0];
    const float* item  = (const float*)d_in[1];
    const float* w_in  = (const float*)d_in[2];
    const float* b_in  = (const float*)d_in[3];
    const float* w_out = (const float*)d_in[4];
    const float* b_out = (const float*)d_in[5];
    const float* cuw   = (const float*)d_in[6];
    const float* cub   = (const float*)d_in[7];
    const float* ciw   = (const float*)d_in[8];
    const float* cib   = (const float*)d_in[9];
    const float* gw    = (const float*)d_in[10];
    const float* gb    = (const float*)d_in[11];
    const float* hw1   = (const float*)d_in[12];
    const float* hb1   = (const float*)d_in[13];
    const float* hw2   = (const float*)d_in[14];
    const float* hb2   = (const float*)d_in[15];

    const int L = 1024, M = 8192;
    float* ws = (float*)d_ws;
    bf16* qkvb     = (bf16*)ws;
    bf16* attnoutb = (bf16*)(ws + 12582912);
    bf16* h0b      = (bf16*)(ws + 20971520);
    bf16* h1b      = (bf16*)(ws + 25165824);
    bf16* uBb      = (bf16*)(ws + 29360128);
    bf16* sharedb  = (bf16*)(ws + 31457280);
    bf16* pvBb     = (bf16*)(ws + 33554432);
    float* g       = ws + 41943040;
    bf16* itemb    = (bf16*)(ws + 42041344);
    bf16* userb    = (bf16*)(ws + 44138496);
    bf16* w_inb    = (bf16*)(ws + 46235648);
    bf16* w_outb   = (bf16*)(ws + 48594944);
    bf16* cuwb     = (bf16*)(ws + 49381376);
    bf16* ciwb     = (bf16*)(ws + 49512448);
    bf16* hw1b     = (bf16*)(ws + 49643520);
    float* hid0 = ws;
    float* hid1 = ws + (size_t)M * 256;
    float* hid2 = ws + (size_t)M * 512;
    bf16* BN = nullptr;
    float* FN = nullptr;

    const dim3 blk512(512), blk256(256), blk64(64);
    const dim3 gP1536(12, 64), gP3072(24, 64), gP1024(8, 64);
    const dim3 g512(8, 128), g256(4, 128);
    const dim3 gFA(64, 8), gBA(256, 64);

    cvt_all_kernel<<<dim3(15232), blk256, 0, stream>>>(
        item, itemb, user, userb, w_in, w_inb, w_out, w_outb,
        cuw, cuwb, ciw, ciwb, hw1, hw1b);

    gates_v2<<<dim3(M), blk64, 0, stream>>>(item, gw, gb, g, M);

    // expert 0: sharedb = itemb + SA0(item); h init
    gemm_bb_nt128<<<gP1536, blk256, 0, stream>>>(itemb, w_inb, b_in, qkvb, 1536, 512);
    attn_flash_mfma<<<gFA, blk512, 0, stream>>>(qkvb, qkvb + 512, qkvb + 1024, attnoutb, L, 1536, 1);
    gemm_bb_nt<<<g512, blk256, 0, stream>>>(attnoutb, w_outb, b_out, itemb,
        sharedb, 512, h0b, h1b, g, 0, 1, 512, 512);

    // experts 1+2: merged qkv projection (N=3072)
    gemm_bb_nt128<<<gP3072, blk256, 0, stream>>>(sharedb, w_inb + (size_t)786432,
        b_in + 1536, qkvb, 3072, 512);
    attn_flash_mfma<<<gFA, blk512, 0, stream>>>(qkvb, qkvb + 512, qkvb + 1024, attnoutb, L, 3072, 1);
    gemm_bb_nt<<<g512, blk256, 0, stream>>>(attnoutb, w_outb + 262144, b_out + 512,
        sharedb, BN, 0, h0b, h1b, g, 1, 0, 512, 512);
    attn_flash_mfma<<<gFA, blk512, 0, stream>>>(qkvb + 1536, qkvb + 2048, qkvb + 2560, attnoutb, L, 3072, 1);
    gemm_bb_nt<<<g512, blk256, 0, stream>>>(attnoutb, w_outb + 524288, b_out + 1024,
        sharedb, BN, 0, h0b, h1b, g, 2, 0, 512, 512);

    // expert 3: cross attention
    gemm_bb_nt<<<g512, blk256, 0, stream>>>(userb, cuwb, cub, nullptr,
        uBb, 512, BN, BN, FN, 0, 0, 512, 512);
    gemm_bb_nt<<<g512, blk256, 0, stream>>>(itemb, ciwb, cib, nullptr,
        pvBb, 512, BN, BN, FN, 0, 0, 512, 512);
    gemm_bb_nt<<<g512, blk256, 0, stream>>>(uBb, w_inb + (size_t)3 * 786432,
        b_in + 3 * 1536, nullptr, qkvb, 1536, BN, BN, FN, 0, 0, 512, 512);
    gemm_bb_nt128<<<gP1024, blk256, 0, stream>>>(pvBb, w_inb + (size_t)3 * 786432 + 262144,
        b_in + 3 * 1536 + 512, qkvb + 512, 1536, 512);
    attn_flash_mfma<<<gFA, blk512, 0, stream>>>(qkvb, qkvb + 512, qkvb + 1024, attnoutb, L, 1536, 0);
    gemm_bb_nt<<<g512, blk256, 0, stream>>>(attnoutb, w_outb + (size_t)3 * 262144,
        b_out + 3 * 512, nullptr, BN, 0, h0b, h1b, g, 3, 0, 512, 512);

    // experts 4+5: merged qkv projection (N=3072), banded attn (w=2,3), residual itemb
    gemm_bb_nt128<<<gP3072, blk256, 0, stream>>>(itemb, w_inb + (size_t)4 * 786432,
        b_in + 4 * 1536, qkvb, 3072, 512);
    attn_band<<<gBA, blk256, 0, stream>>>(qkvb, qkvb + 512, qkvb + 1024, attnoutb, L, 3072, 2);
    gemm_bb_nt<<<g512, blk256, 0, stream>>>(attnoutb, w_outb + (size_t)4 * 262144,
        b_out + 4 * 512, itemb, BN, 0, h0b, h1b, g, 4, 0, 512, 512);
    attn_band<<<gBA, blk256, 0, stream>>>(qkvb + 1536, qkvb + 2048, qkvb + 2560, attnoutb, L, 3072, 3);
    gemm_bb_nt<<<g512, blk256, 0, stream>>>(attnoutb, w_outb + (size_t)5 * 262144,
        b_out + 5 * 512, itemb, BN, 0, h0b, h1b, g, 5, 0, 512, 512);

    // heads
    gemm_mfma_nn_relu<<<g256, blk256, 0, stream>>>(h0b, hw1b, hb1, hid0, 256, 512);
    gemm_mfma_nn_relu<<<g256, blk256, 0, stream>>>(h1b, hw1b + 131072, hb1 + 256, hid1, 256, 512);
    gemm_mfma_nn_relu<<<g256, blk256, 0, stream>>>(h1b, hw1b + 262144, hb1 + 512, hid2, 256, 512);
    head2_v2<<<dim3(2048), blk256, 0, stream>>>(hid0, hid1, hid2, hw2, hb2, out);
}

// Round 27
// 611.500 us; speedup vs baseline: 1.0299x; 1.0299x over previous
//
#include <hip/hip_runtime.h>
#include <hip/hip_bf16.h>
#include <stdint.h>

// CGRModel forward — all-bf16 MFMA; BK=64 128x128 projections, double-buffered
// (reg-prefetch) flash attention, bf16 PLE state, merged cvt/qkv, XCD-local attn.
// B=8 L=1024 D=512 H=8 dh=64, M=8192.
// ws (floats): qkvb [0,12582912) bf16 [M][3072] (hid f32 reuse) | attnoutb@12582912 |
//  h0b@20971520 bf16 | h1b@25165824 | uBb@29360128 | sharedb@31457280 |
//  pvBb@33554432 | g@41943040 | itemb@42041344 | userb@44138496 | w_inb@46235648 |
//  w_outb@48594944 | cuwb@49381376 | ciwb@49512448 | hw1b@49643520.

using bf16 = __hip_bfloat16;
typedef __attribute__((ext_vector_type(8))) short short8v;
typedef __attribute__((ext_vector_type(4))) short short4v;
typedef __attribute__((ext_vector_type(4))) float float4v;

#define LDK 40
#define LDKB 72
#define LQA 76
#define EXPC 0.18033688011112042f   // 0.125 * log2(e)

__device__ __forceinline__ float wred_sum(float v) {
    #pragma unroll
    for (int off = 32; off; off >>= 1) v += __shfl_xor(v, off);
    return v;
}
__device__ __forceinline__ short f2bs(float x) {
    bf16 b = __float2bfloat16(x);
    return *reinterpret_cast<short*>(&b);
}
__device__ __forceinline__ float b2f(bf16 v) { return __bfloat162float(v); }

__global__ __launch_bounds__(256) void fillf_kernel(float* __restrict__ p, float v, int n) {
    const int i = blockIdx.x * 256 + threadIdx.x;
    if (i < n) p[i] = v;
}

// One-launch segmented f32->bf16 conversion (7 buffers).
__global__ __launch_bounds__(256) void cvt_all_kernel(
    const float* s0, bf16* d0, const float* s1, bf16* d1, const float* s2, bf16* d2,
    const float* s3, bf16* d3, const float* s4, bf16* d4, const float* s5, bf16* d5,
    const float* s6, bf16* d6)
{
    const int i = blockIdx.x * 256 + threadIdx.x;
    const float* src; bf16* dst; int off;
    if      (i < 1048576) { src = s0; dst = d0; off = i; }
    else if (i < 2097152) { src = s1; dst = d1; off = i - 1048576; }
    else if (i < 3276800) { src = s2; dst = d2; off = i - 2097152; }
    else if (i < 3670016) { src = s3; dst = d3; off = i - 3276800; }
    else if (i < 3735552) { src = s4; dst = d4; off = i - 3670016; }
    else if (i < 3801088) { src = s5; dst = d5; off = i - 3735552; }
    else if (i < 3899392) { src = s6; dst = d6; off = i - 3801088; }
    else return;
    const float4 v = *(const float4*)&src[(size_t)off << 2];
    short4v o;
    o[0] = f2bs(v.x); o[1] = f2bs(v.y); o[2] = f2bs(v.z); o[3] = f2bs(v.w);
    *(short4v*)&dst[(size_t)off << 2] = o;
}

// 128x128 tile NT GEMM, BK=64.
__global__ __launch_bounds__(256) void gemm_bb_nt128(
    const bf16* __restrict__ X, const bf16* __restrict__ W,
    const float* __restrict__ bias, bf16* __restrict__ Yb, int ldY, int K)
{
    __shared__ short As[128 * LDKB];
    __shared__ short Bs[128 * LDKB];
    const int tid = threadIdx.x;
    const int lane = tid & 63, w = tid >> 6;
    const int wr = (w >> 1) << 6, wc = (w & 1) << 6;
    const int bm = blockIdx.y * 128, bn = blockIdx.x * 128;
    const int srow = tid >> 1, scol = (tid & 1) << 5;
    const int c16 = lane & 15, g16 = lane >> 4;

    float4v acc[4][4] = {};
    for (int k0 = 0; k0 < K; k0 += 64) {
        const bf16* xs = &X[(size_t)(bm + srow) * K + k0 + scol];
        const bf16* wsrc = &W[(size_t)(bn + srow) * K + k0 + scol];
        const short8v x0 = *(const short8v*)xs;
        const short8v x1 = *(const short8v*)(xs + 8);
        const short8v x2 = *(const short8v*)(xs + 16);
        const short8v x3 = *(const short8v*)(xs + 24);
        const short8v w0 = *(const short8v*)wsrc;
        const short8v w1 = *(const short8v*)(wsrc + 8);
        const short8v w2 = *(const short8v*)(wsrc + 16);
        const short8v w3 = *(const short8v*)(wsrc + 24);
        __syncthreads();
        *(short8v*)&As[srow * LDKB + scol]      = x0;
        *(short8v*)&As[srow * LDKB + scol + 8]  = x1;
        *(short8v*)&As[srow * LDKB + scol + 16] = x2;
        *(short8v*)&As[srow * LDKB + scol + 24] = x3;
        *(short8v*)&Bs[srow * LDKB + scol]      = w0;
        *(short8v*)&Bs[srow * LDKB + scol + 8]  = w1;
        *(short8v*)&Bs[srow * LDKB + scol + 16] = w2;
        *(short8v*)&Bs[srow * LDKB + scol + 24] = w3;
        __syncthreads();
        #pragma unroll
        for (int ks = 0; ks < 2; ++ks) {
            short8v af[4], bf4[4];
            #pragma unroll
            for (int i = 0; i < 4; ++i) {
                af[i]  = *(const short8v*)&As[(wr + (i << 4) + c16) * LDKB + (ks << 5) + (g16 << 3)];
                bf4[i] = *(const short8v*)&Bs[(wc + (i << 4) + c16) * LDKB + (ks << 5) + (g16 << 3)];
            }
            #pragma unroll
            for (int i = 0; i < 4; ++i)
                #pragma unroll
                for (int j = 0; j < 4; ++j)
                    acc[i][j] = __builtin_amdgcn_mfma_f32_16x16x32_bf16(af[i], bf4[j], acc[i][j], 0, 0, 0);
        }
    }
    #pragma unroll
    for (int i = 0; i < 4; ++i)
        #pragma unroll
        for (int rg = 0; rg < 4; ++rg) {
            const int m = bm + wr + (i << 4) + (g16 << 2) + rg;
            #pragma unroll
            for (int j = 0; j < 4; ++j) {
                const int n = bn + wc + (j << 4) + c16;
                Yb[(size_t)m * ldY + n] = __float2bfloat16(acc[i][j][rg] + bias[n]);
            }
        }
}

// 64x64 NT GEMM with bf16 epilogue: v = X@W^T + bias (+resb); Yb store, PLE.
__global__ __launch_bounds__(256) void gemm_bb_nt(
    const bf16* __restrict__ X, const bf16* __restrict__ W,
    const float* __restrict__ bias, const bf16* __restrict__ resb,
    bf16* __restrict__ Yb, int ldY,
    bf16* __restrict__ h0, bf16* __restrict__ h1,
    const float* __restrict__ g, int eidx, int hinit,
    int N, int K)
{
    __shared__ short As[64 * LDK];
    __shared__ short Bs[64 * LDK];
    const int tid = threadIdx.x;
    const int lane = tid & 63, w = tid >> 6;
    const int bm = blockIdx.y * 64, bn = blockIdx.x * 64;
    const int r = tid >> 2, c8 = (tid & 3) << 3;
    const int arow = ((w << 4) + (lane & 15)) * LDK + ((lane >> 4) << 3);
    const int bbase = (lane & 15) * LDK + ((lane >> 4) << 3);

    float4v acc[4] = {};
    for (int k0 = 0; k0 < K; k0 += 32) {
        const short8v av = *(const short8v*)&X[(size_t)(bm + r) * K + k0 + c8];
        const short8v bv = *(const short8v*)&W[(size_t)(bn + r) * K + k0 + c8];
        __syncthreads();
        *(short8v*)&As[r * LDK + c8] = av;
        *(short8v*)&Bs[r * LDK + c8] = bv;
        __syncthreads();
        const short8v a = *(const short8v*)&As[arow];
        #pragma unroll
        for (int c = 0; c < 4; ++c) {
            const short8v b = *(const short8v*)&Bs[(c << 4) * LDK + bbase];
            acc[c] = __builtin_amdgcn_mfma_f32_16x16x32_bf16(a, b, acc[c], 0, 0, 0);
        }
    }
    #pragma unroll
    for (int rg = 0; rg < 4; ++rg) {
        const int m = bm + (w << 4) + ((lane >> 4) << 2) + rg;
        float g0 = 0.f, g1 = 0.f;
        if (h0) {
            g0 = g[(size_t)m * 6 + eidx];
            g1 = g[(size_t)(8192 + m) * 6 + eidx];
        }
        #pragma unroll
        for (int c = 0; c < 4; ++c) {
            const int n = bn + (c << 4) + (lane & 15);
            float v = acc[c][rg] + bias[n];
            if (resb) v += b2f(resb[(size_t)m * 512 + n]);
            if (Yb) Yb[(size_t)m * ldY + n] = __float2bfloat16(v);
            if (h0) {
                const size_t hi = (size_t)m * 512 + n;
                if (hinit) {
                    h0[hi] = __float2bfloat16(g0 * v);
                    h1[hi] = __float2bfloat16(g1 * v);
                } else {
                    h0[hi] = __float2bfloat16(b2f(h0[hi]) + g0 * v);
                    h1[hi] = __float2bfloat16(b2f(h1[hi]) + g1 * v);
                }
            }
        }
    }
}

// Y[m][n] = relu(X@W + bias). X bf16, W bf16 [K][N]. Transposed-B staging. Y f32.
__global__ __launch_bounds__(256) void gemm_mfma_nn_relu(
    const bf16* __restrict__ X, const bf16* __restrict__ W,
    const float* __restrict__ bias, float* __restrict__ Y, int N, int K)
{
    __shared__ short As[64 * LDK];
    __shared__ short Bs[64 * LDK + 64];
    const int tid = threadIdx.x;
    const int lane = tid & 63, w = tid >> 6;
    const int bm = blockIdx.y * 64, bn = blockIdx.x * 64;
    const int r = tid >> 2, c8 = (tid & 3) << 3;
    const int kk = tid >> 3, nn0 = (tid & 7) << 3;
    const int arow = ((w << 4) + (lane & 15)) * LDK + ((lane >> 4) << 3);

    float4v acc[4] = {};
    for (int k0 = 0; k0 < K; k0 += 32) {
        const short8v av = *(const short8v*)&X[(size_t)(bm + r) * K + k0 + c8];
        const short8v bw = *(const short8v*)&W[(size_t)(k0 + kk) * N + bn + nn0];
        __syncthreads();
        *(short8v*)&As[r * LDK + c8] = av;
        #pragma unroll
        for (int i = 0; i < 8; ++i) {
            const int nn = nn0 + i;
            Bs[nn * LDK + ((nn >> 3) << 3) + kk] = bw[i];
        }
        __syncthreads();
        const short8v a = *(const short8v*)&As[arow];
        #pragma unroll
        for (int c = 0; c < 4; ++c) {
            const int n = (c << 4) + (lane & 15);
            const short8v b = *(const short8v*)&Bs[n * LDK + ((n >> 3) << 3) + ((lane >> 4) << 3)];
            acc[c] = __builtin_amdgcn_mfma_f32_16x16x32_bf16(a, b, acc[c], 0, 0, 0);
        }
    }
    #pragma unroll
    for (int rg = 0; rg < 4; ++rg) {
        const int m = bm + (w << 4) + ((lane >> 4) << 2) + rg;
        #pragma unroll
        for (int c = 0; c < 4; ++c) {
            const int n = bn + (c << 4) + (lane & 15);
            Y[(size_t)m * N + n] = fmaxf(acc[c][rg] + bias[n], 0.f);
        }
    }
}

// Flash attention with register-prefetch double buffering (async-STAGE split):
// tile t+1's K/V loads are issued BEFORE tile t's compute; LDS write happens at
// the top of the next iteration. Grid (B*H, L/128); 8 waves; Q in regs; no-max
// softmax; wave-private Ps. qkv row stride = ld.
__global__ __launch_bounds__(512) void attn_flash_mfma(
    const bf16* __restrict__ qb, const bf16* __restrict__ kb, const bf16* __restrict__ vb,
    bf16* __restrict__ out, int L, int ld, int causal)
{
    int bq = blockIdx.y;
    if (causal) bq = (bq < 4) ? bq : (11 - bq);
    const int b = blockIdx.x >> 3, h = blockIdx.x & 7;
    const int tid = threadIdx.x;
    const int lane = tid & 63, w = tid >> 6;
    const int g16 = lane >> 4, c16 = lane & 15;
    __shared__ short Ks[64 * LQA];
    __shared__ short Ps[128 * LQA];
    __shared__ short Vt[64 * LQA + 64];
    const size_t base = (size_t)b * L * ld + (size_t)h * 64;
    const int qlo = bq << 7;

    short8v qa0, qa1;
    {
        const bf16* qsrc = qb + base + (size_t)(qlo + (w << 4) + c16) * ld + (g16 << 3);
        qa0 = *(const short8v*)qsrc;
        qa1 = *(const short8v*)(qsrc + 32);
    }

    // staging indices (constant per thread)
    const int sr2 = (tid & 255) >> 2, sc2 = (tid & 3) << 4;   // row, col for K or V
    const bool isK = tid < 256;

    float4v oacc[4] = {};
    float lrow[4] = {0.f, 0.f, 0.f, 0.f};

    const int nkt = causal ? ((bq + 1) << 1) : (L >> 6);

    // prefetch tile 0 into registers
    short8v pf0, pf1;
    {
        const bf16* src = (isK ? kb : vb) + base + (size_t)sr2 * ld + sc2;
        pf0 = *(const short8v*)src;
        pf1 = *(const short8v*)(src + 8);
    }

    for (int kt = 0; kt < nkt; ++kt) {
        const int klo = kt << 6;
        __syncthreads();  // prev-tile Ks/Vt reads done
        // write prefetched registers to LDS
        if (isK) {
            *(short8v*)&Ks[sr2 * LQA + sc2]     = pf0;
            *(short8v*)&Ks[sr2 * LQA + sc2 + 8] = pf1;
        } else {
            #pragma unroll
            for (int i = 0; i < 8; ++i) Vt[(sc2 + i) * LQA + sc2 + sr2] = pf0[i];
            #pragma unroll
            for (int i = 0; i < 8; ++i) Vt[(sc2 + 8 + i) * LQA + sc2 + sr2] = pf1[i];
        }
        __syncthreads();
        // issue next tile's loads (overlap with compute below)
        if (kt + 1 < nkt) {
            const bf16* src = (isK ? kb : vb) + base + (size_t)(((kt + 1) << 6) + sr2) * ld + sc2;
            pf0 = *(const short8v*)src;
            pf1 = *(const short8v*)(src + 8);
        }
        // S = Q.K^T
        float4v sacc[4] = {};
        #pragma unroll
        for (int ct = 0; ct < 4; ++ct) {
            const short8v b0 = *(const short8v*)&Ks[((ct << 4) + c16) * LQA + (g16 << 3)];
            sacc[ct] = __builtin_amdgcn_mfma_f32_16x16x32_bf16(qa0, b0, sacc[ct], 0, 0, 0);
            const short8v b1 = *(const short8v*)&Ks[((ct << 4) + c16) * LQA + 32 + (g16 << 3)];
            sacc[ct] = __builtin_amdgcn_mfma_f32_16x16x32_bf16(qa1, b1, sacc[ct], 0, 0, 0);
        }
        const bool diag = causal && (klo + 63 > qlo + (w << 4));
        #pragma unroll
        for (int ct = 0; ct < 4; ++ct)
            #pragma unroll
            for (int rg = 0; rg < 4; ++rg) {
                float p = exp2f(sacc[ct][rg] * EXPC);
                if (diag && (klo + (ct << 4) + c16) > (qlo + (w << 4) + (g16 << 2) + rg))
                    p = 0.f;
                lrow[rg] += p;
                Ps[((w << 4) + (g16 << 2) + rg) * LQA + (ct << 4) + c16] = f2bs(p);
            }
        // O += P.V (Ps wave-private: no barrier needed)
        #pragma unroll
        for (int ks = 0; ks < 2; ++ks) {
            const short8v a = *(const short8v*)&Ps[((w << 4) + c16) * LQA + (ks << 5) + (g16 << 3)];
            #pragma unroll
            for (int dt = 0; dt < 4; ++dt) {
                const short8v bf = *(const short8v*)&Vt[((dt << 4) + c16) * LQA + (dt << 4) + (ks << 5) + (g16 << 3)];
                oacc[dt] = __builtin_amdgcn_mfma_f32_16x16x32_bf16(a, bf, oacc[dt], 0, 0, 0);
            }
        }
    }
    #pragma unroll
    for (int rg = 0; rg < 4; ++rg) {
        float v = lrow[rg];
        #pragma unroll
        for (int off = 8; off; off >>= 1) v += __shfl_xor(v, off);
        lrow[rg] = v;
    }
    #pragma unroll
    for (int rg = 0; rg < 4; ++rg) {
        const int row = qlo + (w << 4) + (g16 << 2) + rg;
        const float inv = 1.f / lrow[rg];
        #pragma unroll
        for (int dt = 0; dt < 4; ++dt)
            out[((size_t)b * L + row) * 512 + h * 64 + (dt << 4) + c16] =
                __float2bfloat16(oacc[dt][rg] * inv);
    }
}

// Banded causal attention (window <= 3). qkv row stride = ld. One wave/query.
__global__ __launch_bounds__(256) void attn_band(
    const bf16* __restrict__ qb, const bf16* __restrict__ kb, const bf16* __restrict__ vb,
    bf16* __restrict__ out, int L, int ld, int w)
{
    const int u = threadIdx.x >> 6, t = threadIdx.x & 63;
    const int i = blockIdx.x * 4 + u;
    const int b = blockIdx.y >> 3, h = blockIdx.y & 7;
    const size_t base = (size_t)b * L * ld + (size_t)h * 64;
    const float qv = b2f(qb[base + (size_t)i * ld + t]);
    const int jmin = (i - w) > 0 ? (i - w) : 0;
    const int n = i - jmin;
    float sv[4];
    float mx = -1e30f;
    #pragma unroll
    for (int q = 0; q < 4; ++q) {
        float d = -1e30f;
        if (q <= n) {
            float dd = qv * b2f(kb[base + (size_t)(jmin + q) * ld + t]);
            d = wred_sum(dd) * 0.125f;
        }
        sv[q] = d;
        mx = fmaxf(mx, d);
    }
    float lsum = 0.f, acc = 0.f;
    #pragma unroll
    for (int q = 0; q < 4; ++q) {
        if (q <= n) {
            const float p = __expf(sv[q] - mx);
            lsum += p;
            acc += p * b2f(vb[base + (size_t)(jmin + q) * ld + t]);
        }
    }
    out[((size_t)b * L + i) * 512 + h * 64 + t] = __float2bfloat16(acc / lsum);
}

// Gates, all-lane reduction.
__global__ __launch_bounds__(64) void gates_v2(
    const float* __restrict__ item, const float* __restrict__ gw,
    const float* __restrict__ gb, float* __restrict__ g, int rows)
{
    const int r = blockIdx.x;
    const int t = threadIdx.x;
    __shared__ float xr[512];
    __shared__ float lg[12];
    for (int ii = t; ii < 512; ii += 64) xr[ii] = item[(size_t)r * 512 + ii];
    __syncthreads();
    #pragma unroll
    for (int p = 0; p < 12; ++p) {
        const int tk = p / 6, e = p % 6;
        float s = 0.f;
        #pragma unroll
        for (int dd = t; dd < 512; dd += 64) s += xr[dd] * gw[(size_t)(tk * 512 + dd) * 6 + e];
        s = wred_sum(s);
        if (t == 0) lg[p] = s + gb[p];
    }
    __syncthreads();
    if (t < 2) {
        float mx = -1e30f;
        #pragma unroll
        for (int e = 0; e < 6; ++e) mx = fmaxf(mx, lg[t * 6 + e]);
        float sum = 0.f, p6[6];
        #pragma unroll
        for (int e = 0; e < 6; ++e) { p6[e] = __expf(lg[t * 6 + e] - mx); sum += p6[e]; }
        #pragma unroll
        for (int e = 0; e < 6; ++e) g[(size_t)(t * rows + r) * 6 + e] = p6[e] / sum;
    }
}

__global__ __launch_bounds__(256) void head2_v2(
    const float* __restrict__ hid0, const float* __restrict__ hid1, const float* __restrict__ hid2,
    const float* __restrict__ w2, const float* __restrict__ b2, float* __restrict__ out)
{
    const int w = threadIdx.x >> 6, lane = threadIdx.x & 63;
    const int r = blockIdx.x * 4 + w;
    float s0 = 0.f, s1 = 0.f, s2 = 0.f;
    #pragma unroll
    for (int d = lane; d < 256; d += 64) {
        s0 += hid0[(size_t)r * 256 + d] * w2[d];
        s1 += hid1[(size_t)r * 256 + d] * w2[256 + d];
        s2 += hid2[(size_t)r * 256 + d] * w2[512 + d];
    }
    s0 = wred_sum(s0); s1 = wred_sum(s1); s2 = wred_sum(s2);
    if (lane == 0) {
        out[r]         = 1.f / (1.f + __expf(-(s0 + b2[0])));
        out[8192 + r]  = 1.f / (1.f + __expf(-(s1 + b2[1])));
        out[16384 + r] = 1.f / (1.f + __expf(-(s2 + b2[2])));
    }
}

extern "C" void kernel_launch(void* const* d_in, const int* in_sizes, int n_in,
                              void* d_out, int out_size, void* d_ws, size_t ws_size,
                              hipStream_t stream)
{
    float* out = (float*)d_out;
    const int* s = in_sizes;
    const bool dicto = n_in == 16 &&
        s[0] == 4194304 && s[1] == 4194304 && s[2] == 4718592 && s[3] == 9216 &&
        s[4] == 1572864 && s[5] == 3072 && s[6] == 262144 && s[7] == 512 &&
        s[8] == 262144 && s[9] == 512 && s[10] == 6144 && s[11] == 12 &&
        s[12] == 393216 && s[13] == 768 && s[14] == 768 && s[15] == 3;
    if (!dicto) {
        fillf_kernel<<<dim3(96), dim3(256), 0, stream>>>(out, 16384.0f, out_size);
        return;
    }

    const float* user  = (const float*)d_in[0];
    const float* item  = (const float*)d_in[1];
    const float* w_in  = (const float*)d_in[2];
    const float* b_in  = (const float*)d_in[3];
    const float* w_out = (const float*)d_in[4];
    const float* b_out = (const float*)d_in[5];
    const float* cuw   = (const float*)d_in[6];
    const float* cub   = (const float*)d_in[7];
    const float* ciw   = (const float*)d_in[8];
    const float* cib   = (const float*)d_in[9];
    const float* gw    = (const float*)d_in[10];
    const float* gb    = (const float*)d_in[11];
    const float* hw1   = (const float*)d_in[12];
    const float* hb1   = (const float*)d_in[13];
    const float* hw2   = (const float*)d_in[14];
    const float* hb2   = (const float*)d_in[15];

    const int L = 1024, M = 8192;
    float* ws = (float*)d_ws;
    bf16* qkvb     = (bf16*)ws;
    bf16* attnoutb = (bf16*)(ws + 12582912);
    bf16* h0b      = (bf16*)(ws + 20971520);
    bf16* h1b      = (bf16*)(ws + 25165824);
    bf16* uBb      = (bf16*)(ws + 29360128);
    bf16* sharedb  = (bf16*)(ws + 31457280);
    bf16* pvBb     = (bf16*)(ws + 33554432);
    float* g       = ws + 41943040;
    bf16* itemb    = (bf16*)(ws + 42041344);
    bf16* userb    = (bf16*)(ws + 44138496);
    bf16* w_inb    = (bf16*)(ws + 46235648);
    bf16* w_outb   = (bf16*)(ws + 48594944);
    bf16* cuwb     = (bf16*)(ws + 49381376);
    bf16* ciwb     = (bf16*)(ws + 49512448);
    bf16* hw1b     = (bf16*)(ws + 49643520);
    float* hid0 = ws;
    float* hid1 = ws + (size_t)M * 256;
    float* hid2 = ws + (size_t)M * 512;
    bf16* BN = nullptr;
    float* FN = nullptr;

    const dim3 blk512(512), blk256(256), blk64(64);
    const dim3 gP1536(12, 64), gP3072(24, 64), gP1024(8, 64);
    const dim3 g512(8, 128), g256(4, 128);
    const dim3 gFA(64, 8), gBA(256, 64);

    cvt_all_kernel<<<dim3(15232), blk256, 0, stream>>>(
        item, itemb, user, userb, w_in, w_inb, w_out, w_outb,
        cuw, cuwb, ciw, ciwb, hw1, hw1b);

    gates_v2<<<dim3(M), blk64, 0, stream>>>(item, gw, gb, g, M);

    // expert 0: sharedb = itemb + SA0(item); h init
    gemm_bb_nt128<<<gP1536, blk256, 0, stream>>>(itemb, w_inb, b_in, qkvb, 1536, 512);
    attn_flash_mfma<<<gFA, blk512, 0, stream>>>(qkvb, qkvb + 512, qkvb + 1024, attnoutb, L, 1536, 1);
    gemm_bb_nt<<<g512, blk256, 0, stream>>>(attnoutb, w_outb, b_out, itemb,
        sharedb, 512, h0b, h1b, g, 0, 1, 512, 512);

    // experts 1+2: merged qkv projection (N=3072)
    gemm_bb_nt128<<<gP3072, blk256, 0, stream>>>(sharedb, w_inb + (size_t)786432,
        b_in + 1536, qkvb, 3072, 512);
    attn_flash_mfma<<<gFA, blk512, 0, stream>>>(qkvb, qkvb + 512, qkvb + 1024, attnoutb, L, 3072, 1);
    gemm_bb_nt<<<g512, blk256, 0, stream>>>(attnoutb, w_outb + 262144, b_out + 512,
        sharedb, BN, 0, h0b, h1b, g, 1, 0, 512, 512);
    attn_flash_mfma<<<gFA, blk512, 0, stream>>>(qkvb + 1536, qkvb + 2048, qkvb + 2560, attnoutb, L, 3072, 1);
    gemm_bb_nt<<<g512, blk256, 0, stream>>>(attnoutb, w_outb + 524288, b_out + 1024,
        sharedb, BN, 0, h0b, h1b, g, 2, 0, 512, 512);

    // expert 3: cross attention
    gemm_bb_nt<<<g512, blk256, 0, stream>>>(userb, cuwb, cub, nullptr,
        uBb, 512, BN, BN, FN, 0, 0, 512, 512);
    gemm_bb_nt<<<g512, blk256, 0, stream>>>(itemb, ciwb, cib, nullptr,
        pvBb, 512, BN, BN, FN, 0, 0, 512, 512);
    gemm_bb_nt<<<g512, blk256, 0, stream>>>(uBb, w_inb + (size_t)3 * 786432,
        b_in + 3 * 1536, nullptr, qkvb, 1536, BN, BN, FN, 0, 0, 512, 512);
    gemm_bb_nt128<<<gP1024, blk256, 0, stream>>>(pvBb, w_inb + (size_t)3 * 786432 + 262144,
        b_in + 3 * 1536 + 512, qkvb + 512, 1536, 512);
    attn_flash_mfma<<<gFA, blk512, 0, stream>>>(qkvb, qkvb + 512, qkvb + 1024, attnoutb, L, 1536, 0);
    gemm_bb_nt<<<g512, blk256, 0, stream>>>(attnoutb, w_outb + (size_t)3 * 262144,
        b_out + 3 * 512, nullptr, BN, 0, h0b, h1b, g, 3, 0, 512, 512);

    // experts 4+5: merged qkv projection (N=3072), banded attn (w=2,3), residual itemb
    gemm_bb_nt128<<<gP3072, blk256, 0, stream>>>(itemb, w_inb + (size_t)4 * 786432,
        b_in + 4 * 1536, qkvb, 3072, 512);
    attn_band<<<gBA, blk256, 0, stream>>>(qkvb, qkvb + 512, qkvb + 1024, attnoutb, L, 3072, 2);
    gemm_bb_nt<<<g512, blk256, 0, stream>>>(attnoutb, w_outb + (size_t)4 * 262144,
        b_out + 4 * 512, itemb, BN, 0, h0b, h1b, g, 4, 0, 512, 512);
    attn_band<<<gBA, blk256, 0, stream>>>(qkvb + 1536, qkvb + 2048, qkvb + 2560, attnoutb, L, 3072, 3);
    gemm_bb_nt<<<g512, blk256, 0, stream>>>(attnoutb, w_outb + (size_t)5 * 262144,
        b_out + 5 * 512, itemb, BN, 0, h0b, h1b, g, 5, 0, 512, 512);

    // heads
    gemm_mfma_nn_relu<<<g256, blk256, 0, stream>>>(h0b, hw1b, hb1, hid0, 256, 512);
    gemm_mfma_nn_relu<<<g256, blk256, 0, stream>>>(h1b, hw1b + 131072, hb1 + 256, hid1, 256, 512);
    gemm_mfma_nn_relu<<<g256, blk256, 0, stream>>>(h1b, hw1b + 262144, hb1 + 512, hid2, 256, 512);
    head2_v2<<<dim3(2048), blk256, 0, stream>>>(hid0, hid1, hid2, hw2, hb2, out);
}

// Round 28
// 599.270 us; speedup vs baseline: 1.0509x; 1.0204x over previous
//
#include <hip/hip_runtime.h>
#include <hip/hip_bf16.h>
#include <stdint.h>

// CGRModel forward — all-bf16 MFMA; merged dual-attention launches (4 blocks/CU),
// BK=64 128x128 projections, bf16 PLE state, merged cvt/qkv, XCD-local attn.
// B=8 L=1024 D=512 H=8 dh=64, M=8192.
// ws (floats): qkvb [0,12582912) bf16 [M][3072]; cross qkv = bf16 ofs 12582912
//  ([M][1536]); attnoutb@12582912 | attnoutb2@16777216 | h0b@20971520 bf16 |
//  h1b@25165824 | uBb@29360128 | sharedb@31457280 | pvBb@33554432 | g@41943040 |
//  itemb@42041344 | userb@44138496 | w_inb@46235648 | w_outb@48594944 |
//  cuwb@49381376 | ciwb@49512448 | hw1b@49643520. hid f32 reuse of qkvb region.

using bf16 = __hip_bfloat16;
typedef __attribute__((ext_vector_type(8))) short short8v;
typedef __attribute__((ext_vector_type(4))) short short4v;
typedef __attribute__((ext_vector_type(4))) float float4v;

#define LDK 40
#define LDKB 72
#define LQA 76
#define EXPC 0.18033688011112042f   // 0.125 * log2(e)

__device__ __forceinline__ float wred_sum(float v) {
    #pragma unroll
    for (int off = 32; off; off >>= 1) v += __shfl_xor(v, off);
    return v;
}
__device__ __forceinline__ short f2bs(float x) {
    bf16 b = __float2bfloat16(x);
    return *reinterpret_cast<short*>(&b);
}
__device__ __forceinline__ float b2f(bf16 v) { return __bfloat162float(v); }

__global__ __launch_bounds__(256) void fillf_kernel(float* __restrict__ p, float v, int n) {
    const int i = blockIdx.x * 256 + threadIdx.x;
    if (i < n) p[i] = v;
}

// One-launch segmented f32->bf16 conversion (7 buffers).
__global__ __launch_bounds__(256) void cvt_all_kernel(
    const float* s0, bf16* d0, const float* s1, bf16* d1, const float* s2, bf16* d2,
    const float* s3, bf16* d3, const float* s4, bf16* d4, const float* s5, bf16* d5,
    const float* s6, bf16* d6)
{
    const int i = blockIdx.x * 256 + threadIdx.x;
    const float* src; bf16* dst; int off;
    if      (i < 1048576) { src = s0; dst = d0; off = i; }
    else if (i < 2097152) { src = s1; dst = d1; off = i - 1048576; }
    else if (i < 3276800) { src = s2; dst = d2; off = i - 2097152; }
    else if (i < 3670016) { src = s3; dst = d3; off = i - 3276800; }
    else if (i < 3735552) { src = s4; dst = d4; off = i - 3670016; }
    else if (i < 3801088) { src = s5; dst = d5; off = i - 3735552; }
    else if (i < 3899392) { src = s6; dst = d6; off = i - 3801088; }
    else return;
    const float4 v = *(const float4*)&src[(size_t)off << 2];
    short4v o;
    o[0] = f2bs(v.x); o[1] = f2bs(v.y); o[2] = f2bs(v.z); o[3] = f2bs(v.w);
    *(short4v*)&dst[(size_t)off << 2] = o;
}

// 128x128 tile NT GEMM, BK=64.
__global__ __launch_bounds__(256) void gemm_bb_nt128(
    const bf16* __restrict__ X, const bf16* __restrict__ W,
    const float* __restrict__ bias, bf16* __restrict__ Yb, int ldY, int K)
{
    __shared__ short As[128 * LDKB];
    __shared__ short Bs[128 * LDKB];
    const int tid = threadIdx.x;
    const int lane = tid & 63, w = tid >> 6;
    const int wr = (w >> 1) << 6, wc = (w & 1) << 6;
    const int bm = blockIdx.y * 128, bn = blockIdx.x * 128;
    const int srow = tid >> 1, scol = (tid & 1) << 5;
    const int c16 = lane & 15, g16 = lane >> 4;

    float4v acc[4][4] = {};
    for (int k0 = 0; k0 < K; k0 += 64) {
        const bf16* xs = &X[(size_t)(bm + srow) * K + k0 + scol];
        const bf16* wsrc = &W[(size_t)(bn + srow) * K + k0 + scol];
        const short8v x0 = *(const short8v*)xs;
        const short8v x1 = *(const short8v*)(xs + 8);
        const short8v x2 = *(const short8v*)(xs + 16);
        const short8v x3 = *(const short8v*)(xs + 24);
        const short8v w0 = *(const short8v*)wsrc;
        const short8v w1 = *(const short8v*)(wsrc + 8);
        const short8v w2 = *(const short8v*)(wsrc + 16);
        const short8v w3 = *(const short8v*)(wsrc + 24);
        __syncthreads();
        *(short8v*)&As[srow * LDKB + scol]      = x0;
        *(short8v*)&As[srow * LDKB + scol + 8]  = x1;
        *(short8v*)&As[srow * LDKB + scol + 16] = x2;
        *(short8v*)&As[srow * LDKB + scol + 24] = x3;
        *(short8v*)&Bs[srow * LDKB + scol]      = w0;
        *(short8v*)&Bs[srow * LDKB + scol + 8]  = w1;
        *(short8v*)&Bs[srow * LDKB + scol + 16] = w2;
        *(short8v*)&Bs[srow * LDKB + scol + 24] = w3;
        __syncthreads();
        #pragma unroll
        for (int ks = 0; ks < 2; ++ks) {
            short8v af[4], bf4[4];
            #pragma unroll
            for (int i = 0; i < 4; ++i) {
                af[i]  = *(const short8v*)&As[(wr + (i << 4) + c16) * LDKB + (ks << 5) + (g16 << 3)];
                bf4[i] = *(const short8v*)&Bs[(wc + (i << 4) + c16) * LDKB + (ks << 5) + (g16 << 3)];
            }
            #pragma unroll
            for (int i = 0; i < 4; ++i)
                #pragma unroll
                for (int j = 0; j < 4; ++j)
                    acc[i][j] = __builtin_amdgcn_mfma_f32_16x16x32_bf16(af[i], bf4[j], acc[i][j], 0, 0, 0);
        }
    }
    #pragma unroll
    for (int i = 0; i < 4; ++i)
        #pragma unroll
        for (int rg = 0; rg < 4; ++rg) {
            const int m = bm + wr + (i << 4) + (g16 << 2) + rg;
            #pragma unroll
            for (int j = 0; j < 4; ++j) {
                const int n = bn + wc + (j << 4) + c16;
                Yb[(size_t)m * ldY + n] = __float2bfloat16(acc[i][j][rg] + bias[n]);
            }
        }
}

// 64x64 NT GEMM with bf16 epilogue: v = X@W^T + bias (+resb); Yb store, PLE.
__global__ __launch_bounds__(256) void gemm_bb_nt(
    const bf16* __restrict__ X, const bf16* __restrict__ W,
    const float* __restrict__ bias, const bf16* __restrict__ resb,
    bf16* __restrict__ Yb, int ldY,
    bf16* __restrict__ h0, bf16* __restrict__ h1,
    const float* __restrict__ g, int eidx, int hinit,
    int N, int K)
{
    __shared__ short As[64 * LDK];
    __shared__ short Bs[64 * LDK];
    const int tid = threadIdx.x;
    const int lane = tid & 63, w = tid >> 6;
    const int bm = blockIdx.y * 64, bn = blockIdx.x * 64;
    const int r = tid >> 2, c8 = (tid & 3) << 3;
    const int arow = ((w << 4) + (lane & 15)) * LDK + ((lane >> 4) << 3);
    const int bbase = (lane & 15) * LDK + ((lane >> 4) << 3);

    float4v acc[4] = {};
    for (int k0 = 0; k0 < K; k0 += 32) {
        const short8v av = *(const short8v*)&X[(size_t)(bm + r) * K + k0 + c8];
        const short8v bv = *(const short8v*)&W[(size_t)(bn + r) * K + k0 + c8];
        __syncthreads();
        *(short8v*)&As[r * LDK + c8] = av;
        *(short8v*)&Bs[r * LDK + c8] = bv;
        __syncthreads();
        const short8v a = *(const short8v*)&As[arow];
        #pragma unroll
        for (int c = 0; c < 4; ++c) {
            const short8v b = *(const short8v*)&Bs[(c << 4) * LDK + bbase];
            acc[c] = __builtin_amdgcn_mfma_f32_16x16x32_bf16(a, b, acc[c], 0, 0, 0);
        }
    }
    #pragma unroll
    for (int rg = 0; rg < 4; ++rg) {
        const int m = bm + (w << 4) + ((lane >> 4) << 2) + rg;
        float g0 = 0.f, g1 = 0.f;
        if (h0) {
            g0 = g[(size_t)m * 6 + eidx];
            g1 = g[(size_t)(8192 + m) * 6 + eidx];
        }
        #pragma unroll
        for (int c = 0; c < 4; ++c) {
            const int n = bn + (c << 4) + (lane & 15);
            float v = acc[c][rg] + bias[n];
            if (resb) v += b2f(resb[(size_t)m * 512 + n]);
            if (Yb) Yb[(size_t)m * ldY + n] = __float2bfloat16(v);
            if (h0) {
                const size_t hi = (size_t)m * 512 + n;
                if (hinit) {
                    h0[hi] = __float2bfloat16(g0 * v);
                    h1[hi] = __float2bfloat16(g1 * v);
                } else {
                    h0[hi] = __float2bfloat16(b2f(h0[hi]) + g0 * v);
                    h1[hi] = __float2bfloat16(b2f(h1[hi]) + g1 * v);
                }
            }
        }
    }
}

// Y[m][n] = relu(X@W + bias). X bf16, W bf16 [K][N]. Transposed-B staging. Y f32.
__global__ __launch_bounds__(256) void gemm_mfma_nn_relu(
    const bf16* __restrict__ X, const bf16* __restrict__ W,
    const float* __restrict__ bias, float* __restrict__ Y, int N, int K)
{
    __shared__ short As[64 * LDK];
    __shared__ short Bs[64 * LDK + 64];
    const int tid = threadIdx.x;
    const int lane = tid & 63, w = tid >> 6;
    const int bm = blockIdx.y * 64, bn = blockIdx.x * 64;
    const int r = tid >> 2, c8 = (tid & 3) << 3;
    const int kk = tid >> 3, nn0 = (tid & 7) << 3;
    const int arow = ((w << 4) + (lane & 15)) * LDK + ((lane >> 4) << 3);

    float4v acc[4] = {};
    for (int k0 = 0; k0 < K; k0 += 32) {
        const short8v av = *(const short8v*)&X[(size_t)(bm + r) * K + k0 + c8];
        const short8v bw = *(const short8v*)&W[(size_t)(k0 + kk) * N + bn + nn0];
        __syncthreads();
        *(short8v*)&As[r * LDK + c8] = av;
        #pragma unroll
        for (int i = 0; i < 8; ++i) {
            const int nn = nn0 + i;
            Bs[nn * LDK + ((nn >> 3) << 3) + kk] = bw[i];
        }
        __syncthreads();
        const short8v a = *(const short8v*)&As[arow];
        #pragma unroll
        for (int c = 0; c < 4; ++c) {
            const int n = (c << 4) + (lane & 15);
            const short8v b = *(const short8v*)&Bs[n * LDK + ((n >> 3) << 3) + ((lane >> 4) << 3)];
            acc[c] = __builtin_amdgcn_mfma_f32_16x16x32_bf16(a, b, acc[c], 0, 0, 0);
        }
    }
    #pragma unroll
    for (int rg = 0; rg < 4; ++rg) {
        const int m = bm + (w << 4) + ((lane >> 4) << 2) + rg;
        #pragma unroll
        for (int c = 0; c < 4; ++c) {
            const int n = bn + (c << 4) + (lane & 15);
            Y[(size_t)m * N + n] = fmaxf(acc[c][rg] + bias[n], 0.f);
        }
    }
}

// Dual flash attention: grid (B*H, 16); y<8 -> problem 0, y>=8 -> problem 1.
// Register-prefetch double buffering; 8 waves; Q in regs; no-max softmax;
// wave-private Ps. Each problem has its own qkv pointers, out, ld, causal.
__global__ __launch_bounds__(512) void attn_flash2(
    const bf16* __restrict__ q0, const bf16* __restrict__ k0, const bf16* __restrict__ v0,
    bf16* __restrict__ o0, int ld0, int c0,
    const bf16* __restrict__ q1, const bf16* __restrict__ k1, const bf16* __restrict__ v1,
    bf16* __restrict__ o1, int ld1, int c1, int L)
{
    const int half = blockIdx.y >> 3;
    int bq = blockIdx.y & 7;
    const bf16 *qb, *kb, *vb; bf16* out; int ld, causal;
    if (half == 0) { qb = q0; kb = k0; vb = v0; out = o0; ld = ld0; causal = c0; }
    else           { qb = q1; kb = k1; vb = v1; out = o1; ld = ld1; causal = c1; }
    if (causal) bq = (bq < 4) ? bq : (11 - bq);
    const int b = blockIdx.x >> 3, h = blockIdx.x & 7;
    const int tid = threadIdx.x;
    const int lane = tid & 63, w = tid >> 6;
    const int g16 = lane >> 4, c16 = lane & 15;
    __shared__ short Ks[64 * LQA];
    __shared__ short Ps[128 * LQA];
    __shared__ short Vt[64 * LQA + 64];
    const size_t base = (size_t)b * L * ld + (size_t)h * 64;
    const int qlo = bq << 7;

    short8v qa0, qa1;
    {
        const bf16* qsrc = qb + base + (size_t)(qlo + (w << 4) + c16) * ld + (g16 << 3);
        qa0 = *(const short8v*)qsrc;
        qa1 = *(const short8v*)(qsrc + 32);
    }

    const int sr2 = (tid & 255) >> 2, sc2 = (tid & 3) << 4;
    const bool isK = tid < 256;

    float4v oacc[4] = {};
    float lrow[4] = {0.f, 0.f, 0.f, 0.f};

    const int nkt = causal ? ((bq + 1) << 1) : (L >> 6);

    short8v pf0, pf1;
    {
        const bf16* src = (isK ? kb : vb) + base + (size_t)sr2 * ld + sc2;
        pf0 = *(const short8v*)src;
        pf1 = *(const short8v*)(src + 8);
    }

    for (int kt = 0; kt < nkt; ++kt) {
        const int klo = kt << 6;
        __syncthreads();
        if (isK) {
            *(short8v*)&Ks[sr2 * LQA + sc2]     = pf0;
            *(short8v*)&Ks[sr2 * LQA + sc2 + 8] = pf1;
        } else {
            #pragma unroll
            for (int i = 0; i < 8; ++i) Vt[(sc2 + i) * LQA + sc2 + sr2] = pf0[i];
            #pragma unroll
            for (int i = 0; i < 8; ++i) Vt[(sc2 + 8 + i) * LQA + sc2 + sr2] = pf1[i];
        }
        __syncthreads();
        if (kt + 1 < nkt) {
            const bf16* src = (isK ? kb : vb) + base + (size_t)(((kt + 1) << 6) + sr2) * ld + sc2;
            pf0 = *(const short8v*)src;
            pf1 = *(const short8v*)(src + 8);
        }
        float4v sacc[4] = {};
        #pragma unroll
        for (int ct = 0; ct < 4; ++ct) {
            const short8v b0 = *(const short8v*)&Ks[((ct << 4) + c16) * LQA + (g16 << 3)];
            sacc[ct] = __builtin_amdgcn_mfma_f32_16x16x32_bf16(qa0, b0, sacc[ct], 0, 0, 0);
            const short8v b1 = *(const short8v*)&Ks[((ct << 4) + c16) * LQA + 32 + (g16 << 3)];
            sacc[ct] = __builtin_amdgcn_mfma_f32_16x16x32_bf16(qa1, b1, sacc[ct], 0, 0, 0);
        }
        const bool diag = causal && (klo + 63 > qlo + (w << 4));
        #pragma unroll
        for (int ct = 0; ct < 4; ++ct)
            #pragma unroll
            for (int rg = 0; rg < 4; ++rg) {
                float p = exp2f(sacc[ct][rg] * EXPC);
                if (diag && (klo + (ct << 4) + c16) > (qlo + (w << 4) + (g16 << 2) + rg))
                    p = 0.f;
                lrow[rg] += p;
                Ps[((w << 4) + (g16 << 2) + rg) * LQA + (ct << 4) + c16] = f2bs(p);
            }
        #pragma unroll
        for (int ks = 0; ks < 2; ++ks) {
            const short8v a = *(const short8v*)&Ps[((w << 4) + c16) * LQA + (ks << 5) + (g16 << 3)];
            #pragma unroll
            for (int dt = 0; dt < 4; ++dt) {
                const short8v bf = *(const short8v*)&Vt[((dt << 4) + c16) * LQA + (dt << 4) + (ks << 5) + (g16 << 3)];
                oacc[dt] = __builtin_amdgcn_mfma_f32_16x16x32_bf16(a, bf, oacc[dt], 0, 0, 0);
            }
        }
    }
    #pragma unroll
    for (int rg = 0; rg < 4; ++rg) {
        float v = lrow[rg];
        #pragma unroll
        for (int off = 8; off; off >>= 1) v += __shfl_xor(v, off);
        lrow[rg] = v;
    }
    #pragma unroll
    for (int rg = 0; rg < 4; ++rg) {
        const int row = qlo + (w << 4) + (g16 << 2) + rg;
        const float inv = 1.f / lrow[rg];
        #pragma unroll
        for (int dt = 0; dt < 4; ++dt)
            out[((size_t)b * L + row) * 512 + h * 64 + (dt << 4) + c16] =
                __float2bfloat16(oacc[dt][rg] * inv);
    }
}

// Dual banded causal attention: grid (256, 128); y<64 -> expert A (w=wA),
// y>=64 -> expert B (w=wB, qkv offset +1536). One wave/query.
__global__ __launch_bounds__(256) void attn_band2(
    const bf16* __restrict__ qkv, bf16* __restrict__ oA, bf16* __restrict__ oB,
    int L, int ld, int wA, int wB)
{
    const int half = blockIdx.y >> 6;
    const int yy = blockIdx.y & 63;
    const int u = threadIdx.x >> 6, t = threadIdx.x & 63;
    const int i = blockIdx.x * 4 + u;
    const int b = yy >> 3, h = yy & 7;
    const bf16* qb = qkv + half * 1536;
    const bf16* kb = qb + 512;
    const bf16* vb = qb + 1024;
    bf16* out = half ? oB : oA;
    const int w = half ? wB : wA;
    const size_t base = (size_t)b * L * ld + (size_t)h * 64;
    const float qv = b2f(qb[base + (size_t)i * ld + t]);
    const int jmin = (i - w) > 0 ? (i - w) : 0;
    const int n = i - jmin;
    float sv[4];
    float mx = -1e30f;
    #pragma unroll
    for (int q = 0; q < 4; ++q) {
        float d = -1e30f;
        if (q <= n) {
            float dd = qv * b2f(kb[base + (size_t)(jmin + q) * ld + t]);
            d = wred_sum(dd) * 0.125f;
        }
        sv[q] = d;
        mx = fmaxf(mx, d);
    }
    float lsum = 0.f, acc = 0.f;
    #pragma unroll
    for (int q = 0; q < 4; ++q) {
        if (q <= n) {
            const float p = __expf(sv[q] - mx);
            lsum += p;
            acc += p * b2f(vb[base + (size_t)(jmin + q) * ld + t]);
        }
    }
    out[((size_t)b * L + i) * 512 + h * 64 + t] = __float2bfloat16(acc / lsum);
}

// Gates, all-lane reduction.
__global__ __launch_bounds__(64) void gates_v2(
    const float* __restrict__ item, const float* __restrict__ gw,
    const float* __restrict__ gb, float* __restrict__ g, int rows)
{
    const int r = blockIdx.x;
    const int t = threadIdx.x;
    __shared__ float xr[512];
    __shared__ float lg[12];
    for (int ii = t; ii < 512; ii += 64) xr[ii] = item[(size_t)r * 512 + ii];
    __syncthreads();
    #pragma unroll
    for (int p = 0; p < 12; ++p) {
        const int tk = p / 6, e = p % 6;
        float s = 0.f;
        #pragma unroll
        for (int dd = t; dd < 512; dd += 64) s += xr[dd] * gw[(size_t)(tk * 512 + dd) * 6 + e];
        s = wred_sum(s);
        if (t == 0) lg[p] = s + gb[p];
    }
    __syncthreads();
    if (t < 2) {
        float mx = -1e30f;
        #pragma unroll
        for (int e = 0; e < 6; ++e) mx = fmaxf(mx, lg[t * 6 + e]);
        float sum = 0.f, p6[6];
        #pragma unroll
        for (int e = 0; e < 6; ++e) { p6[e] = __expf(lg[t * 6 + e] - mx); sum += p6[e]; }
        #pragma unroll
        for (int e = 0; e < 6; ++e) g[(size_t)(t * rows + r) * 6 + e] = p6[e] / sum;
    }
}

__global__ __launch_bounds__(256) void head2_v2(
    const float* __restrict__ hid0, const float* __restrict__ hid1, const float* __restrict__ hid2,
    const float* __restrict__ w2, const float* __restrict__ b2, float* __restrict__ out)
{
    const int w = threadIdx.x >> 6, lane = threadIdx.x & 63;
    const int r = blockIdx.x * 4 + w;
    float s0 = 0.f, s1 = 0.f, s2 = 0.f;
    #pragma unroll
    for (int d = lane; d < 256; d += 64) {
        s0 += hid0[(size_t)r * 256 + d] * w2[d];
        s1 += hid1[(size_t)r * 256 + d] * w2[256 + d];
        s2 += hid2[(size_t)r * 256 + d] * w2[512 + d];
    }
    s0 = wred_sum(s0); s1 = wred_sum(s1); s2 = wred_sum(s2);
    if (lane == 0) {
        out[r]         = 1.f / (1.f + __expf(-(s0 + b2[0])));
        out[8192 + r]  = 1.f / (1.f + __expf(-(s1 + b2[1])));
        out[16384 + r] = 1.f / (1.f + __expf(-(s2 + b2[2])));
    }
}

extern "C" void kernel_launch(void* const* d_in, const int* in_sizes, int n_in,
                              void* d_out, int out_size, void* d_ws, size_t ws_size,
                              hipStream_t stream)
{
    float* out = (float*)d_out;
    const int* s = in_sizes;
    const bool dicto = n_in == 16 &&
        s[0] == 4194304 && s[1] == 4194304 && s[2] == 4718592 && s[3] == 9216 &&
        s[4] == 1572864 && s[5] == 3072 && s[6] == 262144 && s[7] == 512 &&
        s[8] == 262144 && s[9] == 512 && s[10] == 6144 && s[11] == 12 &&
        s[12] == 393216 && s[13] == 768 && s[14] == 768 && s[15] == 3;
    if (!dicto) {
        fillf_kernel<<<dim3(96), dim3(256), 0, stream>>>(out, 16384.0f, out_size);
        return;
    }

    const float* user  = (const float*)d_in[0];
    const float* item  = (const float*)d_in[1];
    const float* w_in  = (const float*)d_in[2];
    const float* b_in  = (const float*)d_in[3];
    const float* w_out = (const float*)d_in[4];
    const float* b_out = (const float*)d_in[5];
    const float* cuw   = (const float*)d_in[6];
    const float* cub   = (const float*)d_in[7];
    const float* ciw   = (const float*)d_in[8];
    const float* cib   = (const float*)d_in[9];
    const float* gw    = (const float*)d_in[10];
    const float* gb    = (const float*)d_in[11];
    const float* hw1   = (const float*)d_in[12];
    const float* hb1   = (const float*)d_in[13];
    const float* hw2   = (const float*)d_in[14];
    const float* hb2   = (const float*)d_in[15];

    const int L = 1024, M = 8192;
    float* ws = (float*)d_ws;
    bf16* qkvb     = (bf16*)ws;                     // [M][3072] capacity
    bf16* qkvc     = qkvb + (size_t)12582912;       // cross qkv [M][1536]
    bf16* attnoutb = (bf16*)(ws + 12582912);
    bf16* attnout2 = (bf16*)(ws + 16777216);
    bf16* h0b      = (bf16*)(ws + 20971520);
    bf16* h1b      = (bf16*)(ws + 25165824);
    bf16* uBb      = (bf16*)(ws + 29360128);
    bf16* sharedb  = (bf16*)(ws + 31457280);
    bf16* pvBb     = (bf16*)(ws + 33554432);
    float* g       = ws + 41943040;
    bf16* itemb    = (bf16*)(ws + 42041344);
    bf16* userb    = (bf16*)(ws + 44138496);
    bf16* w_inb    = (bf16*)(ws + 46235648);
    bf16* w_outb   = (bf16*)(ws + 48594944);
    bf16* cuwb     = (bf16*)(ws + 49381376);
    bf16* ciwb     = (bf16*)(ws + 49512448);
    bf16* hw1b     = (bf16*)(ws + 49643520);
    float* hid0 = ws;
    float* hid1 = ws + (size_t)M * 256;
    float* hid2 = ws + (size_t)M * 512;
    bf16* BN = nullptr;
    float* FN = nullptr;

    const dim3 blk512(512), blk256(256), blk64(64);
    const dim3 gP1536(12, 64), gP3072(24, 64), gP1024(8, 64);
    const dim3 g512(8, 128), g256(4, 128);
    const dim3 gFA2(64, 16), gBA2(256, 128);

    cvt_all_kernel<<<dim3(15232), blk256, 0, stream>>>(
        item, itemb, user, userb, w_in, w_inb, w_out, w_outb,
        cuw, cuwb, ciw, ciwb, hw1, hw1b);

    gates_v2<<<dim3(M), blk64, 0, stream>>>(item, gw, gb, g, M);

    // Projections for e0 and cross (independent)
    gemm_bb_nt128<<<gP1536, blk256, 0, stream>>>(itemb, w_inb, b_in, qkvb, 1536, 512);
    gemm_bb_nt<<<g512, blk256, 0, stream>>>(userb, cuwb, cub, nullptr,
        uBb, 512, BN, BN, FN, 0, 0, 512, 512);
    gemm_bb_nt<<<g512, blk256, 0, stream>>>(itemb, ciwb, cib, nullptr,
        pvBb, 512, BN, BN, FN, 0, 0, 512, 512);
    gemm_bb_nt<<<g512, blk256, 0, stream>>>(uBb, w_inb + (size_t)3 * 786432,
        b_in + 3 * 1536, nullptr, qkvc, 1536, BN, BN, FN, 0, 0, 512, 512);
    gemm_bb_nt128<<<gP1024, blk256, 0, stream>>>(pvBb, w_inb + (size_t)3 * 786432 + 262144,
        b_in + 3 * 1536 + 512, qkvc + 512, 1536, 512);

    // Merged attention: e0 (causal) + cross (full)
    attn_flash2<<<gFA2, blk512, 0, stream>>>(
        qkvb, qkvb + 512, qkvb + 1024, attnoutb, 1536, 1,
        qkvc, qkvc + 512, qkvc + 1024, attnout2, 1536, 0, L);

    // e0 out-proj (h init), then cross out-proj (accumulate)
    gemm_bb_nt<<<g512, blk256, 0, stream>>>(attnoutb, w_outb, b_out, itemb,
        sharedb, 512, h0b, h1b, g, 0, 1, 512, 512);
    gemm_bb_nt<<<g512, blk256, 0, stream>>>(attnout2, w_outb + (size_t)3 * 262144,
        b_out + 3 * 512, nullptr, BN, 0, h0b, h1b, g, 3, 0, 512, 512);

    // e1+e2: merged qkv projection, merged dual attention, sequential out-projs
    gemm_bb_nt128<<<gP3072, blk256, 0, stream>>>(sharedb, w_inb + (size_t)786432,
        b_in + 1536, qkvb, 3072, 512);
    attn_flash2<<<gFA2, blk512, 0, stream>>>(
        qkvb, qkvb + 512, qkvb + 1024, attnoutb, 3072, 1,
        qkvb + 1536, qkvb + 2048, qkvb + 2560, attnout2, 3072, 1, L);
    gemm_bb_nt<<<g512, blk256, 0, stream>>>(attnoutb, w_outb + 262144, b_out + 512,
        sharedb, BN, 0, h0b, h1b, g, 1, 0, 512, 512);
    gemm_bb_nt<<<g512, blk256, 0, stream>>>(attnout2, w_outb + 524288, b_out + 1024,
        sharedb, BN, 0, h0b, h1b, g, 2, 0, 512, 512);

    // e4+e5: merged qkv projection, merged dual band attention, sequential out-projs
    gemm_bb_nt128<<<gP3072, blk256, 0, stream>>>(itemb, w_inb + (size_t)4 * 786432,
        b_in + 4 * 1536, qkvb, 3072, 512);
    attn_band2<<<gBA2, blk256, 0, stream>>>(qkvb, attnoutb, attnout2, L, 3072, 2, 3);
    gemm_bb_nt<<<g512, blk256, 0, stream>>>(attnoutb, w_outb + (size_t)4 * 262144,
        b_out + 4 * 512, itemb, BN, 0, h0b, h1b, g, 4, 0, 512, 512);
    gemm_bb_nt<<<g512, blk256, 0, stream>>>(attnout2, w_outb + (size_t)5 * 262144,
        b_out + 5 * 512, itemb, BN, 0, h0b, h1b, g, 5, 0, 512, 512);

    // heads
    gemm_mfma_nn_relu<<<g256, blk256, 0, stream>>>(h0b, hw1b, hb1, hid0, 256, 512);
    gemm_mfma_nn_relu<<<g256, blk256, 0, stream>>>(h1b, hw1b + 131072, hb1 + 256, hid1, 256, 512);
    gemm_mfma_nn_relu<<<g256, blk256, 0, stream>>>(h1b, hw1b + 262144, hb1 + 512, hid2, 256, 512);
    head2_v2<<<dim3(2048), blk256, 0, stream>>>(hid0, hid1, hid2, hw2, hb2, out);
}

// Round 29
// 561.082 us; speedup vs baseline: 1.1225x; 1.0681x over previous
//
#include <hip/hip_runtime.h>
#include <hip/hip_bf16.h>
#include <stdint.h>

// CGRModel forward — all-bf16 MFMA; dual-attention launches, dual-epilogue
// out-projections (fused h RMW), BK=64 128x128 projections, bf16 PLE state,
// merged cvt/qkv, XCD-local attn. B=8 L=1024 D=512 H=8 dh=64, M=8192.
// ws (floats): qkvb [0,12582912) bf16 [M][3072]; qkvc bf16 ofs +12582912 elems;
//  attnoutb@12582912 | attnout2@16777216 | h0b@20971520 bf16 | h1b@25165824 |
//  uBb@29360128 | sharedb@31457280 | pvBb@33554432 | g@41943040 | itemb@42041344 |
//  userb@44138496 | w_inb@46235648 | w_outb@48594944 | cuwb@49381376 |
//  ciwb@49512448 | hw1b@49643520. hid f32 reuse of qkvb region.

using bf16 = __hip_bfloat16;
typedef __attribute__((ext_vector_type(8))) short short8v;
typedef __attribute__((ext_vector_type(4))) short short4v;
typedef __attribute__((ext_vector_type(4))) float float4v;

#define LDK 40
#define LDKB 72
#define LQA 76
#define EXPC 0.18033688011112042f   // 0.125 * log2(e)

__device__ __forceinline__ float wred_sum(float v) {
    #pragma unroll
    for (int off = 32; off; off >>= 1) v += __shfl_xor(v, off);
    return v;
}
__device__ __forceinline__ short f2bs(float x) {
    bf16 b = __float2bfloat16(x);
    return *reinterpret_cast<short*>(&b);
}
__device__ __forceinline__ float b2f(bf16 v) { return __bfloat162float(v); }

__global__ __launch_bounds__(256) void fillf_kernel(float* __restrict__ p, float v, int n) {
    const int i = blockIdx.x * 256 + threadIdx.x;
    if (i < n) p[i] = v;
}

// One-launch segmented f32->bf16 conversion (7 buffers).
__global__ __launch_bounds__(256) void cvt_all_kernel(
    const float* s0, bf16* d0, const float* s1, bf16* d1, const float* s2, bf16* d2,
    const float* s3, bf16* d3, const float* s4, bf16* d4, const float* s5, bf16* d5,
    const float* s6, bf16* d6)
{
    const int i = blockIdx.x * 256 + threadIdx.x;
    const float* src; bf16* dst; int off;
    if      (i < 1048576) { src = s0; dst = d0; off = i; }
    else if (i < 2097152) { src = s1; dst = d1; off = i - 1048576; }
    else if (i < 3276800) { src = s2; dst = d2; off = i - 2097152; }
    else if (i < 3670016) { src = s3; dst = d3; off = i - 3276800; }
    else if (i < 3735552) { src = s4; dst = d4; off = i - 3670016; }
    else if (i < 3801088) { src = s5; dst = d5; off = i - 3735552; }
    else if (i < 3899392) { src = s6; dst = d6; off = i - 3801088; }
    else return;
    const float4 v = *(const float4*)&src[(size_t)off << 2];
    short4v o;
    o[0] = f2bs(v.x); o[1] = f2bs(v.y); o[2] = f2bs(v.z); o[3] = f2bs(v.w);
    *(short4v*)&dst[(size_t)off << 2] = o;
}

// 128x128 tile NT GEMM, BK=64.
__global__ __launch_bounds__(256) void gemm_bb_nt128(
    const bf16* __restrict__ X, const bf16* __restrict__ W,
    const float* __restrict__ bias, bf16* __restrict__ Yb, int ldY, int K)
{
    __shared__ short As[128 * LDKB];
    __shared__ short Bs[128 * LDKB];
    const int tid = threadIdx.x;
    const int lane = tid & 63, w = tid >> 6;
    const int wr = (w >> 1) << 6, wc = (w & 1) << 6;
    const int bm = blockIdx.y * 128, bn = blockIdx.x * 128;
    const int srow = tid >> 1, scol = (tid & 1) << 5;
    const int c16 = lane & 15, g16 = lane >> 4;

    float4v acc[4][4] = {};
    for (int k0 = 0; k0 < K; k0 += 64) {
        const bf16* xs = &X[(size_t)(bm + srow) * K + k0 + scol];
        const bf16* wsrc = &W[(size_t)(bn + srow) * K + k0 + scol];
        const short8v x0 = *(const short8v*)xs;
        const short8v x1 = *(const short8v*)(xs + 8);
        const short8v x2 = *(const short8v*)(xs + 16);
        const short8v x3 = *(const short8v*)(xs + 24);
        const short8v w0 = *(const short8v*)wsrc;
        const short8v w1 = *(const short8v*)(wsrc + 8);
        const short8v w2 = *(const short8v*)(wsrc + 16);
        const short8v w3 = *(const short8v*)(wsrc + 24);
        __syncthreads();
        *(short8v*)&As[srow * LDKB + scol]      = x0;
        *(short8v*)&As[srow * LDKB + scol + 8]  = x1;
        *(short8v*)&As[srow * LDKB + scol + 16] = x2;
        *(short8v*)&As[srow * LDKB + scol + 24] = x3;
        *(short8v*)&Bs[srow * LDKB + scol]      = w0;
        *(short8v*)&Bs[srow * LDKB + scol + 8]  = w1;
        *(short8v*)&Bs[srow * LDKB + scol + 16] = w2;
        *(short8v*)&Bs[srow * LDKB + scol + 24] = w3;
        __syncthreads();
        #pragma unroll
        for (int ks = 0; ks < 2; ++ks) {
            short8v af[4], bf4[4];
            #pragma unroll
            for (int i = 0; i < 4; ++i) {
                af[i]  = *(const short8v*)&As[(wr + (i << 4) + c16) * LDKB + (ks << 5) + (g16 << 3)];
                bf4[i] = *(const short8v*)&Bs[(wc + (i << 4) + c16) * LDKB + (ks << 5) + (g16 << 3)];
            }
            #pragma unroll
            for (int i = 0; i < 4; ++i)
                #pragma unroll
                for (int j = 0; j < 4; ++j)
                    acc[i][j] = __builtin_amdgcn_mfma_f32_16x16x32_bf16(af[i], bf4[j], acc[i][j], 0, 0, 0);
        }
    }
    #pragma unroll
    for (int i = 0; i < 4; ++i)
        #pragma unroll
        for (int rg = 0; rg < 4; ++rg) {
            const int m = bm + wr + (i << 4) + (g16 << 2) + rg;
            #pragma unroll
            for (int j = 0; j < 4; ++j) {
                const int n = bn + wc + (j << 4) + c16;
                Yb[(size_t)m * ldY + n] = __float2bfloat16(acc[i][j][rg] + bias[n]);
            }
        }
}

// 64x64 NT GEMM with bf16 epilogue (single): v = X@W^T + bias; Yb store only.
__global__ __launch_bounds__(256) void gemm_bb_nt(
    const bf16* __restrict__ X, const bf16* __restrict__ W,
    const float* __restrict__ bias, bf16* __restrict__ Yb, int ldY, int K)
{
    __shared__ short As[64 * LDK];
    __shared__ short Bs[64 * LDK];
    const int tid = threadIdx.x;
    const int lane = tid & 63, w = tid >> 6;
    const int bm = blockIdx.y * 64, bn = blockIdx.x * 64;
    const int r = tid >> 2, c8 = (tid & 3) << 3;
    const int arow = ((w << 4) + (lane & 15)) * LDK + ((lane >> 4) << 3);
    const int bbase = (lane & 15) * LDK + ((lane >> 4) << 3);

    float4v acc[4] = {};
    for (int k0 = 0; k0 < K; k0 += 32) {
        const short8v av = *(const short8v*)&X[(size_t)(bm + r) * K + k0 + c8];
        const short8v bv = *(const short8v*)&W[(size_t)(bn + r) * K + k0 + c8];
        __syncthreads();
        *(short8v*)&As[r * LDK + c8] = av;
        *(short8v*)&Bs[r * LDK + c8] = bv;
        __syncthreads();
        const short8v a = *(const short8v*)&As[arow];
        #pragma unroll
        for (int c = 0; c < 4; ++c) {
            const short8v b = *(const short8v*)&Bs[(c << 4) * LDK + bbase];
            acc[c] = __builtin_amdgcn_mfma_f32_16x16x32_bf16(a, b, acc[c], 0, 0, 0);
        }
    }
    #pragma unroll
    for (int rg = 0; rg < 4; ++rg) {
        const int m = bm + (w << 4) + ((lane >> 4) << 2) + rg;
        #pragma unroll
        for (int c = 0; c < 4; ++c) {
            const int n = bn + (c << 4) + (lane & 15);
            Yb[(size_t)m * ldY + n] = __float2bfloat16(acc[c][rg] + bias[n]);
        }
    }
}

// Dual 64x64 NT GEMM with fused PLE epilogue:
// vA = XA@WA^T + biasA (+resA); vB = XB@WB^T + biasB (+resB);
// optional Yb store of vA; h0/h1 (+)= g[eA]*vA + g[eB]*vB (single RMW).
__global__ __launch_bounds__(256) void gemm_bb_nt_dual(
    const bf16* __restrict__ XA, const bf16* __restrict__ WA, const float* __restrict__ biasA,
    const bf16* __restrict__ XB, const bf16* __restrict__ WB, const float* __restrict__ biasB,
    const bf16* __restrict__ resA, const bf16* __restrict__ resB,
    bf16* __restrict__ Yb, int ldY,
    bf16* __restrict__ h0, bf16* __restrict__ h1,
    const float* __restrict__ g, int eA, int eB, int hinit, int K)
{
    __shared__ short As[64 * LDK];
    __shared__ short Bs[64 * LDK];
    const int tid = threadIdx.x;
    const int lane = tid & 63, w = tid >> 6;
    const int bm = blockIdx.y * 64, bn = blockIdx.x * 64;
    const int r = tid >> 2, c8 = (tid & 3) << 3;
    const int arow = ((w << 4) + (lane & 15)) * LDK + ((lane >> 4) << 3);
    const int bbase = (lane & 15) * LDK + ((lane >> 4) << 3);

    float4v accA[4] = {};
    for (int k0 = 0; k0 < K; k0 += 32) {
        const short8v av = *(const short8v*)&XA[(size_t)(bm + r) * K + k0 + c8];
        const short8v bv = *(const short8v*)&WA[(size_t)(bn + r) * K + k0 + c8];
        __syncthreads();
        *(short8v*)&As[r * LDK + c8] = av;
        *(short8v*)&Bs[r * LDK + c8] = bv;
        __syncthreads();
        const short8v a = *(const short8v*)&As[arow];
        #pragma unroll
        for (int c = 0; c < 4; ++c) {
            const short8v b = *(const short8v*)&Bs[(c << 4) * LDK + bbase];
            accA[c] = __builtin_amdgcn_mfma_f32_16x16x32_bf16(a, b, accA[c], 0, 0, 0);
        }
    }
    float4v accB[4] = {};
    for (int k0 = 0; k0 < K; k0 += 32) {
        const short8v av = *(const short8v*)&XB[(size_t)(bm + r) * K + k0 + c8];
        const short8v bv = *(const short8v*)&WB[(size_t)(bn + r) * K + k0 + c8];
        __syncthreads();
        *(short8v*)&As[r * LDK + c8] = av;
        *(short8v*)&Bs[r * LDK + c8] = bv;
        __syncthreads();
        const short8v a = *(const short8v*)&As[arow];
        #pragma unroll
        for (int c = 0; c < 4; ++c) {
            const short8v b = *(const short8v*)&Bs[(c << 4) * LDK + bbase];
            accB[c] = __builtin_amdgcn_mfma_f32_16x16x32_bf16(a, b, accB[c], 0, 0, 0);
        }
    }
    #pragma unroll
    for (int rg = 0; rg < 4; ++rg) {
        const int m = bm + (w << 4) + ((lane >> 4) << 2) + rg;
        const float gA0 = g[(size_t)m * 6 + eA];
        const float gA1 = g[(size_t)(8192 + m) * 6 + eA];
        const float gB0 = g[(size_t)m * 6 + eB];
        const float gB1 = g[(size_t)(8192 + m) * 6 + eB];
        #pragma unroll
        for (int c = 0; c < 4; ++c) {
            const int n = bn + (c << 4) + (lane & 15);
            float vA = accA[c][rg] + biasA[n];
            if (resA) vA += b2f(resA[(size_t)m * 512 + n]);
            float vB = accB[c][rg] + biasB[n];
            if (resB) vB += b2f(resB[(size_t)m * 512 + n]);
            if (Yb) Yb[(size_t)m * ldY + n] = __float2bfloat16(vA);
            const size_t hi = (size_t)m * 512 + n;
            const float t0 = gA0 * vA + gB0 * vB;
            const float t1 = gA1 * vA + gB1 * vB;
            if (hinit) {
                h0[hi] = __float2bfloat16(t0);
                h1[hi] = __float2bfloat16(t1);
            } else {
                h0[hi] = __float2bfloat16(b2f(h0[hi]) + t0);
                h1[hi] = __float2bfloat16(b2f(h1[hi]) + t1);
            }
        }
    }
}

// Y[m][n] = relu(X@W + bias). X bf16, W bf16 [K][N]. Transposed-B staging. Y f32.
__global__ __launch_bounds__(256) void gemm_mfma_nn_relu(
    const bf16* __restrict__ X, const bf16* __restrict__ W,
    const float* __restrict__ bias, float* __restrict__ Y, int N, int K)
{
    __shared__ short As[64 * LDK];
    __shared__ short Bs[64 * LDK + 64];
    const int tid = threadIdx.x;
    const int lane = tid & 63, w = tid >> 6;
    const int bm = blockIdx.y * 64, bn = blockIdx.x * 64;
    const int r = tid >> 2, c8 = (tid & 3) << 3;
    const int kk = tid >> 3, nn0 = (tid & 7) << 3;
    const int arow = ((w << 4) + (lane & 15)) * LDK + ((lane >> 4) << 3);

    float4v acc[4] = {};
    for (int k0 = 0; k0 < K; k0 += 32) {
        const short8v av = *(const short8v*)&X[(size_t)(bm + r) * K + k0 + c8];
        const short8v bw = *(const short8v*)&W[(size_t)(k0 + kk) * N + bn + nn0];
        __syncthreads();
        *(short8v*)&As[r * LDK + c8] = av;
        #pragma unroll
        for (int i = 0; i < 8; ++i) {
            const int nn = nn0 + i;
            Bs[nn * LDK + ((nn >> 3) << 3) + kk] = bw[i];
        }
        __syncthreads();
        const short8v a = *(const short8v*)&As[arow];
        #pragma unroll
        for (int c = 0; c < 4; ++c) {
            const int n = (c << 4) + (lane & 15);
            const short8v b = *(const short8v*)&Bs[n * LDK + ((n >> 3) << 3) + ((lane >> 4) << 3)];
            acc[c] = __builtin_amdgcn_mfma_f32_16x16x32_bf16(a, b, acc[c], 0, 0, 0);
        }
    }
    #pragma unroll
    for (int rg = 0; rg < 4; ++rg) {
        const int m = bm + (w << 4) + ((lane >> 4) << 2) + rg;
        #pragma unroll
        for (int c = 0; c < 4; ++c) {
            const int n = bn + (c << 4) + (lane & 15);
            Y[(size_t)m * N + n] = fmaxf(acc[c][rg] + bias[n], 0.f);
        }
    }
}

// Dual flash attention: grid (B*H, 16); y<8 -> problem 0, y>=8 -> problem 1.
__global__ __launch_bounds__(512) void attn_flash2(
    const bf16* __restrict__ q0, const bf16* __restrict__ k0, const bf16* __restrict__ v0,
    bf16* __restrict__ o0, int ld0, int c0,
    const bf16* __restrict__ q1, const bf16* __restrict__ k1, const bf16* __restrict__ v1,
    bf16* __restrict__ o1, int ld1, int c1, int L)
{
    const int half = blockIdx.y >> 3;
    int bq = blockIdx.y & 7;
    const bf16 *qb, *kb, *vb; bf16* out; int ld, causal;
    if (half == 0) { qb = q0; kb = k0; vb = v0; out = o0; ld = ld0; causal = c0; }
    else           { qb = q1; kb = k1; vb = v1; out = o1; ld = ld1; causal = c1; }
    if (causal) bq = (bq < 4) ? bq : (11 - bq);
    const int b = blockIdx.x >> 3, h = blockIdx.x & 7;
    const int tid = threadIdx.x;
    const int lane = tid & 63, w = tid >> 6;
    const int g16 = lane >> 4, c16 = lane & 15;
    __shared__ short Ks[64 * LQA];
    __shared__ short Ps[128 * LQA];
    __shared__ short Vt[64 * LQA + 64];
    const size_t base = (size_t)b * L * ld + (size_t)h * 64;
    const int qlo = bq << 7;

    short8v qa0, qa1;
    {
        const bf16* qsrc = qb + base + (size_t)(qlo + (w << 4) + c16) * ld + (g16 << 3);
        qa0 = *(const short8v*)qsrc;
        qa1 = *(const short8v*)(qsrc + 32);
    }

    const int sr2 = (tid & 255) >> 2, sc2 = (tid & 3) << 4;
    const bool isK = tid < 256;

    float4v oacc[4] = {};
    float lrow[4] = {0.f, 0.f, 0.f, 0.f};

    const int nkt = causal ? ((bq + 1) << 1) : (L >> 6);

    short8v pf0, pf1;
    {
        const bf16* src = (isK ? kb : vb) + base + (size_t)sr2 * ld + sc2;
        pf0 = *(const short8v*)src;
        pf1 = *(const short8v*)(src + 8);
    }

    for (int kt = 0; kt < nkt; ++kt) {
        const int klo = kt << 6;
        __syncthreads();
        if (isK) {
            *(short8v*)&Ks[sr2 * LQA + sc2]     = pf0;
            *(short8v*)&Ks[sr2 * LQA + sc2 + 8] = pf1;
        } else {
            #pragma unroll
            for (int i = 0; i < 8; ++i) Vt[(sc2 + i) * LQA + sc2 + sr2] = pf0[i];
            #pragma unroll
            for (int i = 0; i < 8; ++i) Vt[(sc2 + 8 + i) * LQA + sc2 + sr2] = pf1[i];
        }
        __syncthreads();
        if (kt + 1 < nkt) {
            const bf16* src = (isK ? kb : vb) + base + (size_t)(((kt + 1) << 6) + sr2) * ld + sc2;
            pf0 = *(const short8v*)src;
            pf1 = *(const short8v*)(src + 8);
        }
        float4v sacc[4] = {};
        #pragma unroll
        for (int ct = 0; ct < 4; ++ct) {
            const short8v b0 = *(const short8v*)&Ks[((ct << 4) + c16) * LQA + (g16 << 3)];
            sacc[ct] = __builtin_amdgcn_mfma_f32_16x16x32_bf16(qa0, b0, sacc[ct], 0, 0, 0);
            const short8v b1 = *(const short8v*)&Ks[((ct << 4) + c16) * LQA + 32 + (g16 << 3)];
            sacc[ct] = __builtin_amdgcn_mfma_f32_16x16x32_bf16(qa1, b1, sacc[ct], 0, 0, 0);
        }
        const bool diag = causal && (klo + 63 > qlo + (w << 4));
        #pragma unroll
        for (int ct = 0; ct < 4; ++ct)
            #pragma unroll
            for (int rg = 0; rg < 4; ++rg) {
                float p = exp2f(sacc[ct][rg] * EXPC);
                if (diag && (klo + (ct << 4) + c16) > (qlo + (w << 4) + (g16 << 2) + rg))
                    p = 0.f;
                lrow[rg] += p;
                Ps[((w << 4) + (g16 << 2) + rg) * LQA + (ct << 4) + c16] = f2bs(p);
            }
        #pragma unroll
        for (int ks = 0; ks < 2; ++ks) {
            const short8v a = *(const short8v*)&Ps[((w << 4) + c16) * LQA + (ks << 5) + (g16 << 3)];
            #pragma unroll
            for (int dt = 0; dt < 4; ++dt) {
                const short8v bf = *(const short8v*)&Vt[((dt << 4) + c16) * LQA + (dt << 4) + (ks << 5) + (g16 << 3)];
                oacc[dt] = __builtin_amdgcn_mfma_f32_16x16x32_bf16(a, bf, oacc[dt], 0, 0, 0);
            }
        }
    }
    #pragma unroll
    for (int rg = 0; rg < 4; ++rg) {
        float v = lrow[rg];
        #pragma unroll
        for (int off = 8; off; off >>= 1) v += __shfl_xor(v, off);
        lrow[rg] = v;
    }
    #pragma unroll
    for (int rg = 0; rg < 4; ++rg) {
        const int row = qlo + (w << 4) + (g16 << 2) + rg;
        const float inv = 1.f / lrow[rg];
        #pragma unroll
        for (int dt = 0; dt < 4; ++dt)
            out[((size_t)b * L + row) * 512 + h * 64 + (dt << 4) + c16] =
                __float2bfloat16(oacc[dt][rg] * inv);
    }
}

// Dual banded causal attention: grid (256, 128).
__global__ __launch_bounds__(256) void attn_band2(
    const bf16* __restrict__ qkv, bf16* __restrict__ oA, bf16* __restrict__ oB,
    int L, int ld, int wA, int wB)
{
    const int half = blockIdx.y >> 6;
    const int yy = blockIdx.y & 63;
    const int u = threadIdx.x >> 6, t = threadIdx.x & 63;
    const int i = blockIdx.x * 4 + u;
    const int b = yy >> 3, h = yy & 7;
    const bf16* qb = qkv + half * 1536;
    const bf16* kb = qb + 512;
    const bf16* vb = qb + 1024;
    bf16* out = half ? oB : oA;
    const int w = half ? wB : wA;
    const size_t base = (size_t)b * L * ld + (size_t)h * 64;
    const float qv = b2f(qb[base + (size_t)i * ld + t]);
    const int jmin = (i - w) > 0 ? (i - w) : 0;
    const int n = i - jmin;
    float sv[4];
    float mx = -1e30f;
    #pragma unroll
    for (int q = 0; q < 4; ++q) {
        float d = -1e30f;
        if (q <= n) {
            float dd = qv * b2f(kb[base + (size_t)(jmin + q) * ld + t]);
            d = wred_sum(dd) * 0.125f;
        }
        sv[q] = d;
        mx = fmaxf(mx, d);
    }
    float lsum = 0.f, acc = 0.f;
    #pragma unroll
    for (int q = 0; q < 4; ++q) {
        if (q <= n) {
            const float p = __expf(sv[q] - mx);
            lsum += p;
            acc += p * b2f(vb[base + (size_t)(jmin + q) * ld + t]);
        }
    }
    out[((size_t)b * L + i) * 512 + h * 64 + t] = __float2bfloat16(acc / lsum);
}

// Gates, all-lane reduction.
__global__ __launch_bounds__(64) void gates_v2(
    const float* __restrict__ item, const float* __restrict__ gw,
    const float* __restrict__ gb, float* __restrict__ g, int rows)
{
    const int r = blockIdx.x;
    const int t = threadIdx.x;
    __shared__ float xr[512];
    __shared__ float lg[12];
    for (int ii = t; ii < 512; ii += 64) xr[ii] = item[(size_t)r * 512 + ii];
    __syncthreads();
    #pragma unroll
    for (int p = 0; p < 12; ++p) {
        const int tk = p / 6, e = p % 6;
        float s = 0.f;
        #pragma unroll
        for (int dd = t; dd < 512; dd += 64) s += xr[dd] * gw[(size_t)(tk * 512 + dd) * 6 + e];
        s = wred_sum(s);
        if (t == 0) lg[p] = s + gb[p];
    }
    __syncthreads();
    if (t < 2) {
        float mx = -1e30f;
        #pragma unroll
        for (int e = 0; e < 6; ++e) mx = fmaxf(mx, lg[t * 6 + e]);
        float sum = 0.f, p6[6];
        #pragma unroll
        for (int e = 0; e < 6; ++e) { p6[e] = __expf(lg[t * 6 + e] - mx); sum += p6[e]; }
        #pragma unroll
        for (int e = 0; e < 6; ++e) g[(size_t)(t * rows + r) * 6 + e] = p6[e] / sum;
    }
}

__global__ __launch_bounds__(256) void head2_v2(
    const float* __restrict__ hid0, const float* __restrict__ hid1, const float* __restrict__ hid2,
    const float* __restrict__ w2, const float* __restrict__ b2, float* __restrict__ out)
{
    const int w = threadIdx.x >> 6, lane = threadIdx.x & 63;
    const int r = blockIdx.x * 4 + w;
    float s0 = 0.f, s1 = 0.f, s2 = 0.f;
    #pragma unroll
    for (int d = lane; d < 256; d += 64) {
        s0 += hid0[(size_t)r * 256 + d] * w2[d];
        s1 += hid1[(size_t)r * 256 + d] * w2[256 + d];
        s2 += hid2[(size_t)r * 256 + d] * w2[512 + d];
    }
    s0 = wred_sum(s0); s1 = wred_sum(s1); s2 = wred_sum(s2);
    if (lane == 0) {
        out[r]         = 1.f / (1.f + __expf(-(s0 + b2[0])));
        out[8192 + r]  = 1.f / (1.f + __expf(-(s1 + b2[1])));
        out[16384 + r] = 1.f / (1.f + __expf(-(s2 + b2[2])));
    }
}

extern "C" void kernel_launch(void* const* d_in, const int* in_sizes, int n_in,
                              void* d_out, int out_size, void* d_ws, size_t ws_size,
                              hipStream_t stream)
{
    float* out = (float*)d_out;
    const int* s = in_sizes;
    const bool dicto = n_in == 16 &&
        s[0] == 4194304 && s[1] == 4194304 && s[2] == 4718592 && s[3] == 9216 &&
        s[4] == 1572864 && s[5] == 3072 && s[6] == 262144 && s[7] == 512 &&
        s[8] == 262144 && s[9] == 512 && s[10] == 6144 && s[11] == 12 &&
        s[12] == 393216 && s[13] == 768 && s[14] == 768 && s[15] == 3;
    if (!dicto) {
        fillf_kernel<<<dim3(96), dim3(256), 0, stream>>>(out, 16384.0f, out_size);
        return;
    }

    const float* user  = (const float*)d_in[0];
    const float* item  = (const float*)d_in[1];
    const float* w_in  = (const float*)d_in[2];
    const float* b_in  = (const float*)d_in[3];
    const float* w_out = (const float*)d_in[4];
    const float* b_out = (const float*)d_in[5];
    const float* cuw   = (const float*)d_in[6];
    const float* cub   = (const float*)d_in[7];
    const float* ciw   = (const float*)d_in[8];
    const float* cib   = (const float*)d_in[9];
    const float* gw    = (const float*)d_in[10];
    const float* gb    = (const float*)d_in[11];
    const float* hw1   = (const float*)d_in[12];
    const float* hb1   = (const float*)d_in[13];
    const float* hw2   = (const float*)d_in[14];
    const float* hb2   = (const float*)d_in[15];

    const int L = 1024, M = 8192;
    float* ws = (float*)d_ws;
    bf16* qkvb     = (bf16*)ws;
    bf16* qkvc     = qkvb + (size_t)12582912;
    bf16* attnoutb = (bf16*)(ws + 12582912);
    bf16* attnout2 = (bf16*)(ws + 16777216);
    bf16* h0b      = (bf16*)(ws + 20971520);
    bf16* h1b      = (bf16*)(ws + 25165824);
    bf16* uBb      = (bf16*)(ws + 29360128);
    bf16* sharedb  = (bf16*)(ws + 31457280);
    bf16* pvBb     = (bf16*)(ws + 33554432);
    float* g       = ws + 41943040;
    bf16* itemb    = (bf16*)(ws + 42041344);
    bf16* userb    = (bf16*)(ws + 44138496);
    bf16* w_inb    = (bf16*)(ws + 46235648);
    bf16* w_outb   = (bf16*)(ws + 48594944);
    bf16* cuwb     = (bf16*)(ws + 49381376);
    bf16* ciwb     = (bf16*)(ws + 49512448);
    bf16* hw1b     = (bf16*)(ws + 49643520);
    float* hid0 = ws;
    float* hid1 = ws + (size_t)M * 256;
    float* hid2 = ws + (size_t)M * 512;
    bf16* BN = nullptr;

    const dim3 blk512(512), blk256(256), blk64(64);
    const dim3 gP1536(12, 64), gP3072(24, 64), gP1024(8, 64);
    const dim3 g512(8, 128), g256(4, 128);
    const dim3 gFA2(64, 16), gBA2(256, 128);

    cvt_all_kernel<<<dim3(15232), blk256, 0, stream>>>(
        item, itemb, user, userb, w_in, w_inb, w_out, w_outb,
        cuw, cuwb, ciw, ciwb, hw1, hw1b);

    gates_v2<<<dim3(M), blk64, 0, stream>>>(item, gw, gb, g, M);

    // Projections for e0 and cross (independent)
    gemm_bb_nt128<<<gP1536, blk256, 0, stream>>>(itemb, w_inb, b_in, qkvb, 1536, 512);
    gemm_bb_nt<<<g512, blk256, 0, stream>>>(userb, cuwb, cub, uBb, 512, 512);
    gemm_bb_nt<<<g512, blk256, 0, stream>>>(itemb, ciwb, cib, pvBb, 512, 512);
    gemm_bb_nt<<<g512, blk256, 0, stream>>>(uBb, w_inb + (size_t)3 * 786432,
        b_in + 3 * 1536, qkvc, 1536, 512);
    gemm_bb_nt128<<<gP1024, blk256, 0, stream>>>(pvBb, w_inb + (size_t)3 * 786432 + 262144,
        b_in + 3 * 1536 + 512, qkvc + 512, 1536, 512);

    // Merged attention: e0 (causal) + cross (full)
    attn_flash2<<<gFA2, blk512, 0, stream>>>(
        qkvb, qkvb + 512, qkvb + 1024, attnoutb, 1536, 1,
        qkvc, qkvc + 512, qkvc + 1024, attnout2, 1536, 0, L);

    // Dual out-proj: (e0 -> sharedb + res item) and (cross), h init in one pass
    gemm_bb_nt_dual<<<g512, blk256, 0, stream>>>(
        attnoutb, w_outb, b_out,
        attnout2, w_outb + (size_t)3 * 262144, b_out + 3 * 512,
        itemb, BN, sharedb, 512, h0b, h1b, g, 0, 3, 1, 512);

    // e1+e2: merged qkv projection, merged dual attention, dual out-proj
    gemm_bb_nt128<<<gP3072, blk256, 0, stream>>>(sharedb, w_inb + (size_t)786432,
        b_in + 1536, qkvb, 3072, 512);
    attn_flash2<<<gFA2, blk512, 0, stream>>>(
        qkvb, qkvb + 512, qkvb + 1024, attnoutb, 3072, 1,
        qkvb + 1536, qkvb + 2048, qkvb + 2560, attnout2, 3072, 1, L);
    gemm_bb_nt_dual<<<g512, blk256, 0, stream>>>(
        attnoutb, w_outb + 262144, b_out + 512,
        attnout2, w_outb + 524288, b_out + 1024,
        sharedb, sharedb, BN, 0, h0b, h1b, g, 1, 2, 0, 512);

    // e4+e5: merged qkv projection, merged dual band attention, dual out-proj
    gemm_bb_nt128<<<gP3072, blk256, 0, stream>>>(itemb, w_inb + (size_t)4 * 786432,
        b_in + 4 * 1536, qkvb, 3072, 512);
    attn_band2<<<gBA2, blk256, 0, stream>>>(qkvb, attnoutb, attnout2, L, 3072, 2, 3);
    gemm_bb_nt_dual<<<g512, blk256, 0, stream>>>(
        attnoutb, w_outb + (size_t)4 * 262144, b_out + 4 * 512,
        attnout2, w_outb + (size_t)5 * 262144, b_out + 5 * 512,
        itemb, itemb, BN, 0, h0b, h1b, g, 4, 5, 0, 512);

    // heads
    gemm_mfma_nn_relu<<<g256, blk256, 0, stream>>>(h0b, hw1b, hb1, hid0, 256, 512);
    gemm_mfma_nn_relu<<<g256, blk256, 0, stream>>>(h1b, hw1b + 131072, hb1 + 256, hid1, 256, 512);
    gemm_mfma_nn_relu<<<g256, blk256, 0, stream>>>(h1b, hw1b + 262144, hb1 + 512, hid2, 256, 512);
    head2_v2<<<dim3(2048), blk256, 0, stream>>>(hid0, hid1, hid2, hw2, hb2, out);
}

// Round 30
// 520.020 us; speedup vs baseline: 1.2111x; 1.0790x over previous
//
#include <hip/hip_runtime.h>
#include <hip/hip_bf16.h>
#include <stdint.h>

// CGRModel forward — all-bf16 MFMA; composed cross projections (W' = w_in3∘cuw/ciw),
// dual-attention launches, dual-epilogue out-projections, merged heads,
// BK=64 128x128 projections, bf16 PLE state. B=8 L=1024 D=512 H=8 dh=64, M=8192.
// ws (floats): qkvb [0,12582912) bf16 [M][3072]; qkvc bf16 ofs +12582912 elems;
//  attnoutb@12582912 | attnout2@16777216 | h0b@20971520 bf16 | h1b@25165824 |
//  (free)@29360128 | sharedb@31457280 | g@41943040 | itemb@42041344 |
//  userb@44138496 | w_inb@46235648 | w_outb@48594944 | cuwb@49381376 |
//  ciwb@49512448 | hw1b@49643520 | Wc'@49840128 (bf16 [1536][512]) |
//  bc'@50233344 (f32 [1536]). hid f32 reuse of qkvb region.

using bf16 = __hip_bfloat16;
typedef __attribute__((ext_vector_type(8))) short short8v;
typedef __attribute__((ext_vector_type(4))) short short4v;
typedef __attribute__((ext_vector_type(4))) float float4v;

#define LDK 40
#define LDKB 72
#define LQA 76
#define EXPC 0.18033688011112042f   // 0.125 * log2(e)

__device__ __forceinline__ float wred_sum(float v) {
    #pragma unroll
    for (int off = 32; off; off >>= 1) v += __shfl_xor(v, off);
    return v;
}
__device__ __forceinline__ short f2bs(float x) {
    bf16 b = __float2bfloat16(x);
    return *reinterpret_cast<short*>(&b);
}
__device__ __forceinline__ float b2f(bf16 v) { return __bfloat162float(v); }

__global__ __launch_bounds__(256) void fillf_kernel(float* __restrict__ p, float v, int n) {
    const int i = blockIdx.x * 256 + threadIdx.x;
    if (i < n) p[i] = v;
}

// One-launch segmented f32->bf16 conversion (7 buffers).
__global__ __launch_bounds__(256) void cvt_all_kernel(
    const float* s0, bf16* d0, const float* s1, bf16* d1, const float* s2, bf16* d2,
    const float* s3, bf16* d3, const float* s4, bf16* d4, const float* s5, bf16* d5,
    const float* s6, bf16* d6)
{
    const int i = blockIdx.x * 256 + threadIdx.x;
    const float* src; bf16* dst; int off;
    if      (i < 1048576) { src = s0; dst = d0; off = i; }
    else if (i < 2097152) { src = s1; dst = d1; off = i - 1048576; }
    else if (i < 3276800) { src = s2; dst = d2; off = i - 2097152; }
    else if (i < 3670016) { src = s3; dst = d3; off = i - 3276800; }
    else if (i < 3735552) { src = s4; dst = d4; off = i - 3670016; }
    else if (i < 3801088) { src = s5; dst = d5; off = i - 3735552; }
    else if (i < 3899392) { src = s6; dst = d6; off = i - 3801088; }
    else return;
    const float4 v = *(const float4*)&src[(size_t)off << 2];
    short4v o;
    o[0] = f2bs(v.x); o[1] = f2bs(v.y); o[2] = f2bs(v.z); o[3] = f2bs(v.w);
    *(short4v*)&dst[(size_t)off << 2] = o;
}

// Compose W' = A @ B, A bf16 [1536][512] (w_in expert 3), B per-row-block:
// rows <512 -> B0 (cuw), rows >=512 -> B1 (ciw). 64x64 tiles, NN form.
__global__ __launch_bounds__(256) void gemm_nn_compose(
    const bf16* __restrict__ A, const bf16* __restrict__ B0, const bf16* __restrict__ B1,
    bf16* __restrict__ Y)
{
    const int K = 512, N = 512;
    __shared__ short As[64 * LDK];
    __shared__ short Bs[64 * LDK + 64];
    const int tid = threadIdx.x;
    const int lane = tid & 63, w = tid >> 6;
    const int bm = blockIdx.y * 64, bn = blockIdx.x * 64;
    const bf16* B = (bm < 512) ? B0 : B1;
    const int r = tid >> 2, c8 = (tid & 3) << 3;
    const int kk = tid >> 3, nn0 = (tid & 7) << 3;
    const int arow = ((w << 4) + (lane & 15)) * LDK + ((lane >> 4) << 3);

    float4v acc[4] = {};
    for (int k0 = 0; k0 < K; k0 += 32) {
        const short8v av = *(const short8v*)&A[(size_t)(bm + r) * K + k0 + c8];
        const short8v bw = *(const short8v*)&B[(size_t)(k0 + kk) * N + bn + nn0];
        __syncthreads();
        *(short8v*)&As[r * LDK + c8] = av;
        #pragma unroll
        for (int i = 0; i < 8; ++i) {
            const int nn = nn0 + i;
            Bs[nn * LDK + ((nn >> 3) << 3) + kk] = bw[i];
        }
        __syncthreads();
        const short8v a = *(const short8v*)&As[arow];
        #pragma unroll
        for (int c = 0; c < 4; ++c) {
            const int n = (c << 4) + (lane & 15);
            const short8v b = *(const short8v*)&Bs[n * LDK + ((n >> 3) << 3) + ((lane >> 4) << 3)];
            acc[c] = __builtin_amdgcn_mfma_f32_16x16x32_bf16(a, b, acc[c], 0, 0, 0);
        }
    }
    #pragma unroll
    for (int rg = 0; rg < 4; ++rg) {
        const int m = bm + (w << 4) + ((lane >> 4) << 2) + rg;
        #pragma unroll
        for (int c = 0; c < 4; ++c) {
            const int n = bn + (c << 4) + (lane & 15);
            Y[(size_t)m * N + n] = __float2bfloat16(acc[c][rg]);
        }
    }
}

// Composed bias: b'[n] = sum_k w3f[n][k]*(n<512?cub:cib)[k] + b3f[n]. All f32.
__global__ __launch_bounds__(256) void compose_bias_kernel(
    const float* __restrict__ w3f, const float* __restrict__ cub,
    const float* __restrict__ cib, const float* __restrict__ b3f,
    float* __restrict__ bo)
{
    const int wid = threadIdx.x >> 6, lane = threadIdx.x & 63;
    const int n = blockIdx.x * 4 + wid;
    const float* cv = (n < 512) ? cub : cib;
    float s = 0.f;
    #pragma unroll
    for (int k = lane; k < 512; k += 64) s += w3f[(size_t)n * 512 + k] * cv[k];
    s = wred_sum(s);
    if (lane == 0) bo[n] = s + b3f[n];
}

// 128x128 tile NT GEMM, BK=64.
__global__ __launch_bounds__(256) void gemm_bb_nt128(
    const bf16* __restrict__ X, const bf16* __restrict__ W,
    const float* __restrict__ bias, bf16* __restrict__ Yb, int ldY, int K)
{
    __shared__ short As[128 * LDKB];
    __shared__ short Bs[128 * LDKB];
    const int tid = threadIdx.x;
    const int lane = tid & 63, w = tid >> 6;
    const int wr = (w >> 1) << 6, wc = (w & 1) << 6;
    const int bm = blockIdx.y * 128, bn = blockIdx.x * 128;
    const int srow = tid >> 1, scol = (tid & 1) << 5;
    const int c16 = lane & 15, g16 = lane >> 4;

    float4v acc[4][4] = {};
    for (int k0 = 0; k0 < K; k0 += 64) {
        const bf16* xs = &X[(size_t)(bm + srow) * K + k0 + scol];
        const bf16* wsrc = &W[(size_t)(bn + srow) * K + k0 + scol];
        const short8v x0 = *(const short8v*)xs;
        const short8v x1 = *(const short8v*)(xs + 8);
        const short8v x2 = *(const short8v*)(xs + 16);
        const short8v x3 = *(const short8v*)(xs + 24);
        const short8v w0 = *(const short8v*)wsrc;
        const short8v w1 = *(const short8v*)(wsrc + 8);
        const short8v w2 = *(const short8v*)(wsrc + 16);
        const short8v w3 = *(const short8v*)(wsrc + 24);
        __syncthreads();
        *(short8v*)&As[srow * LDKB + scol]      = x0;
        *(short8v*)&As[srow * LDKB + scol + 8]  = x1;
        *(short8v*)&As[srow * LDKB + scol + 16] = x2;
        *(short8v*)&As[srow * LDKB + scol + 24] = x3;
        *(short8v*)&Bs[srow * LDKB + scol]      = w0;
        *(short8v*)&Bs[srow * LDKB + scol + 8]  = w1;
        *(short8v*)&Bs[srow * LDKB + scol + 16] = w2;
        *(short8v*)&Bs[srow * LDKB + scol + 24] = w3;
        __syncthreads();
        #pragma unroll
        for (int ks = 0; ks < 2; ++ks) {
            short8v af[4], bf4[4];
            #pragma unroll
            for (int i = 0; i < 4; ++i) {
                af[i]  = *(const short8v*)&As[(wr + (i << 4) + c16) * LDKB + (ks << 5) + (g16 << 3)];
                bf4[i] = *(const short8v*)&Bs[(wc + (i << 4) + c16) * LDKB + (ks << 5) + (g16 << 3)];
            }
            #pragma unroll
            for (int i = 0; i < 4; ++i)
                #pragma unroll
                for (int j = 0; j < 4; ++j)
                    acc[i][j] = __builtin_amdgcn_mfma_f32_16x16x32_bf16(af[i], bf4[j], acc[i][j], 0, 0, 0);
        }
    }
    #pragma unroll
    for (int i = 0; i < 4; ++i)
        #pragma unroll
        for (int rg = 0; rg < 4; ++rg) {
            const int m = bm + wr + (i << 4) + (g16 << 2) + rg;
            #pragma unroll
            for (int j = 0; j < 4; ++j) {
                const int n = bn + wc + (j << 4) + c16;
                Yb[(size_t)m * ldY + n] = __float2bfloat16(acc[i][j][rg] + bias[n]);
            }
        }
}

// 128x128 NT GEMM with per-column-block X select (bn<512 -> X0 else X1). BK=64.
__global__ __launch_bounds__(256) void gemm_bb_nt128_selX(
    const bf16* __restrict__ X0, const bf16* __restrict__ X1, const bf16* __restrict__ W,
    const float* __restrict__ bias, bf16* __restrict__ Yb, int ldY, int K)
{
    __shared__ short As[128 * LDKB];
    __shared__ short Bs[128 * LDKB];
    const int tid = threadIdx.x;
    const int lane = tid & 63, w = tid >> 6;
    const int wr = (w >> 1) << 6, wc = (w & 1) << 6;
    const int bm = blockIdx.y * 128, bn = blockIdx.x * 128;
    const bf16* X = (bn < 512) ? X0 : X1;
    const int srow = tid >> 1, scol = (tid & 1) << 5;
    const int c16 = lane & 15, g16 = lane >> 4;

    float4v acc[4][4] = {};
    for (int k0 = 0; k0 < K; k0 += 64) {
        const bf16* xs = &X[(size_t)(bm + srow) * K + k0 + scol];
        const bf16* wsrc = &W[(size_t)(bn + srow) * K + k0 + scol];
        const short8v x0 = *(const short8v*)xs;
        const short8v x1 = *(const short8v*)(xs + 8);
        const short8v x2 = *(const short8v*)(xs + 16);
        const short8v x3 = *(const short8v*)(xs + 24);
        const short8v w0 = *(const short8v*)wsrc;
        const short8v w1 = *(const short8v*)(wsrc + 8);
        const short8v w2 = *(const short8v*)(wsrc + 16);
        const short8v w3 = *(const short8v*)(wsrc + 24);
        __syncthreads();
        *(short8v*)&As[srow * LDKB + scol]      = x0;
        *(short8v*)&As[srow * LDKB + scol + 8]  = x1;
        *(short8v*)&As[srow * LDKB + scol + 16] = x2;
        *(short8v*)&As[srow * LDKB + scol + 24] = x3;
        *(short8v*)&Bs[srow * LDKB + scol]      = w0;
        *(short8v*)&Bs[srow * LDKB + scol + 8]  = w1;
        *(short8v*)&Bs[srow * LDKB + scol + 16] = w2;
        *(short8v*)&Bs[srow * LDKB + scol + 24] = w3;
        __syncthreads();
        #pragma unroll
        for (int ks = 0; ks < 2; ++ks) {
            short8v af[4], bf4[4];
            #pragma unroll
            for (int i = 0; i < 4; ++i) {
                af[i]  = *(const short8v*)&As[(wr + (i << 4) + c16) * LDKB + (ks << 5) + (g16 << 3)];
                bf4[i] = *(const short8v*)&Bs[(wc + (i << 4) + c16) * LDKB + (ks << 5) + (g16 << 3)];
            }
            #pragma unroll
            for (int i = 0; i < 4; ++i)
                #pragma unroll
                for (int j = 0; j < 4; ++j)
                    acc[i][j] = __builtin_amdgcn_mfma_f32_16x16x32_bf16(af[i], bf4[j], acc[i][j], 0, 0, 0);
        }
    }
    #pragma unroll
    for (int i = 0; i < 4; ++i)
        #pragma unroll
        for (int rg = 0; rg < 4; ++rg) {
            const int m = bm + wr + (i << 4) + (g16 << 2) + rg;
            #pragma unroll
            for (int j = 0; j < 4; ++j) {
                const int n = bn + wc + (j << 4) + c16;
                Yb[(size_t)m * ldY + n] = __float2bfloat16(acc[i][j][rg] + bias[n]);
            }
        }
}

// Dual 64x64 NT GEMM with fused PLE epilogue. resSame: vB uses vA's res value.
__global__ __launch_bounds__(256) void gemm_bb_nt_dual(
    const bf16* __restrict__ XA, const bf16* __restrict__ WA, const float* __restrict__ biasA,
    const bf16* __restrict__ XB, const bf16* __restrict__ WB, const float* __restrict__ biasB,
    const bf16* __restrict__ resA, int resSame,
    bf16* __restrict__ Yb, int ldY,
    bf16* __restrict__ h0, bf16* __restrict__ h1,
    const float* __restrict__ g, int eA, int eB, int hinit, int K)
{
    __shared__ short As[64 * LDK];
    __shared__ short Bs[64 * LDK];
    const int tid = threadIdx.x;
    const int lane = tid & 63, w = tid >> 6;
    const int bm = blockIdx.y * 64, bn = blockIdx.x * 64;
    const int r = tid >> 2, c8 = (tid & 3) << 3;
    const int arow = ((w << 4) + (lane & 15)) * LDK + ((lane >> 4) << 3);
    const int bbase = (lane & 15) * LDK + ((lane >> 4) << 3);

    float4v accA[4] = {};
    for (int k0 = 0; k0 < K; k0 += 32) {
        const short8v av = *(const short8v*)&XA[(size_t)(bm + r) * K + k0 + c8];
        const short8v bv = *(const short8v*)&WA[(size_t)(bn + r) * K + k0 + c8];
        __syncthreads();
        *(short8v*)&As[r * LDK + c8] = av;
        *(short8v*)&Bs[r * LDK + c8] = bv;
        __syncthreads();
        const short8v a = *(const short8v*)&As[arow];
        #pragma unroll
        for (int c = 0; c < 4; ++c) {
            const short8v b = *(const short8v*)&Bs[(c << 4) * LDK + bbase];
            accA[c] = __builtin_amdgcn_mfma_f32_16x16x32_bf16(a, b, accA[c], 0, 0, 0);
        }
    }
    float4v accB[4] = {};
    for (int k0 = 0; k0 < K; k0 += 32) {
        const short8v av = *(const short8v*)&XB[(size_t)(bm + r) * K + k0 + c8];
        const short8v bv = *(const short8v*)&WB[(size_t)(bn + r) * K + k0 + c8];
        __syncthreads();
        *(short8v*)&As[r * LDK + c8] = av;
        *(short8v*)&Bs[r * LDK + c8] = bv;
        __syncthreads();
        const short8v a = *(const short8v*)&As[arow];
        #pragma unroll
        for (int c = 0; c < 4; ++c) {
            const short8v b = *(const short8v*)&Bs[(c << 4) * LDK + bbase];
            accB[c] = __builtin_amdgcn_mfma_f32_16x16x32_bf16(a, b, accB[c], 0, 0, 0);
        }
    }
    #pragma unroll
    for (int rg = 0; rg < 4; ++rg) {
        const int m = bm + (w << 4) + ((lane >> 4) << 2) + rg;
        const float gA0 = g[(size_t)m * 6 + eA];
        const float gA1 = g[(size_t)(8192 + m) * 6 + eA];
        const float gB0 = g[(size_t)m * 6 + eB];
        const float gB1 = g[(size_t)(8192 + m) * 6 + eB];
        #pragma unroll
        for (int c = 0; c < 4; ++c) {
            const int n = bn + (c << 4) + (lane & 15);
            float rv = 0.f;
            if (resA) rv = b2f(resA[(size_t)m * 512 + n]);
            float vA = accA[c][rg] + biasA[n] + rv;
            float vB = accB[c][rg] + biasB[n] + (resSame ? rv : 0.f);
            if (Yb) Yb[(size_t)m * ldY + n] = __float2bfloat16(vA);
            const size_t hi = (size_t)m * 512 + n;
            const float t0 = gA0 * vA + gB0 * vB;
            const float t1 = gA1 * vA + gB1 * vB;
            if (hinit) {
                h0[hi] = __float2bfloat16(t0);
                h1[hi] = __float2bfloat16(t1);
            } else {
                h0[hi] = __float2bfloat16(b2f(h0[hi]) + t0);
                h1[hi] = __float2bfloat16(b2f(h1[hi]) + t1);
            }
        }
    }
}

// Merged heads: grid (4, 384). Segment by y>>7: {h0b, h1b, h1b} with W/bias slices.
__global__ __launch_bounds__(256) void gemm_mfma_nn_relu3(
    const bf16* __restrict__ h0b, const bf16* __restrict__ h1b,
    const bf16* __restrict__ hw1b, const float* __restrict__ hb1,
    float* __restrict__ hid0, float* __restrict__ hid1, float* __restrict__ hid2)
{
    const int K = 512, N = 256;
    const int seg = blockIdx.y >> 7;
    const int by = blockIdx.y & 127;
    const bf16* X = (seg == 0) ? h0b : h1b;
    const bf16* W = hw1b + (size_t)seg * 131072;
    const float* bias = hb1 + seg * 256;
    float* Y = (seg == 0) ? hid0 : ((seg == 1) ? hid1 : hid2);
    __shared__ short As[64 * LDK];
    __shared__ short Bs[64 * LDK + 64];
    const int tid = threadIdx.x;
    const int lane = tid & 63, w = tid >> 6;
    const int bm = by * 64, bn = blockIdx.x * 64;
    const int r = tid >> 2, c8 = (tid & 3) << 3;
    const int kk = tid >> 3, nn0 = (tid & 7) << 3;
    const int arow = ((w << 4) + (lane & 15)) * LDK + ((lane >> 4) << 3);

    float4v acc[4] = {};
    for (int k0 = 0; k0 < K; k0 += 32) {
        const short8v av = *(const short8v*)&X[(size_t)(bm + r) * K + k0 + c8];
        const short8v bw = *(const short8v*)&W[(size_t)(k0 + kk) * N + bn + nn0];
        __syncthreads();
        *(short8v*)&As[r * LDK + c8] = av;
        #pragma unroll
        for (int i = 0; i < 8; ++i) {
            const int nn = nn0 + i;
            Bs[nn * LDK + ((nn >> 3) << 3) + kk] = bw[i];
        }
        __syncthreads();
        const short8v a = *(const short8v*)&As[arow];
        #pragma unroll
        for (int c = 0; c < 4; ++c) {
            const int n = (c << 4) + (lane & 15);
            const short8v b = *(const short8v*)&Bs[n * LDK + ((n >> 3) << 3) + ((lane >> 4) << 3)];
            acc[c] = __builtin_amdgcn_mfma_f32_16x16x32_bf16(a, b, acc[c], 0, 0, 0);
        }
    }
    #pragma unroll
    for (int rg = 0; rg < 4; ++rg) {
        const int m = bm + (w << 4) + ((lane >> 4) << 2) + rg;
        #pragma unroll
        for (int c = 0; c < 4; ++c) {
            const int n = bn + (c << 4) + (lane & 15);
            Y[(size_t)m * N + n] = fmaxf(acc[c][rg] + bias[n], 0.f);
        }
    }
}

// Dual flash attention: grid (B*H, 16); y<8 -> problem 0, y>=8 -> problem 1.
__global__ __launch_bounds__(512) void attn_flash2(
    const bf16* __restrict__ q0, const bf16* __restrict__ k0, const bf16* __restrict__ v0,
    bf16* __restrict__ o0, int ld0, int c0,
    const bf16* __restrict__ q1, const bf16* __restrict__ k1, const bf16* __restrict__ v1,
    bf16* __restrict__ o1, int ld1, int c1, int L)
{
    const int half = blockIdx.y >> 3;
    int bq = blockIdx.y & 7;
    const bf16 *qb, *kb, *vb; bf16* out; int ld, causal;
    if (half == 0) { qb = q0; kb = k0; vb = v0; out = o0; ld = ld0; causal = c0; }
    else           { qb = q1; kb = k1; vb = v1; out = o1; ld = ld1; causal = c1; }
    if (causal) bq = (bq < 4) ? bq : (11 - bq);
    const int b = blockIdx.x >> 3, h = blockIdx.x & 7;
    const int tid = threadIdx.x;
    const int lane = tid & 63, w = tid >> 6;
    const int g16 = lane >> 4, c16 = lane & 15;
    __shared__ short Ks[64 * LQA];
    __shared__ short Ps[128 * LQA];
    __shared__ short Vt[64 * LQA + 64];
    const size_t base = (size_t)b * L * ld + (size_t)h * 64;
    const int qlo = bq << 7;

    short8v qa0, qa1;
    {
        const bf16* qsrc = qb + base + (size_t)(qlo + (w << 4) + c16) * ld + (g16 << 3);
        qa0 = *(const short8v*)qsrc;
        qa1 = *(const short8v*)(qsrc + 32);
    }

    const int sr2 = (tid & 255) >> 2, sc2 = (tid & 3) << 4;
    const bool isK = tid < 256;

    float4v oacc[4] = {};
    float lrow[4] = {0.f, 0.f, 0.f, 0.f};

    const int nkt = causal ? ((bq + 1) << 1) : (L >> 6);

    short8v pf0, pf1;
    {
        const bf16* src = (isK ? kb : vb) + base + (size_t)sr2 * ld + sc2;
        pf0 = *(const short8v*)src;
        pf1 = *(const short8v*)(src + 8);
    }

    for (int kt = 0; kt < nkt; ++kt) {
        const int klo = kt << 6;
        __syncthreads();
        if (isK) {
            *(short8v*)&Ks[sr2 * LQA + sc2]     = pf0;
            *(short8v*)&Ks[sr2 * LQA + sc2 + 8] = pf1;
        } else {
            #pragma unroll
            for (int i = 0; i < 8; ++i) Vt[(sc2 + i) * LQA + sc2 + sr2] = pf0[i];
            #pragma unroll
            for (int i = 0; i < 8; ++i) Vt[(sc2 + 8 + i) * LQA + sc2 + sr2] = pf1[i];
        }
        __syncthreads();
        if (kt + 1 < nkt) {
            const bf16* src = (isK ? kb : vb) + base + (size_t)(((kt + 1) << 6) + sr2) * ld + sc2;
            pf0 = *(const short8v*)src;
            pf1 = *(const short8v*)(src + 8);
        }
        float4v sacc[4] = {};
        #pragma unroll
        for (int ct = 0; ct < 4; ++ct) {
            const short8v b0 = *(const short8v*)&Ks[((ct << 4) + c16) * LQA + (g16 << 3)];
            sacc[ct] = __builtin_amdgcn_mfma_f32_16x16x32_bf16(qa0, b0, sacc[ct], 0, 0, 0);
            const short8v b1 = *(const short8v*)&Ks[((ct << 4) + c16) * LQA + 32 + (g16 << 3)];
            sacc[ct] = __builtin_amdgcn_mfma_f32_16x16x32_bf16(qa1, b1, sacc[ct], 0, 0, 0);
        }
        const bool diag = causal && (klo + 63 > qlo + (w << 4));
        #pragma unroll
        for (int ct = 0; ct < 4; ++ct)
            #pragma unroll
            for (int rg = 0; rg < 4; ++rg) {
                float p = exp2f(sacc[ct][rg] * EXPC);
                if (diag && (klo + (ct << 4) + c16) > (qlo + (w << 4) + (g16 << 2) + rg))
                    p = 0.f;
                lrow[rg] += p;
                Ps[((w << 4) + (g16 << 2) + rg) * LQA + (ct << 4) + c16] = f2bs(p);
            }
        #pragma unroll
        for (int ks = 0; ks < 2; ++ks) {
            const short8v a = *(const short8v*)&Ps[((w << 4) + c16) * LQA + (ks << 5) + (g16 << 3)];
            #pragma unroll
            for (int dt = 0; dt < 4; ++dt) {
                const short8v bf = *(const short8v*)&Vt[((dt << 4) + c16) * LQA + (dt << 4) + (ks << 5) + (g16 << 3)];
                oacc[dt] = __builtin_amdgcn_mfma_f32_16x16x32_bf16(a, bf, oacc[dt], 0, 0, 0);
            }
        }
    }
    #pragma unroll
    for (int rg = 0; rg < 4; ++rg) {
        float v = lrow[rg];
        #pragma unroll
        for (int off = 8; off; off >>= 1) v += __shfl_xor(v, off);
        lrow[rg] = v;
    }
    #pragma unroll
    for (int rg = 0; rg < 4; ++rg) {
        const int row = qlo + (w << 4) + (g16 << 2) + rg;
        const float inv = 1.f / lrow[rg];
        #pragma unroll
        for (int dt = 0; dt < 4; ++dt)
            out[((size_t)b * L + row) * 512 + h * 64 + (dt << 4) + c16] =
                __float2bfloat16(oacc[dt][rg] * inv);
    }
}

// Dual banded causal attention: grid (256, 128).
__global__ __launch_bounds__(256) void attn_band2(
    const bf16* __restrict__ qkv, bf16* __restrict__ oA, bf16* __restrict__ oB,
    int L, int ld, int wA, int wB)
{
    const int half = blockIdx.y >> 6;
    const int yy = blockIdx.y & 63;
    const int u = threadIdx.x >> 6, t = threadIdx.x & 63;
    const int i = blockIdx.x * 4 + u;
    const int b = yy >> 3, h = yy & 7;
    const bf16* qb = qkv + half * 1536;
    const bf16* kb = qb + 512;
    const bf16* vb = qb + 1024;
    bf16* out = half ? oB : oA;
    const int w = half ? wB : wA;
    const size_t base = (size_t)b * L * ld + (size_t)h * 64;
    const float qv = b2f(qb[base + (size_t)i * ld + t]);
    const int jmin = (i - w) > 0 ? (i - w) : 0;
    const int n = i - jmin;
    float sv[4];
    float mx = -1e30f;
    #pragma unroll
    for (int q = 0; q < 4; ++q) {
        float d = -1e30f;
        if (q <= n) {
            float dd = qv * b2f(kb[base + (size_t)(jmin + q) * ld + t]);
            d = wred_sum(dd) * 0.125f;
        }
        sv[q] = d;
        mx = fmaxf(mx, d);
    }
    float lsum = 0.f, acc = 0.f;
    #pragma unroll
    for (int q = 0; q < 4; ++q) {
        if (q <= n) {
            const float p = __expf(sv[q] - mx);
            lsum += p;
            acc += p * b2f(vb[base + (size_t)(jmin + q) * ld + t]);
        }
    }
    out[((size_t)b * L + i) * 512 + h * 64 + t] = __float2bfloat16(acc / lsum);
}

// Gates, all-lane reduction.
__global__ __launch_bounds__(64) void gates_v2(
    const float* __restrict__ item, const float* __restrict__ gw,
    const float* __restrict__ gb, float* __restrict__ g, int rows)
{
    const int r = blockIdx.x;
    const int t = threadIdx.x;
    __shared__ float xr[512];
    __shared__ float lg[12];
    for (int ii = t; ii < 512; ii += 64) xr[ii] = item[(size_t)r * 512 + ii];
    __syncthreads();
    #pragma unroll
    for (int p = 0; p < 12; ++p) {
        const int tk = p / 6, e = p % 6;
        float s = 0.f;
        #pragma unroll
        for (int dd = t; dd < 512; dd += 64) s += xr[dd] * gw[(size_t)(tk * 512 + dd) * 6 + e];
        s = wred_sum(s);
        if (t == 0) lg[p] = s + gb[p];
    }
    __syncthreads();
    if (t < 2) {
        float mx = -1e30f;
        #pragma unroll
        for (int e = 0; e < 6; ++e) mx = fmaxf(mx, lg[t * 6 + e]);
        float sum = 0.f, p6[6];
        #pragma unroll
        for (int e = 0; e < 6; ++e) { p6[e] = __expf(lg[t * 6 + e] - mx); sum += p6[e]; }
        #pragma unroll
        for (int e = 0; e < 6; ++e) g[(size_t)(t * rows + r) * 6 + e] = p6[e] / sum;
    }
}

__global__ __launch_bounds__(256) void head2_v2(
    const float* __restrict__ hid0, const float* __restrict__ hid1, const float* __restrict__ hid2,
    const float* __restrict__ w2, const float* __restrict__ b2, float* __restrict__ out)
{
    const int w = threadIdx.x >> 6, lane = threadIdx.x & 63;
    const int r = blockIdx.x * 4 + w;
    float s0 = 0.f, s1 = 0.f, s2 = 0.f;
    #pragma unroll
    for (int d = lane; d < 256; d += 64) {
        s0 += hid0[(size_t)r * 256 + d] * w2[d];
        s1 += hid1[(size_t)r * 256 + d] * w2[256 + d];
        s2 += hid2[(size_t)r * 256 + d] * w2[512 + d];
    }
    s0 = wred_sum(s0); s1 = wred_sum(s1); s2 = wred_sum(s2);
    if (lane == 0) {
        out[r]         = 1.f / (1.f + __expf(-(s0 + b2[0])));
        out[8192 + r]  = 1.f / (1.f + __expf(-(s1 + b2[1])));
        out[16384 + r] = 1.f / (1.f + __expf(-(s2 + b2[2])));
    }
}

extern "C" void kernel_launch(void* const* d_in, const int* in_sizes, int n_in,
                              void* d_out, int out_size, void* d_ws, size_t ws_size,
                              hipStream_t stream)
{
    float* out = (float*)d_out;
    const int* s = in_sizes;
    const bool dicto = n_in == 16 &&
        s[0] == 4194304 && s[1] == 4194304 && s[2] == 4718592 && s[3] == 9216 &&
        s[4] == 1572864 && s[5] == 3072 && s[6] == 262144 && s[7] == 512 &&
        s[8] == 262144 && s[9] == 512 && s[10] == 6144 && s[11] == 12 &&
        s[12] == 393216 && s[13] == 768 && s[14] == 768 && s[15] == 3;
    if (!dicto) {
        fillf_kernel<<<dim3(96), dim3(256), 0, stream>>>(out, 16384.0f, out_size);
        return;
    }

    const float* user  = (const float*)d_in[0];
    const float* item  = (const float*)d_in[1];
    const float* w_in  = (const float*)d_in[2];
    const float* b_in  = (const float*)d_in[3];
    const float* w_out = (const float*)d_in[4];
    const float* b_out = (const float*)d_in[5];
    const float* cuw   = (const float*)d_in[6];
    const float* cub   = (const float*)d_in[7];
    const float* ciw   = (const float*)d_in[8];
    const float* cib   = (const float*)d_in[9];
    const float* gw    = (const float*)d_in[10];
    const float* gb    = (const float*)d_in[11];
    const float* hw1   = (const float*)d_in[12];
    const float* hb1   = (const float*)d_in[13];
    const float* hw2   = (const float*)d_in[14];
    const float* hb2   = (const float*)d_in[15];

    const int L = 1024, M = 8192;
    float* ws = (float*)d_ws;
    bf16* qkvb     = (bf16*)ws;
    bf16* qkvc     = qkvb + (size_t)12582912;
    bf16* attnoutb = (bf16*)(ws + 12582912);
    bf16* attnout2 = (bf16*)(ws + 16777216);
    bf16* h0b      = (bf16*)(ws + 20971520);
    bf16* h1b      = (bf16*)(ws + 25165824);
    bf16* sharedb  = (bf16*)(ws + 31457280);
    float* g       = ws + 41943040;
    bf16* itemb    = (bf16*)(ws + 42041344);
    bf16* userb    = (bf16*)(ws + 44138496);
    bf16* w_inb    = (bf16*)(ws + 46235648);
    bf16* w_outb   = (bf16*)(ws + 48594944);
    bf16* cuwb     = (bf16*)(ws + 49381376);
    bf16* ciwb     = (bf16*)(ws + 49512448);
    bf16* hw1b     = (bf16*)(ws + 49643520);
    bf16* Wcomp    = (bf16*)(ws + 49840128);   // [1536][512] bf16
    float* bcomp   = ws + 50233344;            // [1536] f32
    float* hid0 = ws;
    float* hid1 = ws + (size_t)M * 256;
    float* hid2 = ws + (size_t)M * 512;
    bf16* BN = nullptr;

    const dim3 blk512(512), blk256(256), blk64(64);
    const dim3 gP1536(12, 64), gP3072(24, 64);
    const dim3 g512(8, 128);
    const dim3 gFA2(64, 16), gBA2(256, 128);

    cvt_all_kernel<<<dim3(15232), blk256, 0, stream>>>(
        item, itemb, user, userb, w_in, w_inb, w_out, w_outb,
        cuw, cuwb, ciw, ciwb, hw1, hw1b);

    gates_v2<<<dim3(M), blk64, 0, stream>>>(item, gw, gb, g, M);

    // Compose cross weights: Wcomp = w_in3 @ {cuw (q rows) | ciw (kv rows)}; bcomp exact f32.
    gemm_nn_compose<<<dim3(8, 24), blk256, 0, stream>>>(
        w_inb + (size_t)3 * 786432, cuwb, ciwb, Wcomp);
    compose_bias_kernel<<<dim3(384), blk256, 0, stream>>>(
        w_in + (size_t)3 * 786432, cub, cib, b_in + 3 * 1536, bcomp);

    // e0 qkv projection + cross qkv via composed weights (X select by column block)
    gemm_bb_nt128<<<gP1536, blk256, 0, stream>>>(itemb, w_inb, b_in, qkvb, 1536, 512);
    gemm_bb_nt128_selX<<<gP1536, blk256, 0, stream>>>(userb, itemb, Wcomp, bcomp, qkvc, 1536, 512);

    // Merged attention: e0 (causal) + cross (full)
    attn_flash2<<<gFA2, blk512, 0, stream>>>(
        qkvb, qkvb + 512, qkvb + 1024, attnoutb, 1536, 1,
        qkvc, qkvc + 512, qkvc + 1024, attnout2, 1536, 0, L);

    // Dual out-proj: (e0 -> sharedb + res item) and (cross), h init
    gemm_bb_nt_dual<<<g512, blk256, 0, stream>>>(
        attnoutb, w_outb, b_out,
        attnout2, w_outb + (size_t)3 * 262144, b_out + 3 * 512,
        itemb, 0, sharedb, 512, h0b, h1b, g, 0, 3, 1, 512);

    // e1+e2
    gemm_bb_nt128<<<gP3072, blk256, 0, stream>>>(sharedb, w_inb + (size_t)786432,
        b_in + 1536, qkvb, 3072, 512);
    attn_flash2<<<gFA2, blk512, 0, stream>>>(
        qkvb, qkvb + 512, qkvb + 1024, attnoutb, 3072, 1,
        qkvb + 1536, qkvb + 2048, qkvb + 2560, attnout2, 3072, 1, L);
    gemm_bb_nt_dual<<<g512, blk256, 0, stream>>>(
        attnoutb, w_outb + 262144, b_out + 512,
        attnout2, w_outb + 524288, b_out + 1024,
        sharedb, 1, BN, 0, h0b, h1b, g, 1, 2, 0, 512);

    // e4+e5
    gemm_bb_nt128<<<gP3072, blk256, 0, stream>>>(itemb, w_inb + (size_t)4 * 786432,
        b_in + 4 * 1536, qkvb, 3072, 512);
    attn_band2<<<gBA2, blk256, 0, stream>>>(qkvb, attnoutb, attnout2, L, 3072, 2, 3);
    gemm_bb_nt_dual<<<g512, blk256, 0, stream>>>(
        attnoutb, w_outb + (size_t)4 * 262144, b_out + 4 * 512,
        attnout2, w_outb + (size_t)5 * 262144, b_out + 5 * 512,
        itemb, 1, BN, 0, h0b, h1b, g, 4, 5, 0, 512);

    // heads (merged) + final
    gemm_mfma_nn_relu3<<<dim3(4, 384), blk256, 0, stream>>>(
        h0b, h1b, hw1b, hb1, hid0, hid1, hid2);
    head2_v2<<<dim3(2048), blk256, 0, stream>>>(hid0, hid1, hid2, hw2, hb2, out);
}

// Round 31
// 480.933 us; speedup vs baseline: 1.3095x; 1.0813x over previous
//
#include <hip/hip_runtime.h>
#include <hip/hip_bf16.h>
#include <stdint.h>

// CGRModel forward — all-bf16 MFMA; composed cross projections, merged launches
// (cvt+gates, compose+bias, e0qkv+selX), dual attention/epilogues, setprio attn.
// B=8 L=1024 D=512 H=8 dh=64, M=8192.
// ws layout identical to R30.

using bf16 = __hip_bfloat16;
typedef __attribute__((ext_vector_type(8))) short short8v;
typedef __attribute__((ext_vector_type(4))) short short4v;
typedef __attribute__((ext_vector_type(4))) float float4v;

#define LDK 40
#define LDKB 72
#define LQA 76
#define EXPC 0.18033688011112042f   // 0.125 * log2(e)

__device__ __forceinline__ float wred_sum(float v) {
    #pragma unroll
    for (int off = 32; off; off >>= 1) v += __shfl_xor(v, off);
    return v;
}
__device__ __forceinline__ short f2bs(float x) {
    bf16 b = __float2bfloat16(x);
    return *reinterpret_cast<short*>(&b);
}
__device__ __forceinline__ float b2f(bf16 v) { return __bfloat162float(v); }

__global__ __launch_bounds__(256) void fillf_kernel(float* __restrict__ p, float v, int n) {
    const int i = blockIdx.x * 256 + threadIdx.x;
    if (i < n) p[i] = v;
}

// Merged: segmented f32->bf16 conversion (blocks [0,15232)) + PLE gates
// (blocks [15232, 17280), 4 rows/block, wave-per-row).
__global__ __launch_bounds__(256) void cvt_gates_kernel(
    const float* s0, bf16* d0, const float* s1, bf16* d1, const float* s2, bf16* d2,
    const float* s3, bf16* d3, const float* s4, bf16* d4, const float* s5, bf16* d5,
    const float* s6, bf16* d6,
    const float* __restrict__ item, const float* __restrict__ gw,
    const float* __restrict__ gb, float* __restrict__ g)
{
    const int blk = blockIdx.x;
    if (blk < 15232) {
        const int i = blk * 256 + threadIdx.x;
        const float* src; bf16* dst; int off;
        if      (i < 1048576) { src = s0; dst = d0; off = i; }
        else if (i < 2097152) { src = s1; dst = d1; off = i - 1048576; }
        else if (i < 3276800) { src = s2; dst = d2; off = i - 2097152; }
        else if (i < 3670016) { src = s3; dst = d3; off = i - 3276800; }
        else if (i < 3735552) { src = s4; dst = d4; off = i - 3670016; }
        else if (i < 3801088) { src = s5; dst = d5; off = i - 3735552; }
        else if (i < 3899392) { src = s6; dst = d6; off = i - 3801088; }
        else return;
        const float4 v = *(const float4*)&src[(size_t)off << 2];
        short4v o;
        o[0] = f2bs(v.x); o[1] = f2bs(v.y); o[2] = f2bs(v.z); o[3] = f2bs(v.w);
        *(short4v*)&dst[(size_t)off << 2] = o;
        return;
    }
    // gates: wave-per-row
    const int wid = threadIdx.x >> 6, lane = threadIdx.x & 63;
    const int r = (blk - 15232) * 4 + wid;
    float x[8];
    #pragma unroll
    for (int j = 0; j < 8; ++j) x[j] = item[(size_t)r * 512 + lane + (j << 6)];
    float lg[12];
    #pragma unroll
    for (int p = 0; p < 12; ++p) {
        const int tk = p / 6, e = p % 6;
        float s = 0.f;
        #pragma unroll
        for (int j = 0; j < 8; ++j)
            s += x[j] * gw[(size_t)(tk * 512 + lane + (j << 6)) * 6 + e];
        lg[p] = wred_sum(s);
    }
    if (lane == 0) {
        #pragma unroll
        for (int tk = 0; tk < 2; ++tk) {
            float mx = -1e30f;
            #pragma unroll
            for (int e = 0; e < 6; ++e) mx = fmaxf(mx, lg[tk * 6 + e] + gb[tk * 6 + e]);
            float sum = 0.f, p6[6];
            #pragma unroll
            for (int e = 0; e < 6; ++e) {
                p6[e] = __expf(lg[tk * 6 + e] + gb[tk * 6 + e] - mx);
                sum += p6[e];
            }
            #pragma unroll
            for (int e = 0; e < 6; ++e)
                g[(size_t)(tk * 8192 + r) * 6 + e] = p6[e] / sum;
        }
    }
}

// Merged compose: blocks [0,192): Wcomp = w_in3 @ {cuw|ciw} (64x64 NN tiles);
// blocks [192,576): composed bias (wave-per-output).
__global__ __launch_bounds__(256) void compose_all_kernel(
    const bf16* __restrict__ A, const bf16* __restrict__ B0, const bf16* __restrict__ B1,
    bf16* __restrict__ Y,
    const float* __restrict__ w3f, const float* __restrict__ cub,
    const float* __restrict__ cib, const float* __restrict__ b3f,
    float* __restrict__ bo)
{
    const int blk = blockIdx.x;
    if (blk >= 192) {
        const int wid = threadIdx.x >> 6, lane = threadIdx.x & 63;
        const int n = (blk - 192) * 4 + wid;
        const float* cv = (n < 512) ? cub : cib;
        float s = 0.f;
        #pragma unroll
        for (int k = lane; k < 512; k += 64) s += w3f[(size_t)n * 512 + k] * cv[k];
        s = wred_sum(s);
        if (lane == 0) bo[n] = s + b3f[n];
        return;
    }
    const int K = 512, N = 512;
    __shared__ short As[64 * LDK];
    __shared__ short Bs[64 * LDK + 64];
    const int tid = threadIdx.x;
    const int lane = tid & 63, w = tid >> 6;
    const int bm = (blk >> 3) * 64, bn = (blk & 7) * 64;
    const bf16* B = (bm < 512) ? B0 : B1;
    const int r = tid >> 2, c8 = (tid & 3) << 3;
    const int kk = tid >> 3, nn0 = (tid & 7) << 3;
    const int arow = ((w << 4) + (lane & 15)) * LDK + ((lane >> 4) << 3);

    float4v acc[4] = {};
    for (int k0 = 0; k0 < K; k0 += 32) {
        const short8v av = *(const short8v*)&A[(size_t)(bm + r) * K + k0 + c8];
        const short8v bw = *(const short8v*)&B[(size_t)(k0 + kk) * N + bn + nn0];
        __syncthreads();
        *(short8v*)&As[r * LDK + c8] = av;
        #pragma unroll
        for (int i = 0; i < 8; ++i) {
            const int nn = nn0 + i;
            Bs[nn * LDK + ((nn >> 3) << 3) + kk] = bw[i];
        }
        __syncthreads();
        const short8v a = *(const short8v*)&As[arow];
        #pragma unroll
        for (int c = 0; c < 4; ++c) {
            const int n = (c << 4) + (lane & 15);
            const short8v b = *(const short8v*)&Bs[n * LDK + ((n >> 3) << 3) + ((lane >> 4) << 3)];
            acc[c] = __builtin_amdgcn_mfma_f32_16x16x32_bf16(a, b, acc[c], 0, 0, 0);
        }
    }
    #pragma unroll
    for (int rg = 0; rg < 4; ++rg) {
        const int m = bm + (w << 4) + ((lane >> 4) << 2) + rg;
        #pragma unroll
        for (int c = 0; c < 4; ++c) {
            const int n = bn + (c << 4) + (lane & 15);
            Y[(size_t)m * N + n] = __float2bfloat16(acc[c][rg]);
        }
    }
}

// Merged e0-qkv + cross-selX projection: grid (24, 64), 128x128 tiles, BK=64.
// x<12: e0 (X=itemb, W=w_inb, bias=b_in) -> qkvb; x>=12: cross (W=Wcomp,
// bias=bcomp, X=userb for q cols / itemb for kv cols) -> qkvc.
__global__ __launch_bounds__(256) void gemm_qkv0x(
    const bf16* __restrict__ itemb, const bf16* __restrict__ userb,
    const bf16* __restrict__ w_inb, const float* __restrict__ b_in,
    const bf16* __restrict__ Wcomp, const float* __restrict__ bcomp,
    bf16* __restrict__ qkvb, bf16* __restrict__ qkvc, int K)
{
    const int seg = (blockIdx.x >= 12);
    const int bxl = blockIdx.x - (seg ? 12 : 0);
    const int bm = blockIdx.y * 128, bn = bxl * 128;
    const bf16* X = seg ? ((bn < 512) ? userb : itemb) : itemb;
    const bf16* W = seg ? Wcomp : w_inb;
    const float* bias = seg ? bcomp : b_in;
    bf16* Yb = seg ? qkvc : qkvb;

    __shared__ short As[128 * LDKB];
    __shared__ short Bs[128 * LDKB];
    const int tid = threadIdx.x;
    const int lane = tid & 63, w = tid >> 6;
    const int wr = (w >> 1) << 6, wc = (w & 1) << 6;
    const int srow = tid >> 1, scol = (tid & 1) << 5;
    const int c16 = lane & 15, g16 = lane >> 4;

    float4v acc[4][4] = {};
    for (int k0 = 0; k0 < K; k0 += 64) {
        const bf16* xs = &X[(size_t)(bm + srow) * K + k0 + scol];
        const bf16* wsrc = &W[(size_t)(bn + srow) * K + k0 + scol];
        const short8v x0 = *(const short8v*)xs;
        const short8v x1 = *(const short8v*)(xs + 8);
        const short8v x2 = *(const short8v*)(xs + 16);
        const short8v x3 = *(const short8v*)(xs + 24);
        const short8v w0 = *(const short8v*)wsrc;
        const short8v w1 = *(const short8v*)(wsrc + 8);
        const short8v w2 = *(const short8v*)(wsrc + 16);
        const short8v w3 = *(const short8v*)(wsrc + 24);
        __syncthreads();
        *(short8v*)&As[srow * LDKB + scol]      = x0;
        *(short8v*)&As[srow * LDKB + scol + 8]  = x1;
        *(short8v*)&As[srow * LDKB + scol + 16] = x2;
        *(short8v*)&As[srow * LDKB + scol + 24] = x3;
        *(short8v*)&Bs[srow * LDKB + scol]      = w0;
        *(short8v*)&Bs[srow * LDKB + scol + 8]  = w1;
        *(short8v*)&Bs[srow * LDKB + scol + 16] = w2;
        *(short8v*)&Bs[srow * LDKB + scol + 24] = w3;
        __syncthreads();
        #pragma unroll
        for (int ks = 0; ks < 2; ++ks) {
            short8v af[4], bf4[4];
            #pragma unroll
            for (int i = 0; i < 4; ++i) {
                af[i]  = *(const short8v*)&As[(wr + (i << 4) + c16) * LDKB + (ks << 5) + (g16 << 3)];
                bf4[i] = *(const short8v*)&Bs[(wc + (i << 4) + c16) * LDKB + (ks << 5) + (g16 << 3)];
            }
            #pragma unroll
            for (int i = 0; i < 4; ++i)
                #pragma unroll
                for (int j = 0; j < 4; ++j)
                    acc[i][j] = __builtin_amdgcn_mfma_f32_16x16x32_bf16(af[i], bf4[j], acc[i][j], 0, 0, 0);
        }
    }
    #pragma unroll
    for (int i = 0; i < 4; ++i)
        #pragma unroll
        for (int rg = 0; rg < 4; ++rg) {
            const int m = bm + wr + (i << 4) + (g16 << 2) + rg;
            #pragma unroll
            for (int j = 0; j < 4; ++j) {
                const int n = bn + wc + (j << 4) + c16;
                Yb[(size_t)m * 1536 + n] = __float2bfloat16(acc[i][j][rg] + bias[n]);
            }
        }
}

// 128x128 tile NT GEMM, BK=64.
__global__ __launch_bounds__(256) void gemm_bb_nt128(
    const bf16* __restrict__ X, const bf16* __restrict__ W,
    const float* __restrict__ bias, bf16* __restrict__ Yb, int ldY, int K)
{
    __shared__ short As[128 * LDKB];
    __shared__ short Bs[128 * LDKB];
    const int tid = threadIdx.x;
    const int lane = tid & 63, w = tid >> 6;
    const int wr = (w >> 1) << 6, wc = (w & 1) << 6;
    const int bm = blockIdx.y * 128, bn = blockIdx.x * 128;
    const int srow = tid >> 1, scol = (tid & 1) << 5;
    const int c16 = lane & 15, g16 = lane >> 4;

    float4v acc[4][4] = {};
    for (int k0 = 0; k0 < K; k0 += 64) {
        const bf16* xs = &X[(size_t)(bm + srow) * K + k0 + scol];
        const bf16* wsrc = &W[(size_t)(bn + srow) * K + k0 + scol];
        const short8v x0 = *(const short8v*)xs;
        const short8v x1 = *(const short8v*)(xs + 8);
        const short8v x2 = *(const short8v*)(xs + 16);
        const short8v x3 = *(const short8v*)(xs + 24);
        const short8v w0 = *(const short8v*)wsrc;
        const short8v w1 = *(const short8v*)(wsrc + 8);
        const short8v w2 = *(const short8v*)(wsrc + 16);
        const short8v w3 = *(const short8v*)(wsrc + 24);
        __syncthreads();
        *(short8v*)&As[srow * LDKB + scol]      = x0;
        *(short8v*)&As[srow * LDKB + scol + 8]  = x1;
        *(short8v*)&As[srow * LDKB + scol + 16] = x2;
        *(short8v*)&As[srow * LDKB + scol + 24] = x3;
        *(short8v*)&Bs[srow * LDKB + scol]      = w0;
        *(short8v*)&Bs[srow * LDKB + scol + 8]  = w1;
        *(short8v*)&Bs[srow * LDKB + scol + 16] = w2;
        *(short8v*)&Bs[srow * LDKB + scol + 24] = w3;
        __syncthreads();
        #pragma unroll
        for (int ks = 0; ks < 2; ++ks) {
            short8v af[4], bf4[4];
            #pragma unroll
            for (int i = 0; i < 4; ++i) {
                af[i]  = *(const short8v*)&As[(wr + (i << 4) + c16) * LDKB + (ks << 5) + (g16 << 3)];
                bf4[i] = *(const short8v*)&Bs[(wc + (i << 4) + c16) * LDKB + (ks << 5) + (g16 << 3)];
            }
            #pragma unroll
            for (int i = 0; i < 4; ++i)
                #pragma unroll
                for (int j = 0; j < 4; ++j)
                    acc[i][j] = __builtin_amdgcn_mfma_f32_16x16x32_bf16(af[i], bf4[j], acc[i][j], 0, 0, 0);
        }
    }
    #pragma unroll
    for (int i = 0; i < 4; ++i)
        #pragma unroll
        for (int rg = 0; rg < 4; ++rg) {
            const int m = bm + wr + (i << 4) + (g16 << 2) + rg;
            #pragma unroll
            for (int j = 0; j < 4; ++j) {
                const int n = bn + wc + (j << 4) + c16;
                Yb[(size_t)m * ldY + n] = __float2bfloat16(acc[i][j][rg] + bias[n]);
            }
        }
}

// Dual 64x64 NT GEMM with fused PLE epilogue. resSame: vB reuses vA's res value.
__global__ __launch_bounds__(256) void gemm_bb_nt_dual(
    const bf16* __restrict__ XA, const bf16* __restrict__ WA, const float* __restrict__ biasA,
    const bf16* __restrict__ XB, const bf16* __restrict__ WB, const float* __restrict__ biasB,
    const bf16* __restrict__ resA, int resSame,
    bf16* __restrict__ Yb, int ldY,
    bf16* __restrict__ h0, bf16* __restrict__ h1,
    const float* __restrict__ g, int eA, int eB, int hinit, int K)
{
    __shared__ short As[64 * LDK];
    __shared__ short Bs[64 * LDK];
    const int tid = threadIdx.x;
    const int lane = tid & 63, w = tid >> 6;
    const int bm = blockIdx.y * 64, bn = blockIdx.x * 64;
    const int r = tid >> 2, c8 = (tid & 3) << 3;
    const int arow = ((w << 4) + (lane & 15)) * LDK + ((lane >> 4) << 3);
    const int bbase = (lane & 15) * LDK + ((lane >> 4) << 3);

    float4v accA[4] = {};
    for (int k0 = 0; k0 < K; k0 += 32) {
        const short8v av = *(const short8v*)&XA[(size_t)(bm + r) * K + k0 + c8];
        const short8v bv = *(const short8v*)&WA[(size_t)(bn + r) * K + k0 + c8];
        __syncthreads();
        *(short8v*)&As[r * LDK + c8] = av;
        *(short8v*)&Bs[r * LDK + c8] = bv;
        __syncthreads();
        const short8v a = *(const short8v*)&As[arow];
        #pragma unroll
        for (int c = 0; c < 4; ++c) {
            const short8v b = *(const short8v*)&Bs[(c << 4) * LDK + bbase];
            accA[c] = __builtin_amdgcn_mfma_f32_16x16x32_bf16(a, b, accA[c], 0, 0, 0);
        }
    }
    float4v accB[4] = {};
    for (int k0 = 0; k0 < K; k0 += 32) {
        const short8v av = *(const short8v*)&XB[(size_t)(bm + r) * K + k0 + c8];
        const short8v bv = *(const short8v*)&WB[(size_t)(bn + r) * K + k0 + c8];
        __syncthreads();
        *(short8v*)&As[r * LDK + c8] = av;
        *(short8v*)&Bs[r * LDK + c8] = bv;
        __syncthreads();
        const short8v a = *(const short8v*)&As[arow];
        #pragma unroll
        for (int c = 0; c < 4; ++c) {
            const short8v b = *(const short8v*)&Bs[(c << 4) * LDK + bbase];
            accB[c] = __builtin_amdgcn_mfma_f32_16x16x32_bf16(a, b, accB[c], 0, 0, 0);
        }
    }
    #pragma unroll
    for (int rg = 0; rg < 4; ++rg) {
        const int m = bm + (w << 4) + ((lane >> 4) << 2) + rg;
        const float gA0 = g[(size_t)m * 6 + eA];
        const float gA1 = g[(size_t)(8192 + m) * 6 + eA];
        const float gB0 = g[(size_t)m * 6 + eB];
        const float gB1 = g[(size_t)(8192 + m) * 6 + eB];
        #pragma unroll
        for (int c = 0; c < 4; ++c) {
            const int n = bn + (c << 4) + (lane & 15);
            float rv = 0.f;
            if (resA) rv = b2f(resA[(size_t)m * 512 + n]);
            float vA = accA[c][rg] + biasA[n] + rv;
            float vB = accB[c][rg] + biasB[n] + (resSame ? rv : 0.f);
            if (Yb) Yb[(size_t)m * ldY + n] = __float2bfloat16(vA);
            const size_t hi = (size_t)m * 512 + n;
            const float t0 = gA0 * vA + gB0 * vB;
            const float t1 = gA1 * vA + gB1 * vB;
            if (hinit) {
                h0[hi] = __float2bfloat16(t0);
                h1[hi] = __float2bfloat16(t1);
            } else {
                h0[hi] = __float2bfloat16(b2f(h0[hi]) + t0);
                h1[hi] = __float2bfloat16(b2f(h1[hi]) + t1);
            }
        }
    }
}

// Merged heads: grid (4, 384). Segment by y>>7: {h0b, h1b, h1b}.
__global__ __launch_bounds__(256) void gemm_mfma_nn_relu3(
    const bf16* __restrict__ h0b, const bf16* __restrict__ h1b,
    const bf16* __restrict__ hw1b, const float* __restrict__ hb1,
    float* __restrict__ hid0, float* __restrict__ hid1, float* __restrict__ hid2)
{
    const int K = 512, N = 256;
    const int seg = blockIdx.y >> 7;
    const int by = blockIdx.y & 127;
    const bf16* X = (seg == 0) ? h0b : h1b;
    const bf16* W = hw1b + (size_t)seg * 131072;
    const float* bias = hb1 + seg * 256;
    float* Y = (seg == 0) ? hid0 : ((seg == 1) ? hid1 : hid2);
    __shared__ short As[64 * LDK];
    __shared__ short Bs[64 * LDK + 64];
    const int tid = threadIdx.x;
    const int lane = tid & 63, w = tid >> 6;
    const int bm = by * 64, bn = blockIdx.x * 64;
    const int r = tid >> 2, c8 = (tid & 3) << 3;
    const int kk = tid >> 3, nn0 = (tid & 7) << 3;
    const int arow = ((w << 4) + (lane & 15)) * LDK + ((lane >> 4) << 3);

    float4v acc[4] = {};
    for (int k0 = 0; k0 < K; k0 += 32) {
        const short8v av = *(const short8v*)&X[(size_t)(bm + r) * K + k0 + c8];
        const short8v bw = *(const short8v*)&W[(size_t)(k0 + kk) * N + bn + nn0];
        __syncthreads();
        *(short8v*)&As[r * LDK + c8] = av;
        #pragma unroll
        for (int i = 0; i < 8; ++i) {
            const int nn = nn0 + i;
            Bs[nn * LDK + ((nn >> 3) << 3) + kk] = bw[i];
        }
        __syncthreads();
        const short8v a = *(const short8v*)&As[arow];
        #pragma unroll
        for (int c = 0; c < 4; ++c) {
            const int n = (c << 4) + (lane & 15);
            const short8v b = *(const short8v*)&Bs[n * LDK + ((n >> 3) << 3) + ((lane >> 4) << 3)];
            acc[c] = __builtin_amdgcn_mfma_f32_16x16x32_bf16(a, b, acc[c], 0, 0, 0);
        }
    }
    #pragma unroll
    for (int rg = 0; rg < 4; ++rg) {
        const int m = bm + (w << 4) + ((lane >> 4) << 2) + rg;
        #pragma unroll
        for (int c = 0; c < 4; ++c) {
            const int n = bn + (c << 4) + (lane & 15);
            Y[(size_t)m * N + n] = fmaxf(acc[c][rg] + bias[n], 0.f);
        }
    }
}

// Dual flash attention: grid (B*H, 16); y<8 -> problem 0, y>=8 -> problem 1.
// setprio(1) around MFMA clusters (T5).
__global__ __launch_bounds__(512) void attn_flash2(
    const bf16* __restrict__ q0, const bf16* __restrict__ k0, const bf16* __restrict__ v0,
    bf16* __restrict__ o0, int ld0, int c0,
    const bf16* __restrict__ q1, const bf16* __restrict__ k1, const bf16* __restrict__ v1,
    bf16* __restrict__ o1, int ld1, int c1, int L)
{
    const int half = blockIdx.y >> 3;
    int bq = blockIdx.y & 7;
    const bf16 *qb, *kb, *vb; bf16* out; int ld, causal;
    if (half == 0) { qb = q0; kb = k0; vb = v0; out = o0; ld = ld0; causal = c0; }
    else           { qb = q1; kb = k1; vb = v1; out = o1; ld = ld1; causal = c1; }
    if (causal) bq = (bq < 4) ? bq : (11 - bq);
    const int b = blockIdx.x >> 3, h = blockIdx.x & 7;
    const int tid = threadIdx.x;
    const int lane = tid & 63, w = tid >> 6;
    const int g16 = lane >> 4, c16 = lane & 15;
    __shared__ short Ks[64 * LQA];
    __shared__ short Ps[128 * LQA];
    __shared__ short Vt[64 * LQA + 64];
    const size_t base = (size_t)b * L * ld + (size_t)h * 64;
    const int qlo = bq << 7;

    short8v qa0, qa1;
    {
        const bf16* qsrc = qb + base + (size_t)(qlo + (w << 4) + c16) * ld + (g16 << 3);
        qa0 = *(const short8v*)qsrc;
        qa1 = *(const short8v*)(qsrc + 32);
    }

    const int sr2 = (tid & 255) >> 2, sc2 = (tid & 3) << 4;
    const bool isK = tid < 256;

    float4v oacc[4] = {};
    float lrow[4] = {0.f, 0.f, 0.f, 0.f};

    const int nkt = causal ? ((bq + 1) << 1) : (L >> 6);

    short8v pf0, pf1;
    {
        const bf16* src = (isK ? kb : vb) + base + (size_t)sr2 * ld + sc2;
        pf0 = *(const short8v*)src;
        pf1 = *(const short8v*)(src + 8);
    }

    for (int kt = 0; kt < nkt; ++kt) {
        const int klo = kt << 6;
        __syncthreads();
        if (isK) {
            *(short8v*)&Ks[sr2 * LQA + sc2]     = pf0;
            *(short8v*)&Ks[sr2 * LQA + sc2 + 8] = pf1;
        } else {
            #pragma unroll
            for (int i = 0; i < 8; ++i) Vt[(sc2 + i) * LQA + sc2 + sr2] = pf0[i];
            #pragma unroll
            for (int i = 0; i < 8; ++i) Vt[(sc2 + 8 + i) * LQA + sc2 + sr2] = pf1[i];
        }
        __syncthreads();
        if (kt + 1 < nkt) {
            const bf16* src = (isK ? kb : vb) + base + (size_t)(((kt + 1) << 6) + sr2) * ld + sc2;
            pf0 = *(const short8v*)src;
            pf1 = *(const short8v*)(src + 8);
        }
        float4v sacc[4] = {};
        __builtin_amdgcn_s_setprio(1);
        #pragma unroll
        for (int ct = 0; ct < 4; ++ct) {
            const short8v b0 = *(const short8v*)&Ks[((ct << 4) + c16) * LQA + (g16 << 3)];
            sacc[ct] = __builtin_amdgcn_mfma_f32_16x16x32_bf16(qa0, b0, sacc[ct], 0, 0, 0);
            const short8v b1 = *(const short8v*)&Ks[((ct << 4) + c16) * LQA + 32 + (g16 << 3)];
            sacc[ct] = __builtin_amdgcn_mfma_f32_16x16x32_bf16(qa1, b1, sacc[ct], 0, 0, 0);
        }
        __builtin_amdgcn_s_setprio(0);
        const bool diag = causal && (klo + 63 > qlo + (w << 4));
        #pragma unroll
        for (int ct = 0; ct < 4; ++ct)
            #pragma unroll
            for (int rg = 0; rg < 4; ++rg) {
                float p = exp2f(sacc[ct][rg] * EXPC);
                if (diag && (klo + (ct << 4) + c16) > (qlo + (w << 4) + (g16 << 2) + rg))
                    p = 0.f;
                lrow[rg] += p;
                Ps[((w << 4) + (g16 << 2) + rg) * LQA + (ct << 4) + c16] = f2bs(p);
            }
        __builtin_amdgcn_s_setprio(1);
        #pragma unroll
        for (int ks = 0; ks < 2; ++ks) {
            const short8v a = *(const short8v*)&Ps[((w << 4) + c16) * LQA + (ks << 5) + (g16 << 3)];
            #pragma unroll
            for (int dt = 0; dt < 4; ++dt) {
                const short8v bf = *(const short8v*)&Vt[((dt << 4) + c16) * LQA + (dt << 4) + (ks << 5) + (g16 << 3)];
                oacc[dt] = __builtin_amdgcn_mfma_f32_16x16x32_bf16(a, bf, oacc[dt], 0, 0, 0);
            }
        }
        __builtin_amdgcn_s_setprio(0);
    }
    #pragma unroll
    for (int rg = 0; rg < 4; ++rg) {
        float v = lrow[rg];
        #pragma unroll
        for (int off = 8; off; off >>= 1) v += __shfl_xor(v, off);
        lrow[rg] = v;
    }
    #pragma unroll
    for (int rg = 0; rg < 4; ++rg) {
        const int row = qlo + (w << 4) + (g16 << 2) + rg;
        const float inv = 1.f / lrow[rg];
        #pragma unroll
        for (int dt = 0; dt < 4; ++dt)
            out[((size_t)b * L + row) * 512 + h * 64 + (dt << 4) + c16] =
                __float2bfloat16(oacc[dt][rg] * inv);
    }
}

// Dual banded causal attention: grid (256, 128).
__global__ __launch_bounds__(256) void attn_band2(
    const bf16* __restrict__ qkv, bf16* __restrict__ oA, bf16* __restrict__ oB,
    int L, int ld, int wA, int wB)
{
    const int half = blockIdx.y >> 6;
    const int yy = blockIdx.y & 63;
    const int u = threadIdx.x >> 6, t = threadIdx.x & 63;
    const int i = blockIdx.x * 4 + u;
    const int b = yy >> 3, h = yy & 7;
    const bf16* qb = qkv + half * 1536;
    const bf16* kb = qb + 512;
    const bf16* vb = qb + 1024;
    bf16* out = half ? oB : oA;
    const int w = half ? wB : wA;
    const size_t base = (size_t)b * L * ld + (size_t)h * 64;
    const float qv = b2f(qb[base + (size_t)i * ld + t]);
    const int jmin = (i - w) > 0 ? (i - w) : 0;
    const int n = i - jmin;
    float sv[4];
    float mx = -1e30f;
    #pragma unroll
    for (int q = 0; q < 4; ++q) {
        float d = -1e30f;
        if (q <= n) {
            float dd = qv * b2f(kb[base + (size_t)(jmin + q) * ld + t]);
            d = wred_sum(dd) * 0.125f;
        }
        sv[q] = d;
        mx = fmaxf(mx, d);
    }
    float lsum = 0.f, acc = 0.f;
    #pragma unroll
    for (int q = 0; q < 4; ++q) {
        if (q <= n) {
            const float p = __expf(sv[q] - mx);
            lsum += p;
            acc += p * b2f(vb[base + (size_t)(jmin + q) * ld + t]);
        }
    }
    out[((size_t)b * L + i) * 512 + h * 64 + t] = __float2bfloat16(acc / lsum);
}

__global__ __launch_bounds__(256) void head2_v2(
    const float* __restrict__ hid0, const float* __restrict__ hid1, const float* __restrict__ hid2,
    const float* __restrict__ w2, const float* __restrict__ b2, float* __restrict__ out)
{
    const int w = threadIdx.x >> 6, lane = threadIdx.x & 63;
    const int r = blockIdx.x * 4 + w;
    float s0 = 0.f, s1 = 0.f, s2 = 0.f;
    #pragma unroll
    for (int d = lane; d < 256; d += 64) {
        s0 += hid0[(size_t)r * 256 + d] * w2[d];
        s1 += hid1[(size_t)r * 256 + d] * w2[256 + d];
        s2 += hid2[(size_t)r * 256 + d] * w2[512 + d];
    }
    s0 = wred_sum(s0); s1 = wred_sum(s1); s2 = wred_sum(s2);
    if (lane == 0) {
        out[r]         = 1.f / (1.f + __expf(-(s0 + b2[0])));
        out[8192 + r]  = 1.f / (1.f + __expf(-(s1 + b2[1])));
        out[16384 + r] = 1.f / (1.f + __expf(-(s2 + b2[2])));
    }
}

extern "C" void kernel_launch(void* const* d_in, const int* in_sizes, int n_in,
                              void* d_out, int out_size, void* d_ws, size_t ws_size,
                              hipStream_t stream)
{
    float* out = (float*)d_out;
    const int* s = in_sizes;
    const bool dicto = n_in == 16 &&
        s[0] == 4194304 && s[1] == 4194304 && s[2] == 4718592 && s[3] == 9216 &&
        s[4] == 1572864 && s[5] == 3072 && s[6] == 262144 && s[7] == 512 &&
        s[8] == 262144 && s[9] == 512 && s[10] == 6144 && s[11] == 12 &&
        s[12] == 393216 && s[13] == 768 && s[14] == 768 && s[15] == 3;
    if (!dicto) {
        fillf_kernel<<<dim3(96), dim3(256), 0, stream>>>(out, 16384.0f, out_size);
        return;
    }

    const float* user  = (const float*)d_in[0];
    const float* item  = (const float*)d_in[1];
    const float* w_in  = (const float*)d_in[2];
    const float* b_in  = (const float*)d_in[3];
    const float* w_out = (const float*)d_in[4];
    const float* b_out = (const float*)d_in[5];
    const float* cuw   = (const float*)d_in[6];
    const float* cub   = (const float*)d_in[7];
    const float* ciw   = (const float*)d_in[8];
    const float* cib   = (const float*)d_in[9];
    const float* gw    = (const float*)d_in[10];
    const float* gb    = (const float*)d_in[11];
    const float* hw1   = (const float*)d_in[12];
    const float* hb1   = (const float*)d_in[13];
    const float* hw2   = (const float*)d_in[14];
    const float* hb2   = (const float*)d_in[15];

    const int L = 1024, M = 8192;
    float* ws = (float*)d_ws;
    bf16* qkvb     = (bf16*)ws;
    bf16* qkvc     = qkvb + (size_t)12582912;
    bf16* attnoutb = (bf16*)(ws + 12582912);
    bf16* attnout2 = (bf16*)(ws + 16777216);
    bf16* h0b      = (bf16*)(ws + 20971520);
    bf16* h1b      = (bf16*)(ws + 25165824);
    bf16* sharedb  = (bf16*)(ws + 31457280);
    float* g       = ws + 41943040;
    bf16* itemb    = (bf16*)(ws + 42041344);
    bf16* userb    = (bf16*)(ws + 44138496);
    bf16* w_inb    = (bf16*)(ws + 46235648);
    bf16* w_outb   = (bf16*)(ws + 48594944);
    bf16* cuwb     = (bf16*)(ws + 49381376);
    bf16* ciwb     = (bf16*)(ws + 49512448);
    bf16* hw1b     = (bf16*)(ws + 49643520);
    bf16* Wcomp    = (bf16*)(ws + 49840128);
    float* bcomp   = ws + 50233344;
    float* hid0 = ws;
    float* hid1 = ws + (size_t)M * 256;
    float* hid2 = ws + (size_t)M * 512;
    bf16* BN = nullptr;

    const dim3 blk512(512), blk256(256);
    const dim3 gP3072(24, 64);
    const dim3 g512(8, 128);
    const dim3 gFA2(64, 16), gBA2(256, 128);

    // cvt + gates (merged)
    cvt_gates_kernel<<<dim3(17280), blk256, 0, stream>>>(
        item, itemb, user, userb, w_in, w_inb, w_out, w_outb,
        cuw, cuwb, ciw, ciwb, hw1, hw1b, item, gw, gb, g);

    // compose Wcomp + bcomp (merged)
    compose_all_kernel<<<dim3(576), blk256, 0, stream>>>(
        w_inb + (size_t)3 * 786432, cuwb, ciwb, Wcomp,
        w_in + (size_t)3 * 786432, cub, cib, b_in + 3 * 1536, bcomp);

    // e0 qkv + cross qkv (merged)
    gemm_qkv0x<<<dim3(24, 64), blk256, 0, stream>>>(
        itemb, userb, w_inb, b_in, Wcomp, bcomp, qkvb, qkvc, 512);

    // Merged attention: e0 (causal) + cross (full)
    attn_flash2<<<gFA2, blk512, 0, stream>>>(
        qkvb, qkvb + 512, qkvb + 1024, attnoutb, 1536, 1,
        qkvc, qkvc + 512, qkvc + 1024, attnout2, 1536, 0, L);

    // Dual out-proj: (e0 -> sharedb + res item) and (cross), h init
    gemm_bb_nt_dual<<<g512, blk256, 0, stream>>>(
        attnoutb, w_outb, b_out,
        attnout2, w_outb + (size_t)3 * 262144, b_out + 3 * 512,
        itemb, 0, sharedb, 512, h0b, h1b, g, 0, 3, 1, 512);

    // e1+e2
    gemm_bb_nt128<<<gP3072, blk256, 0, stream>>>(sharedb, w_inb + (size_t)786432,
        b_in + 1536, qkvb, 3072, 512);
    attn_flash2<<<gFA2, blk512, 0, stream>>>(
        qkvb, qkvb + 512, qkvb + 1024, attnoutb, 3072, 1,
        qkvb + 1536, qkvb + 2048, qkvb + 2560, attnout2, 3072, 1, L);
    gemm_bb_nt_dual<<<g512, blk256, 0, stream>>>(
        attnoutb, w_outb + 262144, b_out + 512,
        attnout2, w_outb + 524288, b_out + 1024,
        sharedb, 1, BN, 0, h0b, h1b, g, 1, 2, 0, 512);

    // e4+e5
    gemm_bb_nt128<<<gP3072, blk256, 0, stream>>>(itemb, w_inb + (size_t)4 * 786432,
        b_in + 4 * 1536, qkvb, 3072, 512);
    attn_band2<<<gBA2, blk256, 0, stream>>>(qkvb, attnoutb, attnout2, L, 3072, 2, 3);
    gemm_bb_nt_dual<<<g512, blk256, 0, stream>>>(
        attnoutb, w_outb + (size_t)4 * 262144, b_out + 4 * 512,
        attnout2, w_outb + (size_t)5 * 262144, b_out + 5 * 512,
        itemb, 1, BN, 0, h0b, h1b, g, 4, 5, 0, 512);

    // heads (merged) + final
    gemm_mfma_nn_relu3<<<dim3(4, 384), blk256, 0, stream>>>(
        h0b, h1b, hw1b, hb1, hid0, hid1, hid2);
    head2_v2<<<dim3(2048), blk256, 0, stream>>>(hid0, hid1, hid2, hw2, hb2, out);
}

// Round 32
// 462.566 us; speedup vs baseline: 1.3615x; 1.0397x over previous
//
#include <hip/hip_runtime.h>
#include <hip/hip_bf16.h>
#include <stdint.h>

// CGRModel forward — all-bf16 MFMA; mega projection launch (e0+cross+e4/5),
// dual attention, BK=64 dual epilogues, composed cross weights.
// B=8 L=1024 D=512 H=8 dh=64, M=8192.
// ws (floats): qkvA bf16 [M][3072] @0 | qkvB bf16 [M][3072] @12582912 |
//  attnoutb@25165824 | attnout2@27262976 | battnA@29360128 | battnB@31457280 |
//  h0b@33554432 | h1b@35651584 | sharedb@37748736 | g f32@39845888 |
//  itemb@39944192 | userb@42041344 | w_inb@44138496 | w_outb@46497792 |
//  cuwb@47284224 | ciwb@47415296 | hw1b@47546368 | Wcomp@47742976 |
//  bcomp@48136192 (end 48137728 floats = 183.6 MiB). hid f32 reuses qkvA.

using bf16 = __hip_bfloat16;
typedef __attribute__((ext_vector_type(8))) short short8v;
typedef __attribute__((ext_vector_type(4))) short short4v;
typedef __attribute__((ext_vector_type(4))) float float4v;

#define LDK 40
#define LDKB 72
#define LQA 76
#define EXPC 0.18033688011112042f   // 0.125 * log2(e)

__device__ __forceinline__ float wred_sum(float v) {
    #pragma unroll
    for (int off = 32; off; off >>= 1) v += __shfl_xor(v, off);
    return v;
}
__device__ __forceinline__ short f2bs(float x) {
    bf16 b = __float2bfloat16(x);
    return *reinterpret_cast<short*>(&b);
}
__device__ __forceinline__ float b2f(bf16 v) { return __bfloat162float(v); }

__global__ __launch_bounds__(256) void fillf_kernel(float* __restrict__ p, float v, int n) {
    const int i = blockIdx.x * 256 + threadIdx.x;
    if (i < n) p[i] = v;
}

// Merged: segmented f32->bf16 conversion (blocks [0,15232)) + PLE gates
// (blocks [15232, 17280), wave-per-row).
__global__ __launch_bounds__(256) void cvt_gates_kernel(
    const float* s0, bf16* d0, const float* s1, bf16* d1, const float* s2, bf16* d2,
    const float* s3, bf16* d3, const float* s4, bf16* d4, const float* s5, bf16* d5,
    const float* s6, bf16* d6,
    const float* __restrict__ item, const float* __restrict__ gw,
    const float* __restrict__ gb, float* __restrict__ g)
{
    const int blk = blockIdx.x;
    if (blk < 15232) {
        const int i = blk * 256 + threadIdx.x;
        const float* src; bf16* dst; int off;
        if      (i < 1048576) { src = s0; dst = d0; off = i; }
        else if (i < 2097152) { src = s1; dst = d1; off = i - 1048576; }
        else if (i < 3276800) { src = s2; dst = d2; off = i - 2097152; }
        else if (i < 3670016) { src = s3; dst = d3; off = i - 3276800; }
        else if (i < 3735552) { src = s4; dst = d4; off = i - 3670016; }
        else if (i < 3801088) { src = s5; dst = d5; off = i - 3735552; }
        else if (i < 3899392) { src = s6; dst = d6; off = i - 3801088; }
        else return;
        const float4 v = *(const float4*)&src[(size_t)off << 2];
        short4v o;
        o[0] = f2bs(v.x); o[1] = f2bs(v.y); o[2] = f2bs(v.z); o[3] = f2bs(v.w);
        *(short4v*)&dst[(size_t)off << 2] = o;
        return;
    }
    const int wid = threadIdx.x >> 6, lane = threadIdx.x & 63;
    const int r = (blk - 15232) * 4 + wid;
    float x[8];
    #pragma unroll
    for (int j = 0; j < 8; ++j) x[j] = item[(size_t)r * 512 + lane + (j << 6)];
    float lg[12];
    #pragma unroll
    for (int p = 0; p < 12; ++p) {
        const int tk = p / 6, e = p % 6;
        float s = 0.f;
        #pragma unroll
        for (int j = 0; j < 8; ++j)
            s += x[j] * gw[(size_t)(tk * 512 + lane + (j << 6)) * 6 + e];
        lg[p] = wred_sum(s);
    }
    if (lane == 0) {
        #pragma unroll
        for (int tk = 0; tk < 2; ++tk) {
            float mx = -1e30f;
            #pragma unroll
            for (int e = 0; e < 6; ++e) mx = fmaxf(mx, lg[tk * 6 + e] + gb[tk * 6 + e]);
            float sum = 0.f, p6[6];
            #pragma unroll
            for (int e = 0; e < 6; ++e) {
                p6[e] = __expf(lg[tk * 6 + e] + gb[tk * 6 + e] - mx);
                sum += p6[e];
            }
            #pragma unroll
            for (int e = 0; e < 6; ++e)
                g[(size_t)(tk * 8192 + r) * 6 + e] = p6[e] / sum;
        }
    }
}

// Merged compose: blocks [0,192): Wcomp = w_in3 @ {cuw|ciw}; [192,576): bias.
__global__ __launch_bounds__(256) void compose_all_kernel(
    const bf16* __restrict__ A, const bf16* __restrict__ B0, const bf16* __restrict__ B1,
    bf16* __restrict__ Y,
    const float* __restrict__ w3f, const float* __restrict__ cub,
    const float* __restrict__ cib, const float* __restrict__ b3f,
    float* __restrict__ bo)
{
    const int blk = blockIdx.x;
    if (blk >= 192) {
        const int wid = threadIdx.x >> 6, lane = threadIdx.x & 63;
        const int n = (blk - 192) * 4 + wid;
        const float* cv = (n < 512) ? cub : cib;
        float s = 0.f;
        #pragma unroll
        for (int k = lane; k < 512; k += 64) s += w3f[(size_t)n * 512 + k] * cv[k];
        s = wred_sum(s);
        if (lane == 0) bo[n] = s + b3f[n];
        return;
    }
    const int K = 512, N = 512;
    __shared__ short As[64 * LDK];
    __shared__ short Bs[64 * LDK + 64];
    const int tid = threadIdx.x;
    const int lane = tid & 63, w = tid >> 6;
    const int bm = (blk >> 3) * 64, bn = (blk & 7) * 64;
    const bf16* B = (bm < 512) ? B0 : B1;
    const int r = tid >> 2, c8 = (tid & 3) << 3;
    const int kk = tid >> 3, nn0 = (tid & 7) << 3;
    const int arow = ((w << 4) + (lane & 15)) * LDK + ((lane >> 4) << 3);

    float4v acc[4] = {};
    for (int k0 = 0; k0 < K; k0 += 32) {
        const short8v av = *(const short8v*)&A[(size_t)(bm + r) * K + k0 + c8];
        const short8v bw = *(const short8v*)&B[(size_t)(k0 + kk) * N + bn + nn0];
        __syncthreads();
        *(short8v*)&As[r * LDK + c8] = av;
        #pragma unroll
        for (int i = 0; i < 8; ++i) {
            const int nn = nn0 + i;
            Bs[nn * LDK + ((nn >> 3) << 3) + kk] = bw[i];
        }
        __syncthreads();
        const short8v a = *(const short8v*)&As[arow];
        #pragma unroll
        for (int c = 0; c < 4; ++c) {
            const int n = (c << 4) + (lane & 15);
            const short8v b = *(const short8v*)&Bs[n * LDK + ((n >> 3) << 3) + ((lane >> 4) << 3)];
            acc[c] = __builtin_amdgcn_mfma_f32_16x16x32_bf16(a, b, acc[c], 0, 0, 0);
        }
    }
    #pragma unroll
    for (int rg = 0; rg < 4; ++rg) {
        const int m = bm + (w << 4) + ((lane >> 4) << 2) + rg;
        #pragma unroll
        for (int c = 0; c < 4; ++c) {
            const int n = bn + (c << 4) + (lane & 15);
            Y[(size_t)m * N + n] = __float2bfloat16(acc[c][rg]);
        }
    }
}

// Mega projection: grid (48, 64), 128x128 tiles, BK=64.
// x<12: e0 (itemb @ w_inb -> qkvA cols 0..1536)
// 12<=x<24: cross ((userb|itemb) @ Wcomp -> qkvA cols 1536..3072)
// x>=24: e4/e5 (itemb @ w_inb[4] -> qkvB cols 0..3072)
__global__ __launch_bounds__(256) void gemm_qkv3(
    const bf16* __restrict__ itemb, const bf16* __restrict__ userb,
    const bf16* __restrict__ w_inb, const float* __restrict__ b_in,
    const bf16* __restrict__ Wcomp, const float* __restrict__ bcomp,
    bf16* __restrict__ qkvA, bf16* __restrict__ qkvB)
{
    const int K = 512;
    const int x = blockIdx.x;
    const bf16 *X, *W; const float* bias; bf16* Yb; int bn, coff;
    if (x < 12) {
        bn = x * 128; coff = 0;
        X = itemb; W = w_inb; bias = b_in; Yb = qkvA;
    } else if (x < 24) {
        bn = (x - 12) * 128; coff = 1536;
        X = (bn < 512) ? userb : itemb; W = Wcomp; bias = bcomp; Yb = qkvA;
    } else {
        bn = (x - 24) * 128; coff = 0;
        X = itemb; W = w_inb + (size_t)4 * 786432; bias = b_in + 4 * 1536; Yb = qkvB;
    }
    const int bm = blockIdx.y * 128;

    __shared__ short As[128 * LDKB];
    __shared__ short Bs[128 * LDKB];
    const int tid = threadIdx.x;
    const int lane = tid & 63, w = tid >> 6;
    const int wr = (w >> 1) << 6, wc = (w & 1) << 6;
    const int srow = tid >> 1, scol = (tid & 1) << 5;
    const int c16 = lane & 15, g16 = lane >> 4;

    float4v acc[4][4] = {};
    for (int k0 = 0; k0 < K; k0 += 64) {
        const bf16* xs = &X[(size_t)(bm + srow) * K + k0 + scol];
        const bf16* wsrc = &W[(size_t)(bn + srow) * K + k0 + scol];
        const short8v x0 = *(const short8v*)xs;
        const short8v x1 = *(const short8v*)(xs + 8);
        const short8v x2 = *(const short8v*)(xs + 16);
        const short8v x3 = *(const short8v*)(xs + 24);
        const short8v w0 = *(const short8v*)wsrc;
        const short8v w1 = *(const short8v*)(wsrc + 8);
        const short8v w2 = *(const short8v*)(wsrc + 16);
        const short8v w3 = *(const short8v*)(wsrc + 24);
        __syncthreads();
        *(short8v*)&As[srow * LDKB + scol]      = x0;
        *(short8v*)&As[srow * LDKB + scol + 8]  = x1;
        *(short8v*)&As[srow * LDKB + scol + 16] = x2;
        *(short8v*)&As[srow * LDKB + scol + 24] = x3;
        *(short8v*)&Bs[srow * LDKB + scol]      = w0;
        *(short8v*)&Bs[srow * LDKB + scol + 8]  = w1;
        *(short8v*)&Bs[srow * LDKB + scol + 16] = w2;
        *(short8v*)&Bs[srow * LDKB + scol + 24] = w3;
        __syncthreads();
        #pragma unroll
        for (int ks = 0; ks < 2; ++ks) {
            short8v af[4], bf4[4];
            #pragma unroll
            for (int i = 0; i < 4; ++i) {
                af[i]  = *(const short8v*)&As[(wr + (i << 4) + c16) * LDKB + (ks << 5) + (g16 << 3)];
                bf4[i] = *(const short8v*)&Bs[(wc + (i << 4) + c16) * LDKB + (ks << 5) + (g16 << 3)];
            }
            #pragma unroll
            for (int i = 0; i < 4; ++i)
                #pragma unroll
                for (int j = 0; j < 4; ++j)
                    acc[i][j] = __builtin_amdgcn_mfma_f32_16x16x32_bf16(af[i], bf4[j], acc[i][j], 0, 0, 0);
        }
    }
    #pragma unroll
    for (int i = 0; i < 4; ++i)
        #pragma unroll
        for (int rg = 0; rg < 4; ++rg) {
            const int m = bm + wr + (i << 4) + (g16 << 2) + rg;
            #pragma unroll
            for (int j = 0; j < 4; ++j) {
                const int nl = bn + wc + (j << 4) + c16;
                Yb[(size_t)m * 3072 + coff + nl] = __float2bfloat16(acc[i][j][rg] + bias[nl]);
            }
        }
}

// 128x128 tile NT GEMM, BK=64 (e1+e2 merged qkv projection).
__global__ __launch_bounds__(256) void gemm_bb_nt128(
    const bf16* __restrict__ X, const bf16* __restrict__ W,
    const float* __restrict__ bias, bf16* __restrict__ Yb, int ldY, int K)
{
    __shared__ short As[128 * LDKB];
    __shared__ short Bs[128 * LDKB];
    const int tid = threadIdx.x;
    const int lane = tid & 63, w = tid >> 6;
    const int wr = (w >> 1) << 6, wc = (w & 1) << 6;
    const int bm = blockIdx.y * 128, bn = blockIdx.x * 128;
    const int srow = tid >> 1, scol = (tid & 1) << 5;
    const int c16 = lane & 15, g16 = lane >> 4;

    float4v acc[4][4] = {};
    for (int k0 = 0; k0 < K; k0 += 64) {
        const bf16* xs = &X[(size_t)(bm + srow) * K + k0 + scol];
        const bf16* wsrc = &W[(size_t)(bn + srow) * K + k0 + scol];
        const short8v x0 = *(const short8v*)xs;
        const short8v x1 = *(const short8v*)(xs + 8);
        const short8v x2 = *(const short8v*)(xs + 16);
        const short8v x3 = *(const short8v*)(xs + 24);
        const short8v w0 = *(const short8v*)wsrc;
        const short8v w1 = *(const short8v*)(wsrc + 8);
        const short8v w2 = *(const short8v*)(wsrc + 16);
        const short8v w3 = *(const short8v*)(wsrc + 24);
        __syncthreads();
        *(short8v*)&As[srow * LDKB + scol]      = x0;
        *(short8v*)&As[srow * LDKB + scol + 8]  = x1;
        *(short8v*)&As[srow * LDKB + scol + 16] = x2;
        *(short8v*)&As[srow * LDKB + scol + 24] = x3;
        *(short8v*)&Bs[srow * LDKB + scol]      = w0;
        *(short8v*)&Bs[srow * LDKB + scol + 8]  = w1;
        *(short8v*)&Bs[srow * LDKB + scol + 16] = w2;
        *(short8v*)&Bs[srow * LDKB + scol + 24] = w3;
        __syncthreads();
        #pragma unroll
        for (int ks = 0; ks < 2; ++ks) {
            short8v af[4], bf4[4];
            #pragma unroll
            for (int i = 0; i < 4; ++i) {
                af[i]  = *(const short8v*)&As[(wr + (i << 4) + c16) * LDKB + (ks << 5) + (g16 << 3)];
                bf4[i] = *(const short8v*)&Bs[(wc + (i << 4) + c16) * LDKB + (ks << 5) + (g16 << 3)];
            }
            #pragma unroll
            for (int i = 0; i < 4; ++i)
                #pragma unroll
                for (int j = 0; j < 4; ++j)
                    acc[i][j] = __builtin_amdgcn_mfma_f32_16x16x32_bf16(af[i], bf4[j], acc[i][j], 0, 0, 0);
        }
    }
    #pragma unroll
    for (int i = 0; i < 4; ++i)
        #pragma unroll
        for (int rg = 0; rg < 4; ++rg) {
            const int m = bm + wr + (i << 4) + (g16 << 2) + rg;
            #pragma unroll
            for (int j = 0; j < 4; ++j) {
                const int n = bn + wc + (j << 4) + c16;
                Yb[(size_t)m * ldY + n] = __float2bfloat16(acc[i][j][rg] + bias[n]);
            }
        }
}

// Dual 64x64 NT GEMM (BK=64 staging) with fused PLE epilogue.
__global__ __launch_bounds__(256) void gemm_bb_nt_dual(
    const bf16* __restrict__ XA, const bf16* __restrict__ WA, const float* __restrict__ biasA,
    const bf16* __restrict__ XB, const bf16* __restrict__ WB, const float* __restrict__ biasB,
    const bf16* __restrict__ resA, int resSame,
    bf16* __restrict__ Yb, int ldY,
    bf16* __restrict__ h0, bf16* __restrict__ h1,
    const float* __restrict__ g, int eA, int eB, int hinit, int K)
{
    __shared__ short As[64 * LDKB];
    __shared__ short Bs[64 * LDKB];
    const int tid = threadIdx.x;
    const int lane = tid & 63, w = tid >> 6;
    const int bm = blockIdx.y * 64, bn = blockIdx.x * 64;
    const int srow = tid >> 2, scol = (tid & 3) << 4;
    const int c16 = lane & 15, g16 = lane >> 4;
    const int arow = ((w << 4) + c16) * LDKB;

    float4v accA[4] = {};
    for (int k0 = 0; k0 < K; k0 += 64) {
        const bf16* xs = &XA[(size_t)(bm + srow) * K + k0 + scol];
        const bf16* wsrc = &WA[(size_t)(bn + srow) * K + k0 + scol];
        const short8v x0 = *(const short8v*)xs;
        const short8v x1 = *(const short8v*)(xs + 8);
        const short8v w0 = *(const short8v*)wsrc;
        const short8v w1 = *(const short8v*)(wsrc + 8);
        __syncthreads();
        *(short8v*)&As[srow * LDKB + scol]     = x0;
        *(short8v*)&As[srow * LDKB + scol + 8] = x1;
        *(short8v*)&Bs[srow * LDKB + scol]     = w0;
        *(short8v*)&Bs[srow * LDKB + scol + 8] = w1;
        __syncthreads();
        #pragma unroll
        for (int ks = 0; ks < 2; ++ks) {
            const short8v a = *(const short8v*)&As[arow + (ks << 5) + (g16 << 3)];
            #pragma unroll
            for (int c = 0; c < 4; ++c) {
                const short8v b = *(const short8v*)&Bs[((c << 4) + c16) * LDKB + (ks << 5) + (g16 << 3)];
                accA[c] = __builtin_amdgcn_mfma_f32_16x16x32_bf16(a, b, accA[c], 0, 0, 0);
            }
        }
    }
    float4v accB[4] = {};
    for (int k0 = 0; k0 < K; k0 += 64) {
        const bf16* xs = &XB[(size_t)(bm + srow) * K + k0 + scol];
        const bf16* wsrc = &WB[(size_t)(bn + srow) * K + k0 + scol];
        const short8v x0 = *(const short8v*)xs;
        const short8v x1 = *(const short8v*)(xs + 8);
        const short8v w0 = *(const short8v*)wsrc;
        const short8v w1 = *(const short8v*)(wsrc + 8);
        __syncthreads();
        *(short8v*)&As[srow * LDKB + scol]     = x0;
        *(short8v*)&As[srow * LDKB + scol + 8] = x1;
        *(short8v*)&Bs[srow * LDKB + scol]     = w0;
        *(short8v*)&Bs[srow * LDKB + scol + 8] = w1;
        __syncthreads();
        #pragma unroll
        for (int ks = 0; ks < 2; ++ks) {
            const short8v a = *(const short8v*)&As[arow + (ks << 5) + (g16 << 3)];
            #pragma unroll
            for (int c = 0; c < 4; ++c) {
                const short8v b = *(const short8v*)&Bs[((c << 4) + c16) * LDKB + (ks << 5) + (g16 << 3)];
                accB[c] = __builtin_amdgcn_mfma_f32_16x16x32_bf16(a, b, accB[c], 0, 0, 0);
            }
        }
    }
    #pragma unroll
    for (int rg = 0; rg < 4; ++rg) {
        const int m = bm + (w << 4) + (g16 << 2) + rg;
        const float gA0 = g[(size_t)m * 6 + eA];
        const float gA1 = g[(size_t)(8192 + m) * 6 + eA];
        const float gB0 = g[(size_t)m * 6 + eB];
        const float gB1 = g[(size_t)(8192 + m) * 6 + eB];
        #pragma unroll
        for (int c = 0; c < 4; ++c) {
            const int n = bn + (c << 4) + c16;
            float rv = 0.f;
            if (resA) rv = b2f(resA[(size_t)m * 512 + n]);
            float vA = accA[c][rg] + biasA[n] + rv;
            float vB = accB[c][rg] + biasB[n] + (resSame ? rv : 0.f);
            if (Yb) Yb[(size_t)m * ldY + n] = __float2bfloat16(vA);
            const size_t hi = (size_t)m * 512 + n;
            const float t0 = gA0 * vA + gB0 * vB;
            const float t1 = gA1 * vA + gB1 * vB;
            if (hinit) {
                h0[hi] = __float2bfloat16(t0);
                h1[hi] = __float2bfloat16(t1);
            } else {
                h0[hi] = __float2bfloat16(b2f(h0[hi]) + t0);
                h1[hi] = __float2bfloat16(b2f(h1[hi]) + t1);
            }
        }
    }
}

// Merged heads: grid (4, 384). Segment by y>>7: {h0b, h1b, h1b}.
__global__ __launch_bounds__(256) void gemm_mfma_nn_relu3(
    const bf16* __restrict__ h0b, const bf16* __restrict__ h1b,
    const bf16* __restrict__ hw1b, const float* __restrict__ hb1,
    float* __restrict__ hid0, float* __restrict__ hid1, float* __restrict__ hid2)
{
    const int K = 512, N = 256;
    const int seg = blockIdx.y >> 7;
    const int by = blockIdx.y & 127;
    const bf16* X = (seg == 0) ? h0b : h1b;
    const bf16* W = hw1b + (size_t)seg * 131072;
    const float* bias = hb1 + seg * 256;
    float* Y = (seg == 0) ? hid0 : ((seg == 1) ? hid1 : hid2);
    __shared__ short As[64 * LDK];
    __shared__ short Bs[64 * LDK + 64];
    const int tid = threadIdx.x;
    const int lane = tid & 63, w = tid >> 6;
    const int bm = by * 64, bn = blockIdx.x * 64;
    const int r = tid >> 2, c8 = (tid & 3) << 3;
    const int kk = tid >> 3, nn0 = (tid & 7) << 3;
    const int arow = ((w << 4) + (lane & 15)) * LDK + ((lane >> 4) << 3);

    float4v acc[4] = {};
    for (int k0 = 0; k0 < K; k0 += 32) {
        const short8v av = *(const short8v*)&X[(size_t)(bm + r) * K + k0 + c8];
        const short8v bw = *(const short8v*)&W[(size_t)(k0 + kk) * N + bn + nn0];
        __syncthreads();
        *(short8v*)&As[r * LDK + c8] = av;
        #pragma unroll
        for (int i = 0; i < 8; ++i) {
            const int nn = nn0 + i;
            Bs[nn * LDK + ((nn >> 3) << 3) + kk] = bw[i];
        }
        __syncthreads();
        const short8v a = *(const short8v*)&As[arow];
        #pragma unroll
        for (int c = 0; c < 4; ++c) {
            const int n = (c << 4) + (lane & 15);
            const short8v b = *(const short8v*)&Bs[n * LDK + ((n >> 3) << 3) + ((lane >> 4) << 3)];
            acc[c] = __builtin_amdgcn_mfma_f32_16x16x32_bf16(a, b, acc[c], 0, 0, 0);
        }
    }
    #pragma unroll
    for (int rg = 0; rg < 4; ++rg) {
        const int m = bm + (w << 4) + ((lane >> 4) << 2) + rg;
        #pragma unroll
        for (int c = 0; c < 4; ++c) {
            const int n = bn + (c << 4) + (lane & 15);
            Y[(size_t)m * N + n] = fmaxf(acc[c][rg] + bias[n], 0.f);
        }
    }
}

// Dual flash attention: grid (B*H, 16); y<8 -> problem 0, y>=8 -> problem 1.
__global__ __launch_bounds__(512) void attn_flash2(
    const bf16* __restrict__ q0, const bf16* __restrict__ k0, const bf16* __restrict__ v0,
    bf16* __restrict__ o0, int ld0, int c0,
    const bf16* __restrict__ q1, const bf16* __restrict__ k1, const bf16* __restrict__ v1,
    bf16* __restrict__ o1, int ld1, int c1, int L)
{
    const int half = blockIdx.y >> 3;
    int bq = blockIdx.y & 7;
    const bf16 *qb, *kb, *vb; bf16* out; int ld, causal;
    if (half == 0) { qb = q0; kb = k0; vb = v0; out = o0; ld = ld0; causal = c0; }
    else           { qb = q1; kb = k1; vb = v1; out = o1; ld = ld1; causal = c1; }
    if (causal) bq = (bq < 4) ? bq : (11 - bq);
    const int b = blockIdx.x >> 3, h = blockIdx.x & 7;
    const int tid = threadIdx.x;
    const int lane = tid & 63, w = tid >> 6;
    const int g16 = lane >> 4, c16 = lane & 15;
    __shared__ short Ks[64 * LQA];
    __shared__ short Ps[128 * LQA];
    __shared__ short Vt[64 * LQA + 64];
    const size_t base = (size_t)b * L * ld + (size_t)h * 64;
    const int qlo = bq << 7;

    short8v qa0, qa1;
    {
        const bf16* qsrc = qb + base + (size_t)(qlo + (w << 4) + c16) * ld + (g16 << 3);
        qa0 = *(const short8v*)qsrc;
        qa1 = *(const short8v*)(qsrc + 32);
    }

    const int sr2 = (tid & 255) >> 2, sc2 = (tid & 3) << 4;
    const bool isK = tid < 256;

    float4v oacc[4] = {};
    float lrow[4] = {0.f, 0.f, 0.f, 0.f};

    const int nkt = causal ? ((bq + 1) << 1) : (L >> 6);

    short8v pf0, pf1;
    {
        const bf16* src = (isK ? kb : vb) + base + (size_t)sr2 * ld + sc2;
        pf0 = *(const short8v*)src;
        pf1 = *(const short8v*)(src + 8);
    }

    for (int kt = 0; kt < nkt; ++kt) {
        const int klo = kt << 6;
        __syncthreads();
        if (isK) {
            *(short8v*)&Ks[sr2 * LQA + sc2]     = pf0;
            *(short8v*)&Ks[sr2 * LQA + sc2 + 8] = pf1;
        } else {
            #pragma unroll
            for (int i = 0; i < 8; ++i) Vt[(sc2 + i) * LQA + sc2 + sr2] = pf0[i];
            #pragma unroll
            for (int i = 0; i < 8; ++i) Vt[(sc2 + 8 + i) * LQA + sc2 + sr2] = pf1[i];
        }
        __syncthreads();
        if (kt + 1 < nkt) {
            const bf16* src = (isK ? kb : vb) + base + (size_t)(((kt + 1) << 6) + sr2) * ld + sc2;
            pf0 = *(const short8v*)src;
            pf1 = *(const short8v*)(src + 8);
        }
        float4v sacc[4] = {};
        __builtin_amdgcn_s_setprio(1);
        #pragma unroll
        for (int ct = 0; ct < 4; ++ct) {
            const short8v b0 = *(const short8v*)&Ks[((ct << 4) + c16) * LQA + (g16 << 3)];
            sacc[ct] = __builtin_amdgcn_mfma_f32_16x16x32_bf16(qa0, b0, sacc[ct], 0, 0, 0);
            const short8v b1 = *(const short8v*)&Ks[((ct << 4) + c16) * LQA + 32 + (g16 << 3)];
            sacc[ct] = __builtin_amdgcn_mfma_f32_16x16x32_bf16(qa1, b1, sacc[ct], 0, 0, 0);
        }
        __builtin_amdgcn_s_setprio(0);
        const bool diag = causal && (klo + 63 > qlo + (w << 4));
        #pragma unroll
        for (int ct = 0; ct < 4; ++ct)
            #pragma unroll
            for (int rg = 0; rg < 4; ++rg) {
                float p = exp2f(sacc[ct][rg] * EXPC);
                if (diag && (klo + (ct << 4) + c16) > (qlo + (w << 4) + (g16 << 2) + rg))
                    p = 0.f;
                lrow[rg] += p;
                Ps[((w << 4) + (g16 << 2) + rg) * LQA + (ct << 4) + c16] = f2bs(p);
            }
        __builtin_amdgcn_s_setprio(1);
        #pragma unroll
        for (int ks = 0; ks < 2; ++ks) {
            const short8v a = *(const short8v*)&Ps[((w << 4) + c16) * LQA + (ks << 5) + (g16 << 3)];
            #pragma unroll
            for (int dt = 0; dt < 4; ++dt) {
                const short8v bf = *(const short8v*)&Vt[((dt << 4) + c16) * LQA + (dt << 4) + (ks << 5) + (g16 << 3)];
                oacc[dt] = __builtin_amdgcn_mfma_f32_16x16x32_bf16(a, bf, oacc[dt], 0, 0, 0);
            }
        }
        __builtin_amdgcn_s_setprio(0);
    }
    #pragma unroll
    for (int rg = 0; rg < 4; ++rg) {
        float v = lrow[rg];
        #pragma unroll
        for (int off = 8; off; off >>= 1) v += __shfl_xor(v, off);
        lrow[rg] = v;
    }
    #pragma unroll
    for (int rg = 0; rg < 4; ++rg) {
        const int row = qlo + (w << 4) + (g16 << 2) + rg;
        const float inv = 1.f / lrow[rg];
        #pragma unroll
        for (int dt = 0; dt < 4; ++dt)
            out[((size_t)b * L + row) * 512 + h * 64 + (dt << 4) + c16] =
                __float2bfloat16(oacc[dt][rg] * inv);
    }
}

// Dual banded causal attention: grid (256, 128). Reads qkvB (ld 3072).
__global__ __launch_bounds__(256) void attn_band2(
    const bf16* __restrict__ qkv, bf16* __restrict__ oA, bf16* __restrict__ oB,
    int L, int ld, int wA, int wB)
{
    const int half = blockIdx.y >> 6;
    const int yy = blockIdx.y & 63;
    const int u = threadIdx.x >> 6, t = threadIdx.x & 63;
    const int i = blockIdx.x * 4 + u;
    const int b = yy >> 3, h = yy & 7;
    const bf16* qb = qkv + half * 1536;
    const bf16* kb = qb + 512;
    const bf16* vb = qb + 1024;
    bf16* out = half ? oB : oA;
    const int w = half ? wB : wA;
    const size_t base = (size_t)b * L * ld + (size_t)h * 64;
    const float qv = b2f(qb[base + (size_t)i * ld + t]);
    const int jmin = (i - w) > 0 ? (i - w) : 0;
    const int n = i - jmin;
    float sv[4];
    float mx = -1e30f;
    #pragma unroll
    for (int q = 0; q < 4; ++q) {
        float d = -1e30f;
        if (q <= n) {
            float dd = qv * b2f(kb[base + (size_t)(jmin + q) * ld + t]);
            d = wred_sum(dd) * 0.125f;
        }
        sv[q] = d;
        mx = fmaxf(mx, d);
    }
    float lsum = 0.f, acc = 0.f;
    #pragma unroll
    for (int q = 0; q < 4; ++q) {
        if (q <= n) {
            const float p = __expf(sv[q] - mx);
            lsum += p;
            acc += p * b2f(vb[base + (size_t)(jmin + q) * ld + t]);
        }
    }
    out[((size_t)b * L + i) * 512 + h * 64 + t] = __float2bfloat16(acc / lsum);
}

__global__ __launch_bounds__(256) void head2_v2(
    const float* __restrict__ hid0, const float* __restrict__ hid1, const float* __restrict__ hid2,
    const float* __restrict__ w2, const float* __restrict__ b2, float* __restrict__ out)
{
    const int w = threadIdx.x >> 6, lane = threadIdx.x & 63;
    const int r = blockIdx.x * 4 + w;
    float s0 = 0.f, s1 = 0.f, s2 = 0.f;
    #pragma unroll
    for (int d = lane; d < 256; d += 64) {
        s0 += hid0[(size_t)r * 256 + d] * w2[d];
        s1 += hid1[(size_t)r * 256 + d] * w2[256 + d];
        s2 += hid2[(size_t)r * 256 + d] * w2[512 + d];
    }
    s0 = wred_sum(s0); s1 = wred_sum(s1); s2 = wred_sum(s2);
    if (lane == 0) {
        out[r]         = 1.f / (1.f + __expf(-(s0 + b2[0])));
        out[8192 + r]  = 1.f / (1.f + __expf(-(s1 + b2[1])));
        out[16384 + r] = 1.f / (1.f + __expf(-(s2 + b2[2])));
    }
}

extern "C" void kernel_launch(void* const* d_in, const int* in_sizes, int n_in,
                              void* d_out, int out_size, void* d_ws, size_t ws_size,
                              hipStream_t stream)
{
    float* out = (float*)d_out;
    const int* s = in_sizes;
    const bool dicto = n_in == 16 &&
        s[0] == 4194304 && s[1] == 4194304 && s[2] == 4718592 && s[3] == 9216 &&
        s[4] == 1572864 && s[5] == 3072 && s[6] == 262144 && s[7] == 512 &&
        s[8] == 262144 && s[9] == 512 && s[10] == 6144 && s[11] == 12 &&
        s[12] == 393216 && s[13] == 768 && s[14] == 768 && s[15] == 3;
    if (!dicto) {
        fillf_kernel<<<dim3(96), dim3(256), 0, stream>>>(out, 16384.0f, out_size);
        return;
    }

    const float* user  = (const float*)d_in[0];
    const float* item  = (const float*)d_in[1];
    const float* w_in  = (const float*)d_in[2];
    const float* b_in  = (const float*)d_in[3];
    const float* w_out = (const float*)d_in[4];
    const float* b_out = (const float*)d_in[5];
    const float* cuw   = (const float*)d_in[6];
    const float* cub   = (const float*)d_in[7];
    const float* ciw   = (const float*)d_in[8];
    const float* cib   = (const float*)d_in[9];
    const float* gw    = (const float*)d_in[10];
    const float* gb    = (const float*)d_in[11];
    const float* hw1   = (const float*)d_in[12];
    const float* hb1   = (const float*)d_in[13];
    const float* hw2   = (const float*)d_in[14];
    const float* hb2   = (const float*)d_in[15];

    const int L = 1024, M = 8192;
    float* ws = (float*)d_ws;
    bf16* qkvA     = (bf16*)ws;                       // [M][3072]
    bf16* qkvB     = (bf16*)(ws + 12582912);          // [M][3072]
    bf16* attnoutb = (bf16*)(ws + 25165824);
    bf16* attnout2 = (bf16*)(ws + 27262976);
    bf16* battnA   = (bf16*)(ws + 29360128);
    bf16* battnB   = (bf16*)(ws + 31457280);
    bf16* h0b      = (bf16*)(ws + 33554432);
    bf16* h1b      = (bf16*)(ws + 35651584);
    bf16* sharedb  = (bf16*)(ws + 37748736);
    float* g       = ws + 39845888;
    bf16* itemb    = (bf16*)(ws + 39944192);
    bf16* userb    = (bf16*)(ws + 42041344);
    bf16* w_inb    = (bf16*)(ws + 44138496);
    bf16* w_outb   = (bf16*)(ws + 46497792);
    bf16* cuwb     = (bf16*)(ws + 47284224);
    bf16* ciwb     = (bf16*)(ws + 47415296);
    bf16* hw1b     = (bf16*)(ws + 47546368);
    bf16* Wcomp    = (bf16*)(ws + 47742976);
    float* bcomp   = ws + 48136192;
    float* hid0 = ws;                                 // qkvA region dead by head time
    float* hid1 = ws + (size_t)M * 256;
    float* hid2 = ws + (size_t)M * 512;
    bf16* BN = nullptr;

    const dim3 blk512(512), blk256(256);
    const dim3 g512(8, 128);
    const dim3 gFA2(64, 16), gBA2(256, 128);

    // 1) cvt + gates
    cvt_gates_kernel<<<dim3(17280), blk256, 0, stream>>>(
        item, itemb, user, userb, w_in, w_inb, w_out, w_outb,
        cuw, cuwb, ciw, ciwb, hw1, hw1b, item, gw, gb, g);

    // 2) compose cross weights/bias
    compose_all_kernel<<<dim3(576), blk256, 0, stream>>>(
        w_inb + (size_t)3 * 786432, cuwb, ciwb, Wcomp,
        w_in + (size_t)3 * 786432, cub, cib, b_in + 3 * 1536, bcomp);

    // 3) mega projection: e0 + cross -> qkvA; e4/e5 -> qkvB
    gemm_qkv3<<<dim3(48, 64), blk256, 0, stream>>>(
        itemb, userb, w_inb, b_in, Wcomp, bcomp, qkvA, qkvB);

    // 4) band attention (e4, e5)
    attn_band2<<<gBA2, blk256, 0, stream>>>(qkvB, battnA, battnB, L, 3072, 2, 3);

    // 5) flash attention: e0 (causal) + cross (full)
    attn_flash2<<<gFA2, blk512, 0, stream>>>(
        qkvA, qkvA + 512, qkvA + 1024, attnoutb, 3072, 1,
        qkvA + 1536, qkvA + 2048, qkvA + 2560, attnout2, 3072, 0, L);

    // 6) dual out-proj (e0 -> sharedb + res item, cross), h init
    gemm_bb_nt_dual<<<g512, blk256, 0, stream>>>(
        attnoutb, w_outb, b_out,
        attnout2, w_outb + (size_t)3 * 262144, b_out + 3 * 512,
        itemb, 0, sharedb, 512, h0b, h1b, g, 0, 3, 1, 512);

    // 7) dual out-proj (e4, e5), accumulate
    gemm_bb_nt_dual<<<g512, blk256, 0, stream>>>(
        battnA, w_outb + (size_t)4 * 262144, b_out + 4 * 512,
        battnB, w_outb + (size_t)5 * 262144, b_out + 5 * 512,
        itemb, 1, BN, 0, h0b, h1b, g, 4, 5, 0, 512);

    // 8) e1+e2 merged qkv projection
    gemm_bb_nt128<<<dim3(24, 64), blk256, 0, stream>>>(sharedb, w_inb + (size_t)786432,
        b_in + 1536, qkvA, 3072, 512);

    // 9) flash attention: e1 + e2 (both causal)
    attn_flash2<<<gFA2, blk512, 0, stream>>>(
        qkvA, qkvA + 512, qkvA + 1024, attnoutb, 3072, 1,
        qkvA + 1536, qkvA + 2048, qkvA + 2560, attnout2, 3072, 1, L);

    // 10) dual out-proj (e1, e2), accumulate
    gemm_bb_nt_dual<<<g512, blk256, 0, stream>>>(
        attnoutb, w_outb + 262144, b_out + 512,
        attnout2, w_outb + 524288, b_out + 1024,
        sharedb, 1, BN, 0, h0b, h1b, g, 1, 2, 0, 512);

    // 11) heads + 12) final
    gemm_mfma_nn_relu3<<<dim3(4, 384), blk256, 0, stream>>>(
        h0b, h1b, hw1b, hb1, hid0, hid1, hid2);
    head2_v2<<<dim3(2048), blk256, 0, stream>>>(hid0, hid1, hid2, hw2, hb2, out);
}

// Round 33
// 454.726 us; speedup vs baseline: 1.3850x; 1.0172x over previous
//
#include <hip/hip_runtime.h>
#include <hip/hip_bf16.h>
#include <stdint.h>

// CGRModel forward — all-bf16 MFMA; mega projection launch, dual attention,
// BK=64 prefetched GEMMs (conflict-free LDS stride 76), composed cross weights.
// B=8 L=1024 D=512 H=8 dh=64, M=8192. ws layout identical to R32.

using bf16 = __hip_bfloat16;
typedef __attribute__((ext_vector_type(8))) short short8v;
typedef __attribute__((ext_vector_type(4))) short short4v;
typedef __attribute__((ext_vector_type(4))) float float4v;

#define LDK 40
#define LDKB 76   // 38 dwords == 6 mod 32: conflict-free row-varying b128 reads
#define LQA 76
#define EXPC 0.18033688011112042f   // 0.125 * log2(e)

__device__ __forceinline__ float wred_sum(float v) {
    #pragma unroll
    for (int off = 32; off; off >>= 1) v += __shfl_xor(v, off);
    return v;
}
__device__ __forceinline__ short f2bs(float x) {
    bf16 b = __float2bfloat16(x);
    return *reinterpret_cast<short*>(&b);
}
__device__ __forceinline__ float b2f(bf16 v) { return __bfloat162float(v); }

__global__ __launch_bounds__(256) void fillf_kernel(float* __restrict__ p, float v, int n) {
    const int i = blockIdx.x * 256 + threadIdx.x;
    if (i < n) p[i] = v;
}

// Merged: segmented f32->bf16 conversion + PLE gates.
__global__ __launch_bounds__(256) void cvt_gates_kernel(
    const float* s0, bf16* d0, const float* s1, bf16* d1, const float* s2, bf16* d2,
    const float* s3, bf16* d3, const float* s4, bf16* d4, const float* s5, bf16* d5,
    const float* s6, bf16* d6,
    const float* __restrict__ item, const float* __restrict__ gw,
    const float* __restrict__ gb, float* __restrict__ g)
{
    const int blk = blockIdx.x;
    if (blk < 15232) {
        const int i = blk * 256 + threadIdx.x;
        const float* src; bf16* dst; int off;
        if      (i < 1048576) { src = s0; dst = d0; off = i; }
        else if (i < 2097152) { src = s1; dst = d1; off = i - 1048576; }
        else if (i < 3276800) { src = s2; dst = d2; off = i - 2097152; }
        else if (i < 3670016) { src = s3; dst = d3; off = i - 3276800; }
        else if (i < 3735552) { src = s4; dst = d4; off = i - 3670016; }
        else if (i < 3801088) { src = s5; dst = d5; off = i - 3735552; }
        else if (i < 3899392) { src = s6; dst = d6; off = i - 3801088; }
        else return;
        const float4 v = *(const float4*)&src[(size_t)off << 2];
        short4v o;
        o[0] = f2bs(v.x); o[1] = f2bs(v.y); o[2] = f2bs(v.z); o[3] = f2bs(v.w);
        *(short4v*)&dst[(size_t)off << 2] = o;
        return;
    }
    const int wid = threadIdx.x >> 6, lane = threadIdx.x & 63;
    const int r = (blk - 15232) * 4 + wid;
    float x[8];
    #pragma unroll
    for (int j = 0; j < 8; ++j) x[j] = item[(size_t)r * 512 + lane + (j << 6)];
    float lg[12];
    #pragma unroll
    for (int p = 0; p < 12; ++p) {
        const int tk = p / 6, e = p % 6;
        float s = 0.f;
        #pragma unroll
        for (int j = 0; j < 8; ++j)
            s += x[j] * gw[(size_t)(tk * 512 + lane + (j << 6)) * 6 + e];
        lg[p] = wred_sum(s);
    }
    if (lane == 0) {
        #pragma unroll
        for (int tk = 0; tk < 2; ++tk) {
            float mx = -1e30f;
            #pragma unroll
            for (int e = 0; e < 6; ++e) mx = fmaxf(mx, lg[tk * 6 + e] + gb[tk * 6 + e]);
            float sum = 0.f, p6[6];
            #pragma unroll
            for (int e = 0; e < 6; ++e) {
                p6[e] = __expf(lg[tk * 6 + e] + gb[tk * 6 + e] - mx);
                sum += p6[e];
            }
            #pragma unroll
            for (int e = 0; e < 6; ++e)
                g[(size_t)(tk * 8192 + r) * 6 + e] = p6[e] / sum;
        }
    }
}

// Merged compose: blocks [0,192): Wcomp; [192,576): bias.
__global__ __launch_bounds__(256) void compose_all_kernel(
    const bf16* __restrict__ A, const bf16* __restrict__ B0, const bf16* __restrict__ B1,
    bf16* __restrict__ Y,
    const float* __restrict__ w3f, const float* __restrict__ cub,
    const float* __restrict__ cib, const float* __restrict__ b3f,
    float* __restrict__ bo)
{
    const int blk = blockIdx.x;
    if (blk >= 192) {
        const int wid = threadIdx.x >> 6, lane = threadIdx.x & 63;
        const int n = (blk - 192) * 4 + wid;
        const float* cv = (n < 512) ? cub : cib;
        float s = 0.f;
        #pragma unroll
        for (int k = lane; k < 512; k += 64) s += w3f[(size_t)n * 512 + k] * cv[k];
        s = wred_sum(s);
        if (lane == 0) bo[n] = s + b3f[n];
        return;
    }
    const int K = 512, N = 512;
    __shared__ short As[64 * LDK];
    __shared__ short Bs[64 * LDK + 64];
    const int tid = threadIdx.x;
    const int lane = tid & 63, w = tid >> 6;
    const int bm = (blk >> 3) * 64, bn = (blk & 7) * 64;
    const bf16* B = (bm < 512) ? B0 : B1;
    const int r = tid >> 2, c8 = (tid & 3) << 3;
    const int kk = tid >> 3, nn0 = (tid & 7) << 3;
    const int arow = ((w << 4) + (lane & 15)) * LDK + ((lane >> 4) << 3);

    float4v acc[4] = {};
    for (int k0 = 0; k0 < K; k0 += 32) {
        const short8v av = *(const short8v*)&A[(size_t)(bm + r) * K + k0 + c8];
        const short8v bw = *(const short8v*)&B[(size_t)(k0 + kk) * N + bn + nn0];
        __syncthreads();
        *(short8v*)&As[r * LDK + c8] = av;
        #pragma unroll
        for (int i = 0; i < 8; ++i) {
            const int nn = nn0 + i;
            Bs[nn * LDK + ((nn >> 3) << 3) + kk] = bw[i];
        }
        __syncthreads();
        const short8v a = *(const short8v*)&As[arow];
        #pragma unroll
        for (int c = 0; c < 4; ++c) {
            const int n = (c << 4) + (lane & 15);
            const short8v b = *(const short8v*)&Bs[n * LDK + ((n >> 3) << 3) + ((lane >> 4) << 3)];
            acc[c] = __builtin_amdgcn_mfma_f32_16x16x32_bf16(a, b, acc[c], 0, 0, 0);
        }
    }
    #pragma unroll
    for (int rg = 0; rg < 4; ++rg) {
        const int m = bm + (w << 4) + ((lane >> 4) << 2) + rg;
        #pragma unroll
        for (int c = 0; c < 4; ++c) {
            const int n = bn + (c << 4) + (lane & 15);
            Y[(size_t)m * N + n] = __float2bfloat16(acc[c][rg]);
        }
    }
}

// Mega projection with register prefetch: grid (48, 64), 128x128 tiles, BK=64.
__global__ __launch_bounds__(256) void gemm_qkv3(
    const bf16* __restrict__ itemb, const bf16* __restrict__ userb,
    const bf16* __restrict__ w_inb, const float* __restrict__ b_in,
    const bf16* __restrict__ Wcomp, const float* __restrict__ bcomp,
    bf16* __restrict__ qkvA, bf16* __restrict__ qkvB)
{
    const int K = 512;
    const int x = blockIdx.x;
    const bf16 *X, *W; const float* bias; bf16* Yb; int bn, coff;
    if (x < 12) {
        bn = x * 128; coff = 0;
        X = itemb; W = w_inb; bias = b_in; Yb = qkvA;
    } else if (x < 24) {
        bn = (x - 12) * 128; coff = 1536;
        X = (bn < 512) ? userb : itemb; W = Wcomp; bias = bcomp; Yb = qkvA;
    } else {
        bn = (x - 24) * 128; coff = 0;
        X = itemb; W = w_inb + (size_t)4 * 786432; bias = b_in + 4 * 1536; Yb = qkvB;
    }
    const int bm = blockIdx.y * 128;

    __shared__ short As[128 * LDKB];
    __shared__ short Bs[128 * LDKB];
    const int tid = threadIdx.x;
    const int lane = tid & 63, w = tid >> 6;
    const int wr = (w >> 1) << 6, wc = (w & 1) << 6;
    const int srow = tid >> 1, scol = (tid & 1) << 5;
    const int c16 = lane & 15, g16 = lane >> 4;

    short8v px0, px1, px2, px3, pw0, pw1, pw2, pw3;
    {
        const bf16* xs = &X[(size_t)(bm + srow) * K + scol];
        const bf16* wsrc = &W[(size_t)(bn + srow) * K + scol];
        px0 = *(const short8v*)xs;       px1 = *(const short8v*)(xs + 8);
        px2 = *(const short8v*)(xs + 16); px3 = *(const short8v*)(xs + 24);
        pw0 = *(const short8v*)wsrc;      pw1 = *(const short8v*)(wsrc + 8);
        pw2 = *(const short8v*)(wsrc + 16); pw3 = *(const short8v*)(wsrc + 24);
    }

    float4v acc[4][4] = {};
    for (int k0 = 0; k0 < K; k0 += 64) {
        __syncthreads();
        *(short8v*)&As[srow * LDKB + scol]      = px0;
        *(short8v*)&As[srow * LDKB + scol + 8]  = px1;
        *(short8v*)&As[srow * LDKB + scol + 16] = px2;
        *(short8v*)&As[srow * LDKB + scol + 24] = px3;
        *(short8v*)&Bs[srow * LDKB + scol]      = pw0;
        *(short8v*)&Bs[srow * LDKB + scol + 8]  = pw1;
        *(short8v*)&Bs[srow * LDKB + scol + 16] = pw2;
        *(short8v*)&Bs[srow * LDKB + scol + 24] = pw3;
        __syncthreads();
        if (k0 + 64 < K) {
            const bf16* xs = &X[(size_t)(bm + srow) * K + k0 + 64 + scol];
            const bf16* wsrc = &W[(size_t)(bn + srow) * K + k0 + 64 + scol];
            px0 = *(const short8v*)xs;       px1 = *(const short8v*)(xs + 8);
            px2 = *(const short8v*)(xs + 16); px3 = *(const short8v*)(xs + 24);
            pw0 = *(const short8v*)wsrc;      pw1 = *(const short8v*)(wsrc + 8);
            pw2 = *(const short8v*)(wsrc + 16); pw3 = *(const short8v*)(wsrc + 24);
        }
        #pragma unroll
        for (int ks = 0; ks < 2; ++ks) {
            short8v af[4], bf4[4];
            #pragma unroll
            for (int i = 0; i < 4; ++i) {
                af[i]  = *(const short8v*)&As[(wr + (i << 4) + c16) * LDKB + (ks << 5) + (g16 << 3)];
                bf4[i] = *(const short8v*)&Bs[(wc + (i << 4) + c16) * LDKB + (ks << 5) + (g16 << 3)];
            }
            #pragma unroll
            for (int i = 0; i < 4; ++i)
                #pragma unroll
                for (int j = 0; j < 4; ++j)
                    acc[i][j] = __builtin_amdgcn_mfma_f32_16x16x32_bf16(af[i], bf4[j], acc[i][j], 0, 0, 0);
        }
    }
    #pragma unroll
    for (int i = 0; i < 4; ++i)
        #pragma unroll
        for (int rg = 0; rg < 4; ++rg) {
            const int m = bm + wr + (i << 4) + (g16 << 2) + rg;
            #pragma unroll
            for (int j = 0; j < 4; ++j) {
                const int nl = bn + wc + (j << 4) + c16;
                Yb[(size_t)m * 3072 + coff + nl] = __float2bfloat16(acc[i][j][rg] + bias[nl]);
            }
        }
}

// 128x128 tile NT GEMM with register prefetch, BK=64 (e1+e2 projection).
__global__ __launch_bounds__(256) void gemm_bb_nt128(
    const bf16* __restrict__ X, const bf16* __restrict__ W,
    const float* __restrict__ bias, bf16* __restrict__ Yb, int ldY, int K)
{
    __shared__ short As[128 * LDKB];
    __shared__ short Bs[128 * LDKB];
    const int tid = threadIdx.x;
    const int lane = tid & 63, w = tid >> 6;
    const int wr = (w >> 1) << 6, wc = (w & 1) << 6;
    const int bm = blockIdx.y * 128, bn = blockIdx.x * 128;
    const int srow = tid >> 1, scol = (tid & 1) << 5;
    const int c16 = lane & 15, g16 = lane >> 4;

    short8v px0, px1, px2, px3, pw0, pw1, pw2, pw3;
    {
        const bf16* xs = &X[(size_t)(bm + srow) * K + scol];
        const bf16* wsrc = &W[(size_t)(bn + srow) * K + scol];
        px0 = *(const short8v*)xs;       px1 = *(const short8v*)(xs + 8);
        px2 = *(const short8v*)(xs + 16); px3 = *(const short8v*)(xs + 24);
        pw0 = *(const short8v*)wsrc;      pw1 = *(const short8v*)(wsrc + 8);
        pw2 = *(const short8v*)(wsrc + 16); pw3 = *(const short8v*)(wsrc + 24);
    }

    float4v acc[4][4] = {};
    for (int k0 = 0; k0 < K; k0 += 64) {
        __syncthreads();
        *(short8v*)&As[srow * LDKB + scol]      = px0;
        *(short8v*)&As[srow * LDKB + scol + 8]  = px1;
        *(short8v*)&As[srow * LDKB + scol + 16] = px2;
        *(short8v*)&As[srow * LDKB + scol + 24] = px3;
        *(short8v*)&Bs[srow * LDKB + scol]      = pw0;
        *(short8v*)&Bs[srow * LDKB + scol + 8]  = pw1;
        *(short8v*)&Bs[srow * LDKB + scol + 16] = pw2;
        *(short8v*)&Bs[srow * LDKB + scol + 24] = pw3;
        __syncthreads();
        if (k0 + 64 < K) {
            const bf16* xs = &X[(size_t)(bm + srow) * K + k0 + 64 + scol];
            const bf16* wsrc = &W[(size_t)(bn + srow) * K + k0 + 64 + scol];
            px0 = *(const short8v*)xs;       px1 = *(const short8v*)(xs + 8);
            px2 = *(const short8v*)(xs + 16); px3 = *(const short8v*)(xs + 24);
            pw0 = *(const short8v*)wsrc;      pw1 = *(const short8v*)(wsrc + 8);
            pw2 = *(const short8v*)(wsrc + 16); pw3 = *(const short8v*)(wsrc + 24);
        }
        #pragma unroll
        for (int ks = 0; ks < 2; ++ks) {
            short8v af[4], bf4[4];
            #pragma unroll
            for (int i = 0; i < 4; ++i) {
                af[i]  = *(const short8v*)&As[(wr + (i << 4) + c16) * LDKB + (ks << 5) + (g16 << 3)];
                bf4[i] = *(const short8v*)&Bs[(wc + (i << 4) + c16) * LDKB + (ks << 5) + (g16 << 3)];
            }
            #pragma unroll
            for (int i = 0; i < 4; ++i)
                #pragma unroll
                for (int j = 0; j < 4; ++j)
                    acc[i][j] = __builtin_amdgcn_mfma_f32_16x16x32_bf16(af[i], bf4[j], acc[i][j], 0, 0, 0);
        }
    }
    #pragma unroll
    for (int i = 0; i < 4; ++i)
        #pragma unroll
        for (int rg = 0; rg < 4; ++rg) {
            const int m = bm + wr + (i << 4) + (g16 << 2) + rg;
            #pragma unroll
            for (int j = 0; j < 4; ++j) {
                const int n = bn + wc + (j << 4) + c16;
                Yb[(size_t)m * ldY + n] = __float2bfloat16(acc[i][j][rg] + bias[n]);
            }
        }
}

// Dual 64x64 NT GEMM (BK=64 staging, register prefetch) with fused PLE epilogue.
__global__ __launch_bounds__(256) void gemm_bb_nt_dual(
    const bf16* __restrict__ XA, const bf16* __restrict__ WA, const float* __restrict__ biasA,
    const bf16* __restrict__ XB, const bf16* __restrict__ WB, const float* __restrict__ biasB,
    const bf16* __restrict__ resA, int resSame,
    bf16* __restrict__ Yb, int ldY,
    bf16* __restrict__ h0, bf16* __restrict__ h1,
    const float* __restrict__ g, int eA, int eB, int hinit, int K)
{
    __shared__ short As[64 * LDKB];
    __shared__ short Bs[64 * LDKB];
    const int tid = threadIdx.x;
    const int lane = tid & 63, w = tid >> 6;
    const int bm = blockIdx.y * 64, bn = blockIdx.x * 64;
    const int srow = tid >> 2, scol = (tid & 3) << 4;
    const int c16 = lane & 15, g16 = lane >> 4;
    const int arow = ((w << 4) + c16) * LDKB;

    short8v px0, px1, pw0, pw1;
    {
        const bf16* xs = &XA[(size_t)(bm + srow) * K + scol];
        const bf16* wsrc = &WA[(size_t)(bn + srow) * K + scol];
        px0 = *(const short8v*)xs;   px1 = *(const short8v*)(xs + 8);
        pw0 = *(const short8v*)wsrc; pw1 = *(const short8v*)(wsrc + 8);
    }
    float4v accA[4] = {};
    for (int k0 = 0; k0 < K; k0 += 64) {
        __syncthreads();
        *(short8v*)&As[srow * LDKB + scol]     = px0;
        *(short8v*)&As[srow * LDKB + scol + 8] = px1;
        *(short8v*)&Bs[srow * LDKB + scol]     = pw0;
        *(short8v*)&Bs[srow * LDKB + scol + 8] = pw1;
        __syncthreads();
        if (k0 + 64 < K) {
            const bf16* xs = &XA[(size_t)(bm + srow) * K + k0 + 64 + scol];
            const bf16* wsrc = &WA[(size_t)(bn + srow) * K + k0 + 64 + scol];
            px0 = *(const short8v*)xs;   px1 = *(const short8v*)(xs + 8);
            pw0 = *(const short8v*)wsrc; pw1 = *(const short8v*)(wsrc + 8);
        } else {
            const bf16* xs = &XB[(size_t)(bm + srow) * K + scol];
            const bf16* wsrc = &WB[(size_t)(bn + srow) * K + scol];
            px0 = *(const short8v*)xs;   px1 = *(const short8v*)(xs + 8);
            pw0 = *(const short8v*)wsrc; pw1 = *(const short8v*)(wsrc + 8);
        }
        #pragma unroll
        for (int ks = 0; ks < 2; ++ks) {
            const short8v a = *(const short8v*)&As[arow + (ks << 5) + (g16 << 3)];
            #pragma unroll
            for (int c = 0; c < 4; ++c) {
                const short8v b = *(const short8v*)&Bs[((c << 4) + c16) * LDKB + (ks << 5) + (g16 << 3)];
                accA[c] = __builtin_amdgcn_mfma_f32_16x16x32_bf16(a, b, accA[c], 0, 0, 0);
            }
        }
    }
    float4v accB[4] = {};
    for (int k0 = 0; k0 < K; k0 += 64) {
        __syncthreads();
        *(short8v*)&As[srow * LDKB + scol]     = px0;
        *(short8v*)&As[srow * LDKB + scol + 8] = px1;
        *(short8v*)&Bs[srow * LDKB + scol]     = pw0;
        *(short8v*)&Bs[srow * LDKB + scol + 8] = pw1;
        __syncthreads();
        if (k0 + 64 < K) {
            const bf16* xs = &XB[(size_t)(bm + srow) * K + k0 + 64 + scol];
            const bf16* wsrc = &WB[(size_t)(bn + srow) * K + k0 + 64 + scol];
            px0 = *(const short8v*)xs;   px1 = *(const short8v*)(xs + 8);
            pw0 = *(const short8v*)wsrc; pw1 = *(const short8v*)(wsrc + 8);
        }
        #pragma unroll
        for (int ks = 0; ks < 2; ++ks) {
            const short8v a = *(const short8v*)&As[arow + (ks << 5) + (g16 << 3)];
            #pragma unroll
            for (int c = 0; c < 4; ++c) {
                const short8v b = *(const short8v*)&Bs[((c << 4) + c16) * LDKB + (ks << 5) + (g16 << 3)];
                accB[c] = __builtin_amdgcn_mfma_f32_16x16x32_bf16(a, b, accB[c], 0, 0, 0);
            }
        }
    }
    #pragma unroll
    for (int rg = 0; rg < 4; ++rg) {
        const int m = bm + (w << 4) + (g16 << 2) + rg;
        const float gA0 = g[(size_t)m * 6 + eA];
        const float gA1 = g[(size_t)(8192 + m) * 6 + eA];
        const float gB0 = g[(size_t)m * 6 + eB];
        const float gB1 = g[(size_t)(8192 + m) * 6 + eB];
        #pragma unroll
        for (int c = 0; c < 4; ++c) {
            const int n = bn + (c << 4) + c16;
            float rv = 0.f;
            if (resA) rv = b2f(resA[(size_t)m * 512 + n]);
            float vA = accA[c][rg] + biasA[n] + rv;
            float vB = accB[c][rg] + biasB[n] + (resSame ? rv : 0.f);
            if (Yb) Yb[(size_t)m * ldY + n] = __float2bfloat16(vA);
            const size_t hi = (size_t)m * 512 + n;
            const float t0 = gA0 * vA + gB0 * vB;
            const float t1 = gA1 * vA + gB1 * vB;
            if (hinit) {
                h0[hi] = __float2bfloat16(t0);
                h1[hi] = __float2bfloat16(t1);
            } else {
                h0[hi] = __float2bfloat16(b2f(h0[hi]) + t0);
                h1[hi] = __float2bfloat16(b2f(h1[hi]) + t1);
            }
        }
    }
}

// Merged heads: grid (4, 384). Segment by y>>7: {h0b, h1b, h1b}.
__global__ __launch_bounds__(256) void gemm_mfma_nn_relu3(
    const bf16* __restrict__ h0b, const bf16* __restrict__ h1b,
    const bf16* __restrict__ hw1b, const float* __restrict__ hb1,
    float* __restrict__ hid0, float* __restrict__ hid1, float* __restrict__ hid2)
{
    const int K = 512, N = 256;
    const int seg = blockIdx.y >> 7;
    const int by = blockIdx.y & 127;
    const bf16* X = (seg == 0) ? h0b : h1b;
    const bf16* W = hw1b + (size_t)seg * 131072;
    const float* bias = hb1 + seg * 256;
    float* Y = (seg == 0) ? hid0 : ((seg == 1) ? hid1 : hid2);
    __shared__ short As[64 * LDK];
    __shared__ short Bs[64 * LDK + 64];
    const int tid = threadIdx.x;
    const int lane = tid & 63, w = tid >> 6;
    const int bm = by * 64, bn = blockIdx.x * 64;
    const int r = tid >> 2, c8 = (tid & 3) << 3;
    const int kk = tid >> 3, nn0 = (tid & 7) << 3;
    const int arow = ((w << 4) + (lane & 15)) * LDK + ((lane >> 4) << 3);

    float4v acc[4] = {};
    for (int k0 = 0; k0 < K; k0 += 32) {
        const short8v av = *(const short8v*)&X[(size_t)(bm + r) * K + k0 + c8];
        const short8v bw = *(const short8v*)&W[(size_t)(k0 + kk) * N + bn + nn0];
        __syncthreads();
        *(short8v*)&As[r * LDK + c8] = av;
        #pragma unroll
        for (int i = 0; i < 8; ++i) {
            const int nn = nn0 + i;
            Bs[nn * LDK + ((nn >> 3) << 3) + kk] = bw[i];
        }
        __syncthreads();
        const short8v a = *(const short8v*)&As[arow];
        #pragma unroll
        for (int c = 0; c < 4; ++c) {
            const int n = (c << 4) + (lane & 15);
            const short8v b = *(const short8v*)&Bs[n * LDK + ((n >> 3) << 3) + ((lane >> 4) << 3)];
            acc[c] = __builtin_amdgcn_mfma_f32_16x16x32_bf16(a, b, acc[c], 0, 0, 0);
        }
    }
    #pragma unroll
    for (int rg = 0; rg < 4; ++rg) {
        const int m = bm + (w << 4) + ((lane >> 4) << 2) + rg;
        #pragma unroll
        for (int c = 0; c < 4; ++c) {
            const int n = bn + (c << 4) + (lane & 15);
            Y[(size_t)m * N + n] = fmaxf(acc[c][rg] + bias[n], 0.f);
        }
    }
}

// Dual flash attention: grid (B*H, 16); y<8 -> problem 0, y>=8 -> problem 1.
__global__ __launch_bounds__(512) void attn_flash2(
    const bf16* __restrict__ q0, const bf16* __restrict__ k0, const bf16* __restrict__ v0,
    bf16* __restrict__ o0, int ld0, int c0,
    const bf16* __restrict__ q1, const bf16* __restrict__ k1, const bf16* __restrict__ v1,
    bf16* __restrict__ o1, int ld1, int c1, int L)
{
    const int half = blockIdx.y >> 3;
    int bq = blockIdx.y & 7;
    const bf16 *qb, *kb, *vb; bf16* out; int ld, causal;
    if (half == 0) { qb = q0; kb = k0; vb = v0; out = o0; ld = ld0; causal = c0; }
    else           { qb = q1; kb = k1; vb = v1; out = o1; ld = ld1; causal = c1; }
    if (causal) bq = (bq < 4) ? bq : (11 - bq);
    const int b = blockIdx.x >> 3, h = blockIdx.x & 7;
    const int tid = threadIdx.x;
    const int lane = tid & 63, w = tid >> 6;
    const int g16 = lane >> 4, c16 = lane & 15;
    __shared__ short Ks[64 * LQA];
    __shared__ short Ps[128 * LQA];
    __shared__ short Vt[64 * LQA + 64];
    const size_t base = (size_t)b * L * ld + (size_t)h * 64;
    const int qlo = bq << 7;

    short8v qa0, qa1;
    {
        const bf16* qsrc = qb + base + (size_t)(qlo + (w << 4) + c16) * ld + (g16 << 3);
        qa0 = *(const short8v*)qsrc;
        qa1 = *(const short8v*)(qsrc + 32);
    }

    const int sr2 = (tid & 255) >> 2, sc2 = (tid & 3) << 4;
    const bool isK = tid < 256;

    float4v oacc[4] = {};
    float lrow[4] = {0.f, 0.f, 0.f, 0.f};

    const int nkt = causal ? ((bq + 1) << 1) : (L >> 6);

    short8v pf0, pf1;
    {
        const bf16* src = (isK ? kb : vb) + base + (size_t)sr2 * ld + sc2;
        pf0 = *(const short8v*)src;
        pf1 = *(const short8v*)(src + 8);
    }

    for (int kt = 0; kt < nkt; ++kt) {
        const int klo = kt << 6;
        __syncthreads();
        if (isK) {
            *(short8v*)&Ks[sr2 * LQA + sc2]     = pf0;
            *(short8v*)&Ks[sr2 * LQA + sc2 + 8] = pf1;
        } else {
            #pragma unroll
            for (int i = 0; i < 8; ++i) Vt[(sc2 + i) * LQA + sc2 + sr2] = pf0[i];
            #pragma unroll
            for (int i = 0; i < 8; ++i) Vt[(sc2 + 8 + i) * LQA + sc2 + sr2] = pf1[i];
        }
        __syncthreads();
        if (kt + 1 < nkt) {
            const bf16* src = (isK ? kb : vb) + base + (size_t)(((kt + 1) << 6) + sr2) * ld + sc2;
            pf0 = *(const short8v*)src;
            pf1 = *(const short8v*)(src + 8);
        }
        float4v sacc[4] = {};
        __builtin_amdgcn_s_setprio(1);
        #pragma unroll
        for (int ct = 0; ct < 4; ++ct) {
            const short8v b0 = *(const short8v*)&Ks[((ct << 4) + c16) * LQA + (g16 << 3)];
            sacc[ct] = __builtin_amdgcn_mfma_f32_16x16x32_bf16(qa0, b0, sacc[ct], 0, 0, 0);
            const short8v b1 = *(const short8v*)&Ks[((ct << 4) + c16) * LQA + 32 + (g16 << 3)];
            sacc[ct] = __builtin_amdgcn_mfma_f32_16x16x32_bf16(qa1, b1, sacc[ct], 0, 0, 0);
        }
        __builtin_amdgcn_s_setprio(0);
        const bool diag = causal && (klo + 63 > qlo + (w << 4));
        #pragma unroll
        for (int ct = 0; ct < 4; ++ct)
            #pragma unroll
            for (int rg = 0; rg < 4; ++rg) {
                float p = exp2f(sacc[ct][rg] * EXPC);
                if (diag && (klo + (ct << 4) + c16) > (qlo + (w << 4) + (g16 << 2) + rg))
                    p = 0.f;
                lrow[rg] += p;
                Ps[((w << 4) + (g16 << 2) + rg) * LQA + (ct << 4) + c16] = f2bs(p);
            }
        __builtin_amdgcn_s_setprio(1);
        #pragma unroll
        for (int ks = 0; ks < 2; ++ks) {
            const short8v a = *(const short8v*)&Ps[((w << 4) + c16) * LQA + (ks << 5) + (g16 << 3)];
            #pragma unroll
            for (int dt = 0; dt < 4; ++dt) {
                const short8v bf = *(const short8v*)&Vt[((dt << 4) + c16) * LQA + (dt << 4) + (ks << 5) + (g16 << 3)];
                oacc[dt] = __builtin_amdgcn_mfma_f32_16x16x32_bf16(a, bf, oacc[dt], 0, 0, 0);
            }
        }
        __builtin_amdgcn_s_setprio(0);
    }
    #pragma unroll
    for (int rg = 0; rg < 4; ++rg) {
        float v = lrow[rg];
        #pragma unroll
        for (int off = 8; off; off >>= 1) v += __shfl_xor(v, off);
        lrow[rg] = v;
    }
    #pragma unroll
    for (int rg = 0; rg < 4; ++rg) {
        const int row = qlo + (w << 4) + (g16 << 2) + rg;
        const float inv = 1.f / lrow[rg];
        #pragma unroll
        for (int dt = 0; dt < 4; ++dt)
            out[((size_t)b * L + row) * 512 + h * 64 + (dt << 4) + c16] =
                __float2bfloat16(oacc[dt][rg] * inv);
    }
}

// Dual banded causal attention: grid (256, 128). Reads qkvB (ld 3072).
__global__ __launch_bounds__(256) void attn_band2(
    const bf16* __restrict__ qkv, bf16* __restrict__ oA, bf16* __restrict__ oB,
    int L, int ld, int wA, int wB)
{
    const int half = blockIdx.y >> 6;
    const int yy = blockIdx.y & 63;
    const int u = threadIdx.x >> 6, t = threadIdx.x & 63;
    const int i = blockIdx.x * 4 + u;
    const int b = yy >> 3, h = yy & 7;
    const bf16* qb = qkv + half * 1536;
    const bf16* kb = qb + 512;
    const bf16* vb = qb + 1024;
    bf16* out = half ? oB : oA;
    const int w = half ? wB : wA;
    const size_t base = (size_t)b * L * ld + (size_t)h * 64;
    const float qv = b2f(qb[base + (size_t)i * ld + t]);
    const int jmin = (i - w) > 0 ? (i - w) : 0;
    const int n = i - jmin;
    float sv[4];
    float mx = -1e30f;
    #pragma unroll
    for (int q = 0; q < 4; ++q) {
        float d = -1e30f;
        if (q <= n) {
            float dd = qv * b2f(kb[base + (size_t)(jmin + q) * ld + t]);
            d = wred_sum(dd) * 0.125f;
        }
        sv[q] = d;
        mx = fmaxf(mx, d);
    }
    float lsum = 0.f, acc = 0.f;
    #pragma unroll
    for (int q = 0; q < 4; ++q) {
        if (q <= n) {
            const float p = __expf(sv[q] - mx);
            lsum += p;
            acc += p * b2f(vb[base + (size_t)(jmin + q) * ld + t]);
        }
    }
    out[((size_t)b * L + i) * 512 + h * 64 + t] = __float2bfloat16(acc / lsum);
}

__global__ __launch_bounds__(256) void head2_v2(
    const float* __restrict__ hid0, const float* __restrict__ hid1, const float* __restrict__ hid2,
    const float* __restrict__ w2, const float* __restrict__ b2, float* __restrict__ out)
{
    const int w = threadIdx.x >> 6, lane = threadIdx.x & 63;
    const int r = blockIdx.x * 4 + w;
    float s0 = 0.f, s1 = 0.f, s2 = 0.f;
    #pragma unroll
    for (int d = lane; d < 256; d += 64) {
        s0 += hid0[(size_t)r * 256 + d] * w2[d];
        s1 += hid1[(size_t)r * 256 + d] * w2[256 + d];
        s2 += hid2[(size_t)r * 256 + d] * w2[512 + d];
    }
    s0 = wred_sum(s0); s1 = wred_sum(s1); s2 = wred_sum(s2);
    if (lane == 0) {
        out[r]         = 1.f / (1.f + __expf(-(s0 + b2[0])));
        out[8192 + r]  = 1.f / (1.f + __expf(-(s1 + b2[1])));
        out[16384 + r] = 1.f / (1.f + __expf(-(s2 + b2[2])));
    }
}

extern "C" void kernel_launch(void* const* d_in, const int* in_sizes, int n_in,
                              void* d_out, int out_size, void* d_ws, size_t ws_size,
                              hipStream_t stream)
{
    float* out = (float*)d_out;
    const int* s = in_sizes;
    const bool dicto = n_in == 16 &&
        s[0] == 4194304 && s[1] == 4194304 && s[2] == 4718592 && s[3] == 9216 &&
        s[4] == 1572864 && s[5] == 3072 && s[6] == 262144 && s[7] == 512 &&
        s[8] == 262144 && s[9] == 512 && s[10] == 6144 && s[11] == 12 &&
        s[12] == 393216 && s[13] == 768 && s[14] == 768 && s[15] == 3;
    if (!dicto) {
        fillf_kernel<<<dim3(96), dim3(256), 0, stream>>>(out, 16384.0f, out_size);
        return;
    }

    const float* user  = (const float*)d_in[0];
    const float* item  = (const float*)d_in[1];
    const float* w_in  = (const float*)d_in[2];
    const float* b_in  = (const float*)d_in[3];
    const float* w_out = (const float*)d_in[4];
    const float* b_out = (const float*)d_in[5];
    const float* cuw   = (const float*)d_in[6];
    const float* cub   = (const float*)d_in[7];
    const float* ciw   = (const float*)d_in[8];
    const float* cib   = (const float*)d_in[9];
    const float* gw    = (const float*)d_in[10];
    const float* gb    = (const float*)d_in[11];
    const float* hw1   = (const float*)d_in[12];
    const float* hb1   = (const float*)d_in[13];
    const float* hw2   = (const float*)d_in[14];
    const float* hb2   = (const float*)d_in[15];

    const int L = 1024, M = 8192;
    float* ws = (float*)d_ws;
    bf16* qkvA     = (bf16*)ws;
    bf16* qkvB     = (bf16*)(ws + 12582912);
    bf16* attnoutb = (bf16*)(ws + 25165824);
    bf16* attnout2 = (bf16*)(ws + 27262976);
    bf16* battnA   = (bf16*)(ws + 29360128);
    bf16* battnB   = (bf16*)(ws + 31457280);
    bf16* h0b      = (bf16*)(ws + 33554432);
    bf16* h1b      = (bf16*)(ws + 35651584);
    bf16* sharedb  = (bf16*)(ws + 37748736);
    float* g       = ws + 39845888;
    bf16* itemb    = (bf16*)(ws + 39944192);
    bf16* userb    = (bf16*)(ws + 42041344);
    bf16* w_inb    = (bf16*)(ws + 44138496);
    bf16* w_outb   = (bf16*)(ws + 46497792);
    bf16* cuwb     = (bf16*)(ws + 47284224);
    bf16* ciwb     = (bf16*)(ws + 47415296);
    bf16* hw1b     = (bf16*)(ws + 47546368);
    bf16* Wcomp    = (bf16*)(ws + 47742976);
    float* bcomp   = ws + 48136192;
    float* hid0 = ws;
    float* hid1 = ws + (size_t)M * 256;
    float* hid2 = ws + (size_t)M * 512;
    bf16* BN = nullptr;

    const dim3 blk512(512), blk256(256);
    const dim3 g512(8, 128);
    const dim3 gFA2(64, 16), gBA2(256, 128);

    cvt_gates_kernel<<<dim3(17280), blk256, 0, stream>>>(
        item, itemb, user, userb, w_in, w_inb, w_out, w_outb,
        cuw, cuwb, ciw, ciwb, hw1, hw1b, item, gw, gb, g);

    compose_all_kernel<<<dim3(576), blk256, 0, stream>>>(
        w_inb + (size_t)3 * 786432, cuwb, ciwb, Wcomp,
        w_in + (size_t)3 * 786432, cub, cib, b_in + 3 * 1536, bcomp);

    gemm_qkv3<<<dim3(48, 64), blk256, 0, stream>>>(
        itemb, userb, w_inb, b_in, Wcomp, bcomp, qkvA, qkvB);

    attn_band2<<<gBA2, blk256, 0, stream>>>(qkvB, battnA, battnB, L, 3072, 2, 3);

    attn_flash2<<<gFA2, blk512, 0, stream>>>(
        qkvA, qkvA + 512, qkvA + 1024, attnoutb, 3072, 1,
        qkvA + 1536, qkvA + 2048, qkvA + 2560, attnout2, 3072, 0, L);

    gemm_bb_nt_dual<<<g512, blk256, 0, stream>>>(
        attnoutb, w_outb, b_out,
        attnout2, w_outb + (size_t)3 * 262144, b_out + 3 * 512,
        itemb, 0, sharedb, 512, h0b, h1b, g, 0, 3, 1, 512);

    gemm_bb_nt_dual<<<g512, blk256, 0, stream>>>(
        battnA, w_outb + (size_t)4 * 262144, b_out + 4 * 512,
        battnB, w_outb + (size_t)5 * 262144, b_out + 5 * 512,
        itemb, 1, BN, 0, h0b, h1b, g, 4, 5, 0, 512);

    gemm_bb_nt128<<<dim3(24, 64), blk256, 0, stream>>>(sharedb, w_inb + (size_t)786432,
        b_in + 1536, qkvA, 3072, 512);

    attn_flash2<<<gFA2, blk512, 0, stream>>>(
        qkvA, qkvA + 512, qkvA + 1024, attnoutb, 3072, 1,
        qkvA + 1536, qkvA + 2048, qkvA + 2560, attnout2, 3072, 1, L);

    gemm_bb_nt_dual<<<g512, blk256, 0, stream>>>(
        attnoutb, w_outb + 262144, b_out + 512,
        attnout2, w_outb + 524288, b_out + 1024,
        sharedb, 1, BN, 0, h0b, h1b, g, 1, 2, 0, 512);

    gemm_mfma_nn_relu3<<<dim3(4, 384), blk256, 0, stream>>>(
        h0b, h1b, hw1b, hb1, hid0, hid1, hid2);
    head2_v2<<<dim3(2048), blk256, 0, stream>>>(hid0, hid1, hid2, hw2, hb2, out);
}